// Round 7
// baseline (360.006 us; speedup 1.0000x reference)
//
#include <hip/hip_runtime.h>
#include <hip/hip_bf16.h>
#include <float.h>

#define GG    64
#define NPG   1024
#define EPG   8192      // edges per graph
#define NE    524288
#define FIN   128
#define HID   256
#define K1    512
#define K2    256
#define NN0   65536     // GG*NPG
#define NN1   32768     // GG*K1
#define NN2   16384     // GG*K2
#define EPSBN 1e-5f

typedef short bf16x8 __attribute__((ext_vector_type(8)));
typedef float f32x4 __attribute__((ext_vector_type(4)));

__device__ __forceinline__ float gelu_exact(float v) {
    return 0.5f * v * (1.0f + erff(v * 0.7071067811865476f));
}

__device__ __forceinline__ unsigned short f2bf(float f) {
    union { float f; unsigned int u; } v; v.f = f;
    const unsigned int u = v.u;
    return (unsigned short)((u + 0x7FFFu + ((u >> 16) & 1u)) >> 16);   // RNE
}

__device__ __forceinline__ float bf2f(unsigned short h) {
    union { unsigned int u; float f; } v; v.u = ((unsigned int)h) << 16;
    return v.f;
}

// split fp32 -> hi/lo bf16 (hi + lo carries ~16 mantissa bits)
__device__ __forceinline__ void split_bf(float v, unsigned short& hi, unsigned short& lo) {
    hi = f2bf(v);
    lo = f2bf(v - bf2f(hi));
}

// async global->LDS, 16B per lane; lds dest must be wave-uniform base
__device__ __forceinline__ void gld16(const unsigned short* g, void* lds) {
    __builtin_amdgcn_global_load_lds(
        (const __attribute__((address_space(1))) unsigned int*)g,
        (__attribute__((address_space(3))) unsigned int*)lds, 16, 0, 0);
}

// ---------- weight transpose+concat to split-bf16 [N][K] ----------
__global__ __launch_bounds__(256) void k_w1t(const float* __restrict__ Wrel,
        const float* __restrict__ Wroot, unsigned short* __restrict__ WTh,
        unsigned short* __restrict__ WTl) {
    const int i = blockIdx.x * 256 + threadIdx.x;       // 65536 = 256n x 256k
    const int n = i >> 8, k = i & 255;
    const float v = (k < FIN) ? Wrel[k * HID + n] : Wroot[(k - FIN) * HID + n];
    unsigned short hi, lo; split_bf(v, hi, lo);
    WTh[i] = hi; WTl[i] = lo;
}

__global__ __launch_bounds__(256) void k_w2t(const float* __restrict__ Wrel,
        const float* __restrict__ Wroot, unsigned short* __restrict__ WTh,
        unsigned short* __restrict__ WTl) {
    const int i = blockIdx.x * 256 + threadIdx.x;       // 131072 = 256n x 512k
    const int n = i >> 9, k = i & 511;
    const float v = (k < HID) ? Wrel[k * HID + n] : Wroot[(k - HID) * HID + n];
    unsigned short hi, lo; split_bf(v, hi, lo);
    WTh[i] = hi; WTl[i] = lo;
}

__global__ __launch_bounds__(256) void k_q2norm(const float* __restrict__ p2,
        float* __restrict__ q2) {
    __shared__ float red[256];
    const int c = threadIdx.x;
    const float pv = p2[c];
    red[c] = pv * pv;
    __syncthreads();
    for (int s = 128; s > 0; s >>= 1) {
        if (c < s) red[c] += red[c + s];
        __syncthreads();
    }
    q2[c] = pv * rsqrtf(red[0]);
}

__global__ __launch_bounds__(256) void k_copy_x(const float* __restrict__ x,
        unsigned short* __restrict__ A1h, unsigned short* __restrict__ A1l) {
    const int total = NN0 * (FIN / 4);                  // float4 count
    for (int i = blockIdx.x * 256 + threadIdx.x; i < total; i += gridDim.x * 256) {
        const int r = i >> 5, c4 = i & 31;
        const float4 v = reinterpret_cast<const float4*>(x)[i];
        ushort4 h, l;
        split_bf(v.x, h.x, l.x); split_bf(v.y, h.y, l.y);
        split_bf(v.z, h.z, l.z); split_bf(v.w, h.w, l.w);
        const size_t o = (size_t)r * 256 + 128 + (c4 << 2);
        *reinterpret_cast<ushort4*>(&A1h[o]) = h;
        *reinterpret_cast<ushort4*>(&A1l[o]) = l;
    }
}

// ---------- CSR build: bucket edges by dst, one block per graph ----------
__global__ __launch_bounds__(512) void k_csr(const int* __restrict__ src,
        const int* __restrict__ dst, int* __restrict__ rowp,
        int* __restrict__ ssrc) {
    __shared__ int cnt[NPG];
    __shared__ int sa[NPG];
    __shared__ int sb[NPG];
    const int g = blockIdx.x, tid = threadIdx.x;
    const int eb = g * EPG;
    for (int i = tid; i < NPG; i += 512) cnt[i] = 0;
    __syncthreads();
    for (int e = tid; e < EPG; e += 512)
        atomicAdd(&cnt[dst[eb + e] & (NPG - 1)], 1);
    __syncthreads();
    for (int i = tid; i < NPG; i += 512) sa[i] = cnt[i];
    __syncthreads();
    int* cur = sa; int* nxt = sb;
    for (int d = 1; d < NPG; d <<= 1) {                 // inclusive scan
        for (int i = tid; i < NPG; i += 512)
            nxt[i] = cur[i] + ((i >= d) ? cur[i - d] : 0);
        __syncthreads();
        int* t = cur; cur = nxt; nxt = t;
    }
    for (int i = tid; i < NPG; i += 512) {
        const int st = cur[i] - cnt[i];                 // exclusive start
        rowp[g * (NPG + 1) + i] = st;
        cnt[i] = st;                                    // reuse as cursor
    }
    if (tid == 0) rowp[g * (NPG + 1) + NPG] = EPG;
    __syncthreads();
    for (int e = tid; e < EPG; e += 512) {
        const int d = dst[eb + e] & (NPG - 1);
        const int p = atomicAdd(&cnt[d], 1);
        ssrc[eb + p] = src[eb + e] & (NPG - 1);
    }
}

// ---------- agg1: CSR gather-sum, fp32 accumulate, split-bf16 out ----------
__global__ __launch_bounds__(256) void k_agg1(const float* __restrict__ x,
        const int* __restrict__ rowp, const int* __restrict__ ssrc,
        unsigned short* __restrict__ A1h, unsigned short* __restrict__ A1l) {
    const int b = blockIdx.x;
    const int g = b & 63;
    const int ng = b >> 6;                              // 0..127
    const int tid = threadIdx.x;
    const int ln = tid & 31;                            // col float4 0..31
    const int node = (ng << 3) + (tid >> 5);            // 0..1023
    const int s0 = rowp[g * (NPG + 1) + node];
    const int s1 = rowp[g * (NPG + 1) + node + 1];
    const float4* x4 = reinterpret_cast<const float4*>(x);
    const size_t gb = (size_t)(g << 10) * 32;           // 32 float4 per x row
    const int* sp = ssrc + (size_t)g * EPG;
    float4 acc = make_float4(0.f, 0.f, 0.f, 0.f);
    for (int j = s0; j < s1; ++j) {
        const float4 v = x4[gb + (size_t)sp[j] * 32 + ln];
        acc.x += v.x; acc.y += v.y; acc.z += v.z; acc.w += v.w;
    }
    ushort4 h, l;
    split_bf(acc.x, h.x, l.x); split_bf(acc.y, h.y, l.y);
    split_bf(acc.z, h.z, l.z); split_bf(acc.w, h.w, l.w);
    const size_t o = ((size_t)((g << 10) + node)) * 256 + (ln << 2);
    *reinterpret_cast<ushort4*>(&A1h[o]) = h;
    *reinterpret_cast<ushort4*>(&A1l[o]) = l;
}

// ---------- agg2: reuse layer-1 CSR buckets, fp32 in, split-bf16 out ----------
__global__ __launch_bounds__(256) void k_agg2(const float* __restrict__ H2F,
        const int* __restrict__ rowp, const int* __restrict__ ssrc,
        const int* __restrict__ perm1, const int* __restrict__ map1,
        unsigned short* __restrict__ A2h, unsigned short* __restrict__ A2l) {
    const int b = blockIdx.x;
    const int g = b & 63;
    const int ng = b >> 6;                              // 0..127
    const int tid = threadIdx.x;
    const int ln = tid & 63;                            // col float4 0..63
    const int ni = (ng << 2) + (tid >> 6);              // new node 0..511
    const int on = perm1[(g << 9) + ni] & (NPG - 1);    // old node id
    const int s0 = rowp[g * (NPG + 1) + on];
    const int s1 = rowp[g * (NPG + 1) + on + 1];
    const float4* h4 = reinterpret_cast<const float4*>(H2F);
    const int* sp = ssrc + (size_t)g * EPG;
    const int* mp = map1 + ((size_t)g << 10);
    float4 acc = make_float4(0.f, 0.f, 0.f, 0.f);
    for (int j = s0; j < s1; ++j) {
        const int ms = mp[sp[j]];                       // global new id or -1
        if (ms < 0) continue;                           // lane-uniform branch
        const float4 v = h4[(size_t)ms * 64 + ln];
        acc.x += v.x; acc.y += v.y; acc.z += v.z; acc.w += v.w;
    }
    ushort4 h, l;
    split_bf(acc.x, h.x, l.x); split_bf(acc.y, h.y, l.y);
    split_bf(acc.z, h.z, l.z); split_bf(acc.w, h.w, l.w);
    const size_t o = ((size_t)((g << 9) + ni)) * 512 + (ln << 2);
    *reinterpret_cast<ushort4*>(&A2h[o]) = h;
    *reinterpret_cast<ushort4*>(&A2l[o]) = l;
}

// ---------- split-bf16 MFMA GEMM with global_load_lds + XOR-swizzled LDS ----
// C[M][256] = (Ah+Al)[M][K] @ (Bh+Bl)[256][K]^T. 128x128 tile, 4 waves 2x2,
// each wave 64x64 = 4x4 frags of 16x16x32. acc += Ah*Bh + Ah*Bl + Al*Bh.
// LDS: 4 planes x [128 rows][32 shorts] linear (64B rows). Value-swizzle:
// LDS[row][slot] holds global k-chunk (slot ^ ((row>>1)&3)); ds_read applies
// the inverse. 16-lane fragment reads hit all 32 banks 2x => conflict-free.
// EPI 0: +bias; 1: +bias, gelu, col sum/sumsq stats; 2: +bias, fused score-dot
template<int K, int EPI>
__global__ __launch_bounds__(256) void k_gemm3(
        const unsigned short* __restrict__ Ah, const unsigned short* __restrict__ Al,
        const unsigned short* __restrict__ Bh, const unsigned short* __restrict__ Bl,
        const float* __restrict__ bias, float* __restrict__ C,
        float* __restrict__ stats, const float* __restrict__ qv2,
        float* __restrict__ scores, int M) {
    __shared__ unsigned short Ash[128 * 32];            // 8 KB each
    __shared__ unsigned short Asl[128 * 32];
    __shared__ unsigned short Bsh[128 * 32];
    __shared__ unsigned short Bsl[128 * 32];
    __shared__ float csum[128];
    __shared__ float csq[128];
    const int tid = threadIdx.x;
    const int l = tid & 63, w = tid >> 6;
    const int wm = w >> 1, wn = w & 1;
    const int m0 = blockIdx.x * 128, n0 = blockIdx.y * 128;
    const int r16 = l & 15, kg = l >> 4;

    // staging geometry: wave w stages 16-row chunks {2w, 2w+1} of each plane.
    // lane: rowInChunk = l>>2, 16B-slot = l&3; global chunk = slot ^ ((row>>1)&3)
    const int c0r = (w << 5) + (l >> 2);                // rows 32w..32w+15
    const int c1r = c0r + 16;
    const size_t aoff0 = (size_t)(m0 + c0r) * K + (((l & 3) ^ ((c0r >> 1) & 3)) << 3);
    const size_t aoff1 = (size_t)(m0 + c1r) * K + (((l & 3) ^ ((c1r >> 1) & 3)) << 3);
    const size_t boff0 = (size_t)(n0 + c0r) * K + (((l & 3) ^ ((c0r >> 1) & 3)) << 3);
    const size_t boff1 = (size_t)(n0 + c1r) * K + (((l & 3) ^ ((c1r >> 1) & 3)) << 3);
    const int lds0 = (w << 11);                          // chunk 2w   byte base
    const int lds1 = (w << 11) + 1024;                   // chunk 2w+1 byte base

    f32x4 acc[4][4] = {};

    for (int k0 = 0; k0 < K; k0 += 32) {
        __syncthreads();                                 // LDS reuse fence
        gld16(Ah + aoff0 + k0, (char*)Ash + lds0);
        gld16(Ah + aoff1 + k0, (char*)Ash + lds1);
        gld16(Al + aoff0 + k0, (char*)Asl + lds0);
        gld16(Al + aoff1 + k0, (char*)Asl + lds1);
        gld16(Bh + boff0 + k0, (char*)Bsh + lds0);
        gld16(Bh + boff1 + k0, (char*)Bsh + lds1);
        gld16(Bl + boff0 + k0, (char*)Bsl + lds0);
        gld16(Bl + boff1 + k0, (char*)Bsl + lds1);
        __syncthreads();                                 // drains vmcnt(0)
        bf16x8 afh[4], afl[4], bfh[4], bfl[4];
#pragma unroll
        for (int mi = 0; mi < 4; ++mi) {
            const int r = wm * 64 + mi * 16 + r16;
            const int bo = r * 64 + (((kg ^ ((r >> 1) & 3))) << 4);
            afh[mi] = *reinterpret_cast<const bf16x8*>((const char*)Ash + bo);
            afl[mi] = *reinterpret_cast<const bf16x8*>((const char*)Asl + bo);
        }
#pragma unroll
        for (int ni = 0; ni < 4; ++ni) {
            const int r = wn * 64 + ni * 16 + r16;
            const int bo = r * 64 + (((kg ^ ((r >> 1) & 3))) << 4);
            bfh[ni] = *reinterpret_cast<const bf16x8*>((const char*)Bsh + bo);
            bfl[ni] = *reinterpret_cast<const bf16x8*>((const char*)Bsl + bo);
        }
#pragma unroll
        for (int mi = 0; mi < 4; ++mi)
#pragma unroll
            for (int ni = 0; ni < 4; ++ni) {
                acc[mi][ni] = __builtin_amdgcn_mfma_f32_16x16x32_bf16(
                    afh[mi], bfh[ni], acc[mi][ni], 0, 0, 0);
                acc[mi][ni] = __builtin_amdgcn_mfma_f32_16x16x32_bf16(
                    afh[mi], bfl[ni], acc[mi][ni], 0, 0, 0);
                acc[mi][ni] = __builtin_amdgcn_mfma_f32_16x16x32_bf16(
                    afl[mi], bfh[ni], acc[mi][ni], 0, 0, 0);
            }
    }

    if (EPI == 1) {
        if (tid < 128) { csum[tid] = 0.f; csq[tid] = 0.f; }
        __syncthreads();
    }

    float qv[4];
    if (EPI == 2) {
#pragma unroll
        for (int ni = 0; ni < 4; ++ni) qv[ni] = qv2[n0 + wn * 64 + ni * 16 + r16];
    }
    float sA[4] = {0, 0, 0, 0};
    float qA[4] = {0, 0, 0, 0};
    float sp[4][4] = {};
#pragma unroll
    for (int mi = 0; mi < 4; ++mi)
#pragma unroll
        for (int ni = 0; ni < 4; ++ni) {
            const int col = n0 + wn * 64 + ni * 16 + r16;
            const float bc = bias[col];
#pragma unroll
            for (int r = 0; r < 4; ++r) {
                const int row = m0 + wm * 64 + mi * 16 + (kg << 2) + r;
                float t = acc[mi][ni][r] + bc;
                if (EPI == 1) {
                    t = gelu_exact(t);
                    sA[ni] += t;
                    qA[ni] += t * t;
                }
                if (EPI == 2) sp[mi][r] += t * qv[ni];
                C[(size_t)row * 256 + col] = t;
            }
        }
    if (EPI == 1) {
#pragma unroll
        for (int ni = 0; ni < 4; ++ni) {
            const int cl = wn * 64 + ni * 16 + r16;
            unsafeAtomicAdd(&csum[cl], sA[ni]);
            unsafeAtomicAdd(&csq[cl], qA[ni]);
        }
        __syncthreads();
        if (tid < 128) {
            unsafeAtomicAdd(&stats[n0 + tid], csum[tid]);
            unsafeAtomicAdd(&stats[HID + n0 + tid], csq[tid]);
        }
    }
    if (EPI == 2) {
#pragma unroll
        for (int mi = 0; mi < 4; ++mi)
#pragma unroll
            for (int r = 0; r < 4; ++r) {
                float s = sp[mi][r];
                s += __shfl_xor(s, 1);
                s += __shfl_xor(s, 2);
                s += __shfl_xor(s, 4);
                s += __shfl_xor(s, 8);
                if (r16 == 0)
                    atomicAdd(&scores[m0 + wm * 64 + mi * 16 + (kg << 2) + r], s);
            }
    }
}

// ---------- BN finalize / score fold ----------
__global__ __launch_bounds__(256) void k_finalize1(const float* __restrict__ stats,
        const float* __restrict__ g1, const float* __restrict__ bt1,
        const float* __restrict__ p1, float* __restrict__ scale,
        float* __restrict__ shift, float* __restrict__ q, float* __restrict__ r) {
    __shared__ float red[256];
    const int c = threadIdx.x;
    const float m = stats[c] * (1.f / NN0);
    const float v = stats[HID + c] * (1.f / NN0) - m * m;
    const float sc = g1[c] * rsqrtf(v + EPSBN);
    const float sh = bt1[c] - m * sc;
    scale[c] = sc;
    shift[c] = sh;
    const float pv = p1[c];
    red[c] = pv * pv;
    __syncthreads();
    for (int s = 128; s > 0; s >>= 1) {
        if (c < s) red[c] += red[c + s];
        __syncthreads();
    }
    const float inv = rsqrtf(red[0]);
    q[c] = sc * pv * inv;
    __syncthreads();
    red[c] = sh * pv * inv;
    __syncthreads();
    for (int s = 128; s > 0; s >>= 1) {
        if (c < s) red[c] += red[c + s];
        __syncthreads();
    }
    if (c == 0) r[0] = red[0];
}

__global__ __launch_bounds__(256) void k_finalize2(const float* __restrict__ stats,
        const float* __restrict__ g2, const float* __restrict__ bt2,
        float* __restrict__ scale, float* __restrict__ shift) {
    const int c = threadIdx.x;
    const float m = stats[c] * (1.f / NN1);
    const float v = stats[HID + c] * (1.f / NN1) - m * m;
    const float sc = g2[c] * rsqrtf(v + EPSBN);
    scale[c] = sc;
    shift[c] = bt2[c] - m * sc;
}

// ---------- scores (layer1): raw dot h.q + r (tanh applied in topk) ----------
__global__ __launch_bounds__(256) void k_score(const float* __restrict__ H,
        const float* __restrict__ q, const float* __restrict__ r,
        float* __restrict__ out) {
    const int node = blockIdx.x * 4 + (threadIdx.x >> 6);
    const int lane = threadIdx.x & 63;
    const float4 h = *reinterpret_cast<const float4*>(H + (size_t)node * HID + (lane << 2));
    const float4 qv = *reinterpret_cast<const float4*>(q + (lane << 2));
    float d = h.x * qv.x + h.y * qv.y + h.z * qv.z + h.w * qv.w;
#pragma unroll
    for (int off = 32; off > 0; off >>= 1) d += __shfl_xor(d, off);
    if (lane == 0) out[node] = d + (r ? r[0] : 0.f);
}

// ---------- per-graph bitonic top-k (applies tanh at load) ----------
template<int NN_, int KK_, int NT_>
__global__ __launch_bounds__(NT_) void k_topk(const float* __restrict__ scores,
        int* __restrict__ perm, float* __restrict__ vals, int* __restrict__ mapping) {
    __shared__ float s[NN_];
    __shared__ int id[NN_];
    const int g = blockIdx.x, tid = threadIdx.x;
    for (int i = tid; i < NN_; i += NT_) { s[i] = tanhf(scores[g * NN_ + i]); id[i] = i; }
    __syncthreads();
    for (int k = 2; k <= NN_; k <<= 1) {
        for (int j = k >> 1; j > 0; j >>= 1) {
            for (int t = tid; t < NN_; t += NT_) {
                const int ixj = t ^ j;
                if (ixj > t) {
                    const bool desc = ((t & k) == 0);
                    const float s1 = s[t], s2 = s[ixj];
                    const int i1 = id[t], i2 = id[ixj];
                    const bool inOrder = (s1 > s2) || (s1 == s2 && i1 < i2);
                    if (inOrder != desc) { s[t] = s2; s[ixj] = s1; id[t] = i2; id[ixj] = i1; }
                }
            }
            __syncthreads();
        }
    }
    for (int i = tid; i < KK_; i += NT_) {
        const int oid = id[i];
        perm[g * KK_ + i] = g * NN_ + oid;
        vals[g * KK_ + i] = s[i];
        if (mapping) mapping[g * NN_ + oid] = g * KK_ + i;
    }
}

// ---------- pool1 apply, stage 1: 512 blocks (g x 8 node-groups) ----------
__global__ __launch_bounds__(256) void k_pool1p(const float* __restrict__ HG,
        const int* __restrict__ perm, const float* __restrict__ vals,
        const float* __restrict__ scale1, const float* __restrict__ shift1,
        float* __restrict__ H1P, float* __restrict__ pmax,
        float* __restrict__ psum, float* __restrict__ psq) {
    const int b = blockIdx.x;
    const int g = b >> 3, ig = b & 7;
    const int c = threadIdx.x;
    const float sc = scale1[c], sh = shift1[c];
    float mx = -FLT_MAX, sm = 0.f, sq = 0.f;
    for (int i = ig * 64; i < ig * 64 + 64; ++i) {
        const int idx = (g << 9) + i;
        const int srow = perm[idx];
        const float val = vals[idx];
        const float hv = HG[(size_t)srow * HID + c];
        const float xn = (hv * sc + sh) * val;
        H1P[(size_t)idx * HID + c] = xn;
        mx = fmaxf(mx, xn);
        sm += xn;
        sq += xn * xn;
    }
    pmax[b * 256 + c] = mx;
    psum[b * 256 + c] = sm;
    psq[b * 256 + c] = sq;
}

// ---------- pool1 stage 2: reduce 8 partials, x1 readout, bn2 stats ----------
__global__ __launch_bounds__(256) void k_pool1r(const float* __restrict__ pmax,
        const float* __restrict__ psum, const float* __restrict__ psq,
        float* __restrict__ X1, float* __restrict__ stats2) {
    const int g = blockIdx.x, c = threadIdx.x;
    float mx = -FLT_MAX, sm = 0.f, sq = 0.f;
    for (int ig = 0; ig < 8; ++ig) {
        const int o = ((g << 3) + ig) * 256 + c;
        mx = fmaxf(mx, pmax[o]);
        sm += psum[o];
        sq += psq[o];
    }
    X1[g * 512 + c] = mx;
    X1[g * 512 + 256 + c] = sm * (1.f / K1);
    unsafeAtomicAdd(&stats2[c], sm);
    unsafeAtomicAdd(&stats2[HID + c], sq);
}

// ---------- h2in = gelu(bn2(h1p)): fp32 copy + split-bf16 A2 right half ----------
__global__ __launch_bounds__(256) void k_h2in(const float* __restrict__ H1P,
        const float* __restrict__ scale2, const float* __restrict__ shift2,
        unsigned short* __restrict__ A2h, unsigned short* __restrict__ A2l,
        float* __restrict__ H2F) {
    const int total = NN1 * (HID / 4);
    for (int i = blockIdx.x * 256 + threadIdx.x; i < total; i += gridDim.x * 256) {
        const int r = i >> 6, c4 = i & 63;
        const float4 v = reinterpret_cast<const float4*>(H1P)[i];
        const float4 sc = reinterpret_cast<const float4*>(scale2)[c4];
        const float4 sh = reinterpret_cast<const float4*>(shift2)[c4];
        float4 o;
        o.x = gelu_exact(v.x * sc.x + sh.x);
        o.y = gelu_exact(v.y * sc.y + sh.y);
        o.z = gelu_exact(v.z * sc.z + sh.z);
        o.w = gelu_exact(v.w * sc.w + sh.w);
        reinterpret_cast<float4*>(H2F)[i] = o;
        ushort4 h, l;
        split_bf(o.x, h.x, l.x); split_bf(o.y, h.y, l.y);
        split_bf(o.z, h.z, l.z); split_bf(o.w, h.w, l.w);
        const size_t off = (size_t)r * 512 + 256 + (c4 << 2);
        *reinterpret_cast<ushort4*>(&A2h[off]) = h;
        *reinterpret_cast<ushort4*>(&A2l[off]) = l;
    }
}

// ---------- x2 readout ----------
__global__ __launch_bounds__(256) void k_x2(const float* __restrict__ H2,
        const int* __restrict__ perm, const float* __restrict__ vals,
        float* __restrict__ X2) {
    const int g = blockIdx.x, c = threadIdx.x;
    float mx = -FLT_MAX, sm = 0.f;
    for (int i = 0; i < K2; ++i) {
        const int idx = g * K2 + i;
        const int srow = perm[idx];
        const float v = H2[(size_t)srow * HID + c] * vals[idx];
        mx = fmaxf(mx, v);
        sm += v;
    }
    X2[g * 512 + c] = mx;
    X2[g * 512 + 256 + c] = sm * (1.f / K2);
}

// ---------- final linear: out = (x1+x2) @ Wl + bl ----------
__global__ __launch_bounds__(256) void k_final(const float* __restrict__ X1,
        const float* __restrict__ X2, const float* __restrict__ Wl,
        const float* __restrict__ bl, float* __restrict__ out) {
    const int g = blockIdx.x, c = threadIdx.x;
    float acc = bl[c];
    for (int k = 0; k < 512; ++k) {
        const float xv = X1[g * 512 + k] + X2[g * 512 + k];
        acc = fmaf(xv, Wl[k * HID + c], acc);
    }
    out[g * HID + c] = acc;
}

extern "C" void kernel_launch(void* const* d_in, const int* in_sizes, int n_in,
                              void* d_out, int out_size, void* d_ws, size_t ws_size,
                              hipStream_t stream) {
    (void)in_sizes; (void)n_in; (void)out_size; (void)ws_size;
    const float* x       = (const float*)d_in[0];
    const int*   src     = (const int*)  d_in[1];
    const int*   dst     = (const int*)  d_in[2];
    const float* W_rel1  = (const float*)d_in[3];
    const float* b_rel1  = (const float*)d_in[4];
    const float* W_root1 = (const float*)d_in[5];
    const float* g1      = (const float*)d_in[6];
    const float* bt1     = (const float*)d_in[7];
    const float* p1      = (const float*)d_in[8];
    const float* g2      = (const float*)d_in[9];
    const float* bt2     = (const float*)d_in[10];
    const float* W_rel2  = (const float*)d_in[11];
    const float* b_rel2  = (const float*)d_in[12];
    const float* W_root2 = (const float*)d_in[13];
    const float* p2      = (const float*)d_in[14];
    const float* Wl      = (const float*)d_in[15];
    const float* bl      = (const float*)d_in[16];
    float* out = (float*)d_out;

    char* w = (char*)d_ws;
    size_t off = 0;
    auto alloc = [&](size_t bytes) -> void* {
        void* p = w + off;
        off += (bytes + 255) & ~(size_t)255;
        return p;
    };
    unsigned short* A1h = (unsigned short*)alloc((size_t)NN0 * 256 * 2);  // 32 MB
    unsigned short* A1l = (unsigned short*)alloc((size_t)NN0 * 256 * 2);  // 32 MB
    float* HG     = (float*)alloc((size_t)NN0 * 256 * 4);   // 64 MB: gelu(conv1) fp32
    float* H2F    = (float*)alloc((size_t)NN1 * 256 * 4);   // 32 MB: gelu(bn2) fp32
    int*   ROWP   = (int*)  alloc((size_t)GG * (NPG + 1) * 4);
    int*   SSRC   = (int*)  alloc((size_t)NE * 4);
    float* SCORES = (float*)alloc((size_t)NN0 * 4);         // reused for pool2
    int*   PERM1  = (int*)  alloc((size_t)NN1 * 4);
    float* VALS1  = (float*)alloc((size_t)NN1 * 4);
    int*   MAP1   = (int*)  alloc((size_t)NN0 * 4);
    int*   PERM2  = (int*)  alloc((size_t)NN2 * 4);
    float* VALS2  = (float*)alloc((size_t)NN2 * 4);
    float* STATS1 = (float*)alloc(512 * 4);
    float* STATS2 = (float*)alloc(512 * 4);
    float* SCALE1 = (float*)alloc(256 * 4);
    float* SHIFT1 = (float*)alloc(256 * 4);
    float* Q1     = (float*)alloc(256 * 4);
    float* R1     = (float*)alloc(256);
    float* SCALE2 = (float*)alloc(256 * 4);
    float* SHIFT2 = (float*)alloc(256 * 4);
    float* Q2     = (float*)alloc(256 * 4);
    unsigned short* W1Th = (unsigned short*)alloc((size_t)256 * 256 * 2);
    unsigned short* W1Tl = (unsigned short*)alloc((size_t)256 * 256 * 2);
    unsigned short* W2Th = (unsigned short*)alloc((size_t)256 * 512 * 2);
    unsigned short* W2Tl = (unsigned short*)alloc((size_t)256 * 512 * 2);
    float* X1     = (float*)alloc((size_t)GG * 512 * 4);
    float* X2     = (float*)alloc((size_t)GG * 512 * 4);
    float* PMAX   = (float*)alloc((size_t)512 * 256 * 4);
    float* PSUM   = (float*)alloc((size_t)512 * 256 * 4);
    float* PSQ    = (float*)alloc((size_t)512 * 256 * 4);
    // aliases (stream-ordered, producer dead before reuse):
    float* H1P = (float*)A1h;                 // 32 MB: written after gemm1 consumed A1h
    float* H2  = (float*)A1l;                 // 32 MB: gemm2 out, after gemm1
    unsigned short* A2h = (unsigned short*)HG;                   // 32 MB of HG
    unsigned short* A2l = (unsigned short*)(HG + (size_t)NN0 * 128);  // next 32 MB

    hipMemsetAsync(STATS1, 0, 512 * sizeof(float), stream);
    hipMemsetAsync(STATS2, 0, 512 * sizeof(float), stream);
    hipMemsetAsync(MAP1, 0xFF, (size_t)NN0 * sizeof(int), stream);

    k_csr<<<GG, 512, 0, stream>>>(src, dst, ROWP, SSRC);
    k_w1t<<<256, 256, 0, stream>>>(W_rel1, W_root1, W1Th, W1Tl);
    k_w2t<<<512, 256, 0, stream>>>(W_rel2, W_root2, W2Th, W2Tl);
    k_q2norm<<<1, 256, 0, stream>>>(p2, Q2);
    k_copy_x<<<2048, 256, 0, stream>>>(x, A1h, A1l);
    k_agg1<<<8192, 256, 0, stream>>>(x, ROWP, SSRC, A1h, A1l);
    k_gemm3<256, 1><<<dim3(512, 2), 256, 0, stream>>>(A1h, A1l, W1Th, W1Tl,
        b_rel1, HG, STATS1, nullptr, nullptr, NN0);
    k_finalize1<<<1, 256, 0, stream>>>(STATS1, g1, bt1, p1, SCALE1, SHIFT1, Q1, R1);
    k_score<<<NN0 / 4, 256, 0, stream>>>(HG, Q1, R1, SCORES);
    k_topk<NPG, K1, 512><<<GG, 512, 0, stream>>>(SCORES, PERM1, VALS1, MAP1);
    k_pool1p<<<512, 256, 0, stream>>>(HG, PERM1, VALS1, SCALE1, SHIFT1, H1P, PMAX, PSUM, PSQ);
    k_pool1r<<<GG, 256, 0, stream>>>(PMAX, PSUM, PSQ, X1, STATS2);
    k_finalize2<<<1, 256, 0, stream>>>(STATS2, g2, bt2, SCALE2, SHIFT2);
    k_h2in<<<2048, 256, 0, stream>>>(H1P, SCALE2, SHIFT2, A2h, A2l, H2F);
    k_agg2<<<8192, 256, 0, stream>>>(H2F, ROWP, SSRC, PERM1, MAP1, A2h, A2l);
    hipMemsetAsync(SCORES, 0, (size_t)NN1 * sizeof(float), stream);
    k_gemm3<512, 2><<<dim3(256, 2), 256, 0, stream>>>(A2h, A2l, W2Th, W2Tl,
        b_rel2, H2, nullptr, Q2, SCORES, NN1);
    k_topk<K1, K2, 256><<<GG, 256, 0, stream>>>(SCORES, PERM2, VALS2, nullptr);
    k_x2<<<GG, 256, 0, stream>>>(H2, PERM2, VALS2, X2);
    k_final<<<GG, 256, 0, stream>>>(X1, X2, Wl, bl, out);
}

// Round 8
// 352.316 us; speedup vs baseline: 1.0218x; 1.0218x over previous
//
#include <hip/hip_runtime.h>
#include <hip/hip_bf16.h>
#include <float.h>

#define GG    64
#define NPG   1024
#define EPG   8192      // edges per graph
#define NE    524288
#define FIN   128
#define HID   256
#define K1    512
#define K2    256
#define NN0   65536     // GG*NPG
#define NN1   32768     // GG*K1
#define NN2   16384     // GG*K2
#define EPSBN 1e-5f

typedef short bf16x8 __attribute__((ext_vector_type(8)));
typedef float f32x4 __attribute__((ext_vector_type(4)));

__device__ __forceinline__ float gelu_exact(float v) {
    return 0.5f * v * (1.0f + erff(v * 0.7071067811865476f));
}

__device__ __forceinline__ unsigned short f2bf(float f) {
    union { float f; unsigned int u; } v; v.f = f;
    const unsigned int u = v.u;
    return (unsigned short)((u + 0x7FFFu + ((u >> 16) & 1u)) >> 16);   // RNE
}

__device__ __forceinline__ float bf2f(unsigned short h) {
    union { unsigned int u; float f; } v; v.u = ((unsigned int)h) << 16;
    return v.f;
}

// split fp32 -> hi/lo bf16 (hi + lo carries ~16 mantissa bits)
__device__ __forceinline__ void split_bf(float v, unsigned short& hi, unsigned short& lo) {
    hi = f2bf(v);
    lo = f2bf(v - bf2f(hi));
}

// async global->LDS, 16B per lane; lds dest must be wave-uniform base
__device__ __forceinline__ void gld16(const unsigned short* g, void* lds) {
    __builtin_amdgcn_global_load_lds(
        (const __attribute__((address_space(1))) unsigned int*)g,
        (__attribute__((address_space(3))) unsigned int*)lds, 16, 0, 0);
}

// ---------- weight transpose+concat to split-bf16 [N][K] ----------
__global__ __launch_bounds__(256) void k_w1t(const float* __restrict__ Wrel,
        const float* __restrict__ Wroot, unsigned short* __restrict__ WTh,
        unsigned short* __restrict__ WTl) {
    const int i = blockIdx.x * 256 + threadIdx.x;       // 65536 = 256n x 256k
    const int n = i >> 8, k = i & 255;
    const float v = (k < FIN) ? Wrel[k * HID + n] : Wroot[(k - FIN) * HID + n];
    unsigned short hi, lo; split_bf(v, hi, lo);
    WTh[i] = hi; WTl[i] = lo;
}

__global__ __launch_bounds__(256) void k_w2t(const float* __restrict__ Wrel,
        const float* __restrict__ Wroot, unsigned short* __restrict__ WTh,
        unsigned short* __restrict__ WTl) {
    const int i = blockIdx.x * 256 + threadIdx.x;       // 131072 = 256n x 512k
    const int n = i >> 9, k = i & 511;
    const float v = (k < HID) ? Wrel[k * HID + n] : Wroot[(k - HID) * HID + n];
    unsigned short hi, lo; split_bf(v, hi, lo);
    WTh[i] = hi; WTl[i] = lo;
}

__global__ __launch_bounds__(256) void k_q2norm(const float* __restrict__ p2,
        float* __restrict__ q2) {
    __shared__ float red[256];
    const int c = threadIdx.x;
    const float pv = p2[c];
    red[c] = pv * pv;
    __syncthreads();
    for (int s = 128; s > 0; s >>= 1) {
        if (c < s) red[c] += red[c + s];
        __syncthreads();
    }
    q2[c] = pv * rsqrtf(red[0]);
}

// ---------- CSR build: bucket edges by dst, one block per graph ----------
__global__ __launch_bounds__(512) void k_csr(const int* __restrict__ src,
        const int* __restrict__ dst, int* __restrict__ rowp,
        int* __restrict__ ssrc) {
    __shared__ int cnt[NPG];
    __shared__ int sa[NPG];
    __shared__ int sb[NPG];
    const int g = blockIdx.x, tid = threadIdx.x;
    const int eb = g * EPG;
    for (int i = tid; i < NPG; i += 512) cnt[i] = 0;
    __syncthreads();
    for (int e = tid; e < EPG; e += 512)
        atomicAdd(&cnt[dst[eb + e] & (NPG - 1)], 1);
    __syncthreads();
    for (int i = tid; i < NPG; i += 512) sa[i] = cnt[i];
    __syncthreads();
    int* cur = sa; int* nxt = sb;
    for (int d = 1; d < NPG; d <<= 1) {                 // inclusive scan
        for (int i = tid; i < NPG; i += 512)
            nxt[i] = cur[i] + ((i >= d) ? cur[i - d] : 0);
        __syncthreads();
        int* t = cur; cur = nxt; nxt = t;
    }
    for (int i = tid; i < NPG; i += 512) {
        const int st = cur[i] - cnt[i];                 // exclusive start
        rowp[g * (NPG + 1) + i] = st;
        cnt[i] = st;                                    // reuse as cursor
    }
    if (tid == 0) rowp[g * (NPG + 1) + NPG] = EPG;
    __syncthreads();
    for (int e = tid; e < EPG; e += 512) {
        const int d = dst[eb + e] & (NPG - 1);
        const int p = atomicAdd(&cnt[d], 1);
        ssrc[eb + p] = src[eb + e] & (NPG - 1);
    }
}

// ---------- agg1: CSR gather-sum + own-row copy, split-bf16 out ----------
__global__ __launch_bounds__(256) void k_agg1(const float* __restrict__ x,
        const int* __restrict__ rowp, const int* __restrict__ ssrc,
        unsigned short* __restrict__ A1h, unsigned short* __restrict__ A1l) {
    const int b = blockIdx.x;
    const int g = b & 63;
    const int ng = b >> 6;                              // 0..127
    const int tid = threadIdx.x;
    const int ln = tid & 31;                            // col float4 0..31
    const int node = (ng << 3) + (tid >> 5);            // 0..1023
    const int s0 = rowp[g * (NPG + 1) + node];
    const int s1 = rowp[g * (NPG + 1) + node + 1];
    const float4* x4 = reinterpret_cast<const float4*>(x);
    const size_t gb = (size_t)(g << 10) * 32;           // 32 float4 per x row
    const int* sp = ssrc + (size_t)g * EPG;
    float4 acc = make_float4(0.f, 0.f, 0.f, 0.f);
    for (int j = s0; j < s1; ++j) {
        const float4 v = x4[gb + (size_t)sp[j] * 32 + ln];
        acc.x += v.x; acc.y += v.y; acc.z += v.z; acc.w += v.w;
    }
    const size_t rb = ((size_t)((g << 10) + node)) * 256;
    ushort4 h, l;
    split_bf(acc.x, h.x, l.x); split_bf(acc.y, h.y, l.y);
    split_bf(acc.z, h.z, l.z); split_bf(acc.w, h.w, l.w);
    *reinterpret_cast<ushort4*>(&A1h[rb + (ln << 2)]) = h;
    *reinterpret_cast<ushort4*>(&A1l[rb + (ln << 2)]) = l;
    // own-row (lin_root operand) into right half
    const float4 xv = x4[gb + (size_t)node * 32 + ln];
    split_bf(xv.x, h.x, l.x); split_bf(xv.y, h.y, l.y);
    split_bf(xv.z, h.z, l.z); split_bf(xv.w, h.w, l.w);
    *reinterpret_cast<ushort4*>(&A1h[rb + 128 + (ln << 2)]) = h;
    *reinterpret_cast<ushort4*>(&A1l[rb + 128 + (ln << 2)]) = l;
}

// ---------- agg2: reuse layer-1 CSR buckets, fp32 in, split-bf16 out ----------
__global__ __launch_bounds__(256) void k_agg2(const float* __restrict__ H2F,
        const int* __restrict__ rowp, const int* __restrict__ ssrc,
        const int* __restrict__ perm1, const int* __restrict__ map1,
        unsigned short* __restrict__ A2h, unsigned short* __restrict__ A2l) {
    const int b = blockIdx.x;
    const int g = b & 63;
    const int ng = b >> 6;                              // 0..127
    const int tid = threadIdx.x;
    const int ln = tid & 63;                            // col float4 0..63
    const int ni = (ng << 2) + (tid >> 6);              // new node 0..511
    const int on = perm1[(g << 9) + ni] & (NPG - 1);    // old node id
    const int s0 = rowp[g * (NPG + 1) + on];
    const int s1 = rowp[g * (NPG + 1) + on + 1];
    const float4* h4 = reinterpret_cast<const float4*>(H2F);
    const int* sp = ssrc + (size_t)g * EPG;
    const int* mp = map1 + ((size_t)g << 10);
    float4 acc = make_float4(0.f, 0.f, 0.f, 0.f);
    for (int j = s0; j < s1; ++j) {
        const int ms = mp[sp[j]];                       // global new id or -1
        if (ms < 0) continue;                           // lane-uniform branch
        const float4 v = h4[(size_t)ms * 64 + ln];
        acc.x += v.x; acc.y += v.y; acc.z += v.z; acc.w += v.w;
    }
    ushort4 h, l;
    split_bf(acc.x, h.x, l.x); split_bf(acc.y, h.y, l.y);
    split_bf(acc.z, h.z, l.z); split_bf(acc.w, h.w, l.w);
    const size_t o = ((size_t)((g << 9) + ni)) * 512 + (ln << 2);
    *reinterpret_cast<ushort4*>(&A2h[o]) = h;
    *reinterpret_cast<ushort4*>(&A2l[o]) = l;
}

// ---------- split-bf16 MFMA GEMM: A dbuf + counted vmcnt (T4) ----------
// C[M][256] = (Ah+Al)[M][K] @ (Bh+Bl)[256][K]^T. 128x128 tile, 4 waves 2x2.
// A planes double-buffered (prefetch k+1 in flight across barriers, vmcnt(4));
// B single-buffered (L2-resident, short latency). Value-swizzled LDS, 0 conflicts.
// EPI 0: +bias; 1: +bias, gelu, col sum/sumsq stats; 2: +bias, fused score-dot
template<int K, int EPI>
__global__ __launch_bounds__(256) void k_gemm3(
        const unsigned short* __restrict__ Ah, const unsigned short* __restrict__ Al,
        const unsigned short* __restrict__ Bh, const unsigned short* __restrict__ Bl,
        const float* __restrict__ bias, float* __restrict__ C,
        float* __restrict__ stats, const float* __restrict__ qv2,
        float* __restrict__ scores, int M) {
    __shared__ unsigned short Ash[2][128 * 32];          // 8 KB per buf
    __shared__ unsigned short Asl[2][128 * 32];
    __shared__ unsigned short Bsh[128 * 32];
    __shared__ unsigned short Bsl[128 * 32];
    __shared__ float csum[128];
    __shared__ float csq[128];
    const int tid = threadIdx.x;
    const int l = tid & 63, w = tid >> 6;
    const int wm = w >> 1, wn = w & 1;
    const int m0 = blockIdx.x * 128, n0 = blockIdx.y * 128;
    const int r16 = l & 15, kg = l >> 4;

    // staging: wave w stages 16-row chunks {2w, 2w+1}; lane row = l>>2,
    // 16B-slot = l&3, global k-chunk = slot ^ ((row>>1)&3)  (value swizzle)
    const int c0r = (w << 5) + (l >> 2);
    const int c1r = c0r + 16;
    const size_t aoff0 = (size_t)(m0 + c0r) * K + (((l & 3) ^ ((c0r >> 1) & 3)) << 3);
    const size_t aoff1 = (size_t)(m0 + c1r) * K + (((l & 3) ^ ((c1r >> 1) & 3)) << 3);
    const size_t boff0 = (size_t)(n0 + c0r) * K + (((l & 3) ^ ((c0r >> 1) & 3)) << 3);
    const size_t boff1 = (size_t)(n0 + c1r) * K + (((l & 3) ^ ((c1r >> 1) & 3)) << 3);
    const int lds0 = (w << 11);
    const int lds1 = (w << 11) + 1024;

    f32x4 acc[4][4] = {};

    // prologue: A(0) -> buf 0
    gld16(Ah + aoff0, (char*)Ash[0] + lds0);
    gld16(Ah + aoff1, (char*)Ash[0] + lds1);
    gld16(Al + aoff0, (char*)Asl[0] + lds0);
    gld16(Al + aoff1, (char*)Asl[0] + lds1);

    for (int k0 = 0; k0 < K; k0 += 32) {
        const int cur = (k0 >> 5) & 1;
        __builtin_amdgcn_sched_barrier(0);
        __builtin_amdgcn_s_barrier();                    // frees Bs + abuf[cur^1]
        __builtin_amdgcn_sched_barrier(0);
        gld16(Bh + boff0 + k0, (char*)Bsh + lds0);
        gld16(Bh + boff1 + k0, (char*)Bsh + lds1);
        gld16(Bl + boff0 + k0, (char*)Bsl + lds0);
        gld16(Bl + boff1 + k0, (char*)Bsl + lds1);
        if (k0 + 32 < K) {
            const int nxt = cur ^ 1;
            gld16(Ah + aoff0 + k0 + 32, (char*)Ash[nxt] + lds0);
            gld16(Ah + aoff1 + k0 + 32, (char*)Ash[nxt] + lds1);
            gld16(Al + aoff0 + k0 + 32, (char*)Asl[nxt] + lds0);
            gld16(Al + aoff1 + k0 + 32, (char*)Asl[nxt] + lds1);
            asm volatile("s_waitcnt vmcnt(4)" ::: "memory");  // A(k),B(k) landed; A(k+1) in flight
        } else {
            asm volatile("s_waitcnt vmcnt(0)" ::: "memory");
        }
        __builtin_amdgcn_s_barrier();
        __builtin_amdgcn_sched_barrier(0);
        const char* abh = (const char*)Ash[cur];
        const char* abl = (const char*)Asl[cur];
        bf16x8 afh[4], afl[4], bfh[4], bfl[4];
#pragma unroll
        for (int mi = 0; mi < 4; ++mi) {
            const int r = wm * 64 + mi * 16 + r16;
            const int bo = r * 64 + (((kg ^ ((r >> 1) & 3))) << 4);
            afh[mi] = *reinterpret_cast<const bf16x8*>(abh + bo);
            afl[mi] = *reinterpret_cast<const bf16x8*>(abl + bo);
        }
#pragma unroll
        for (int ni = 0; ni < 4; ++ni) {
            const int r = wn * 64 + ni * 16 + r16;
            const int bo = r * 64 + (((kg ^ ((r >> 1) & 3))) << 4);
            bfh[ni] = *reinterpret_cast<const bf16x8*>((const char*)Bsh + bo);
            bfl[ni] = *reinterpret_cast<const bf16x8*>((const char*)Bsl + bo);
        }
#pragma unroll
        for (int mi = 0; mi < 4; ++mi)
#pragma unroll
            for (int ni = 0; ni < 4; ++ni) {
                acc[mi][ni] = __builtin_amdgcn_mfma_f32_16x16x32_bf16(
                    afh[mi], bfh[ni], acc[mi][ni], 0, 0, 0);
                acc[mi][ni] = __builtin_amdgcn_mfma_f32_16x16x32_bf16(
                    afh[mi], bfl[ni], acc[mi][ni], 0, 0, 0);
                acc[mi][ni] = __builtin_amdgcn_mfma_f32_16x16x32_bf16(
                    afl[mi], bfh[ni], acc[mi][ni], 0, 0, 0);
            }
    }

    if (EPI == 1) {
        if (tid < 128) { csum[tid] = 0.f; csq[tid] = 0.f; }
        __syncthreads();
    }

    float qv[4];
    if (EPI == 2) {
#pragma unroll
        for (int ni = 0; ni < 4; ++ni) qv[ni] = qv2[n0 + wn * 64 + ni * 16 + r16];
    }
    float sA[4] = {0, 0, 0, 0};
    float qA[4] = {0, 0, 0, 0};
    float sp[4][4] = {};
#pragma unroll
    for (int mi = 0; mi < 4; ++mi)
#pragma unroll
        for (int ni = 0; ni < 4; ++ni) {
            const int col = n0 + wn * 64 + ni * 16 + r16;
            const float bc = bias[col];
#pragma unroll
            for (int r = 0; r < 4; ++r) {
                const int row = m0 + wm * 64 + mi * 16 + (kg << 2) + r;
                float t = acc[mi][ni][r] + bc;
                if (EPI == 1) {
                    t = gelu_exact(t);
                    sA[ni] += t;
                    qA[ni] += t * t;
                }
                if (EPI == 2) sp[mi][r] += t * qv[ni];
                C[(size_t)row * 256 + col] = t;
            }
        }
    if (EPI == 1) {
#pragma unroll
        for (int ni = 0; ni < 4; ++ni) {
            const int cl = wn * 64 + ni * 16 + r16;
            unsafeAtomicAdd(&csum[cl], sA[ni]);
            unsafeAtomicAdd(&csq[cl], qA[ni]);
        }
        __syncthreads();
        if (tid < 128) {
            unsafeAtomicAdd(&stats[n0 + tid], csum[tid]);
            unsafeAtomicAdd(&stats[HID + n0 + tid], csq[tid]);
        }
    }
    if (EPI == 2) {
#pragma unroll
        for (int mi = 0; mi < 4; ++mi)
#pragma unroll
            for (int r = 0; r < 4; ++r) {
                float s = sp[mi][r];
                s += __shfl_xor(s, 1);
                s += __shfl_xor(s, 2);
                s += __shfl_xor(s, 4);
                s += __shfl_xor(s, 8);
                if (r16 == 0)
                    atomicAdd(&scores[m0 + wm * 64 + mi * 16 + (kg << 2) + r], s);
            }
    }
}

// ---------- BN finalize / score fold ----------
__global__ __launch_bounds__(256) void k_finalize1(const float* __restrict__ stats,
        const float* __restrict__ g1, const float* __restrict__ bt1,
        const float* __restrict__ p1, float* __restrict__ scale,
        float* __restrict__ shift, float* __restrict__ q, float* __restrict__ r) {
    __shared__ float red[256];
    const int c = threadIdx.x;
    const float m = stats[c] * (1.f / NN0);
    const float v = stats[HID + c] * (1.f / NN0) - m * m;
    const float sc = g1[c] * rsqrtf(v + EPSBN);
    const float sh = bt1[c] - m * sc;
    scale[c] = sc;
    shift[c] = sh;
    const float pv = p1[c];
    red[c] = pv * pv;
    __syncthreads();
    for (int s = 128; s > 0; s >>= 1) {
        if (c < s) red[c] += red[c + s];
        __syncthreads();
    }
    const float inv = rsqrtf(red[0]);
    q[c] = sc * pv * inv;
    __syncthreads();
    red[c] = sh * pv * inv;
    __syncthreads();
    for (int s = 128; s > 0; s >>= 1) {
        if (c < s) red[c] += red[c + s];
        __syncthreads();
    }
    if (c == 0) r[0] = red[0];
}

__global__ __launch_bounds__(256) void k_finalize2(const float* __restrict__ stats,
        const float* __restrict__ g2, const float* __restrict__ bt2,
        float* __restrict__ scale, float* __restrict__ shift) {
    const int c = threadIdx.x;
    const float m = stats[c] * (1.f / NN1);
    const float v = stats[HID + c] * (1.f / NN1) - m * m;
    const float sc = g2[c] * rsqrtf(v + EPSBN);
    scale[c] = sc;
    shift[c] = bt2[c] - m * sc;
}

// ---------- scores (layer1): raw dot h.q + r (tanh applied in topk) ----------
__global__ __launch_bounds__(256) void k_score(const float* __restrict__ H,
        const float* __restrict__ q, const float* __restrict__ r,
        float* __restrict__ out) {
    const int node = blockIdx.x * 4 + (threadIdx.x >> 6);
    const int lane = threadIdx.x & 63;
    const float4 h = *reinterpret_cast<const float4*>(H + (size_t)node * HID + (lane << 2));
    const float4 qv = *reinterpret_cast<const float4*>(q + (lane << 2));
    float d = h.x * qv.x + h.y * qv.y + h.z * qv.z + h.w * qv.w;
#pragma unroll
    for (int off = 32; off > 0; off >>= 1) d += __shfl_xor(d, off);
    if (lane == 0) out[node] = d + (r ? r[0] : 0.f);
}

// ---------- per-graph bitonic top-k (applies tanh at load) ----------
template<int NN_, int KK_, int NT_>
__global__ __launch_bounds__(NT_) void k_topk(const float* __restrict__ scores,
        int* __restrict__ perm, float* __restrict__ vals, int* __restrict__ mapping) {
    __shared__ float s[NN_];
    __shared__ int id[NN_];
    const int g = blockIdx.x, tid = threadIdx.x;
    for (int i = tid; i < NN_; i += NT_) { s[i] = tanhf(scores[g * NN_ + i]); id[i] = i; }
    __syncthreads();
    for (int k = 2; k <= NN_; k <<= 1) {
        for (int j = k >> 1; j > 0; j >>= 1) {
            for (int t = tid; t < NN_; t += NT_) {
                const int ixj = t ^ j;
                if (ixj > t) {
                    const bool desc = ((t & k) == 0);
                    const float s1 = s[t], s2 = s[ixj];
                    const int i1 = id[t], i2 = id[ixj];
                    const bool inOrder = (s1 > s2) || (s1 == s2 && i1 < i2);
                    if (inOrder != desc) { s[t] = s2; s[ixj] = s1; id[t] = i2; id[ixj] = i1; }
                }
            }
            __syncthreads();
        }
    }
    for (int i = tid; i < KK_; i += NT_) {
        const int oid = id[i];
        perm[g * KK_ + i] = g * NN_ + oid;
        vals[g * KK_ + i] = s[i];
        if (mapping) mapping[g * NN_ + oid] = g * KK_ + i;
    }
}

// ---------- pool1 apply, stage 1: 512 blocks (g x 8 node-groups) ----------
__global__ __launch_bounds__(256) void k_pool1p(const float* __restrict__ HG,
        const int* __restrict__ perm, const float* __restrict__ vals,
        const float* __restrict__ scale1, const float* __restrict__ shift1,
        float* __restrict__ H1P, float* __restrict__ pmax,
        float* __restrict__ psum, float* __restrict__ psq) {
    const int b = blockIdx.x;
    const int g = b >> 3, ig = b & 7;
    const int c = threadIdx.x;
    const float sc = scale1[c], sh = shift1[c];
    float mx = -FLT_MAX, sm = 0.f, sq = 0.f;
    for (int i = ig * 64; i < ig * 64 + 64; ++i) {
        const int idx = (g << 9) + i;
        const int srow = perm[idx];
        const float val = vals[idx];
        const float hv = HG[(size_t)srow * HID + c];
        const float xn = (hv * sc + sh) * val;
        H1P[(size_t)idx * HID + c] = xn;
        mx = fmaxf(mx, xn);
        sm += xn;
        sq += xn * xn;
    }
    pmax[b * 256 + c] = mx;
    psum[b * 256 + c] = sm;
    psq[b * 256 + c] = sq;
}

// ---------- pool1 stage 2: reduce 8 partials, x1 readout, bn2 stats ----------
__global__ __launch_bounds__(256) void k_pool1r(const float* __restrict__ pmax,
        const float* __restrict__ psum, const float* __restrict__ psq,
        float* __restrict__ X1, float* __restrict__ stats2) {
    const int g = blockIdx.x, c = threadIdx.x;
    float mx = -FLT_MAX, sm = 0.f, sq = 0.f;
    for (int ig = 0; ig < 8; ++ig) {
        const int o = ((g << 3) + ig) * 256 + c;
        mx = fmaxf(mx, pmax[o]);
        sm += psum[o];
        sq += psq[o];
    }
    X1[g * 512 + c] = mx;
    X1[g * 512 + 256 + c] = sm * (1.f / K1);
    unsafeAtomicAdd(&stats2[c], sm);
    unsafeAtomicAdd(&stats2[HID + c], sq);
}

// ---------- h2in = gelu(bn2(h1p)): fp32 copy + split-bf16 A2 right half ----------
__global__ __launch_bounds__(256) void k_h2in(const float* __restrict__ H1P,
        const float* __restrict__ scale2, const float* __restrict__ shift2,
        unsigned short* __restrict__ A2h, unsigned short* __restrict__ A2l,
        float* __restrict__ H2F) {
    const int total = NN1 * (HID / 4);
    for (int i = blockIdx.x * 256 + threadIdx.x; i < total; i += gridDim.x * 256) {
        const int r = i >> 6, c4 = i & 63;
        const float4 v = reinterpret_cast<const float4*>(H1P)[i];
        const float4 sc = reinterpret_cast<const float4*>(scale2)[c4];
        const float4 sh = reinterpret_cast<const float4*>(shift2)[c4];
        float4 o;
        o.x = gelu_exact(v.x * sc.x + sh.x);
        o.y = gelu_exact(v.y * sc.y + sh.y);
        o.z = gelu_exact(v.z * sc.z + sh.z);
        o.w = gelu_exact(v.w * sc.w + sh.w);
        reinterpret_cast<float4*>(H2F)[i] = o;
        ushort4 h, l;
        split_bf(o.x, h.x, l.x); split_bf(o.y, h.y, l.y);
        split_bf(o.z, h.z, l.z); split_bf(o.w, h.w, l.w);
        const size_t off = (size_t)r * 512 + 256 + (c4 << 2);
        *reinterpret_cast<ushort4*>(&A2h[off]) = h;
        *reinterpret_cast<ushort4*>(&A2l[off]) = l;
    }
}

// ---------- x2 readout ----------
__global__ __launch_bounds__(256) void k_x2(const float* __restrict__ H2,
        const int* __restrict__ perm, const float* __restrict__ vals,
        float* __restrict__ X2) {
    const int g = blockIdx.x, c = threadIdx.x;
    float mx = -FLT_MAX, sm = 0.f;
    for (int i = 0; i < K2; ++i) {
        const int idx = g * K2 + i;
        const int srow = perm[idx];
        const float v = H2[(size_t)srow * HID + c] * vals[idx];
        mx = fmaxf(mx, v);
        sm += v;
    }
    X2[g * 512 + c] = mx;
    X2[g * 512 + 256 + c] = sm * (1.f / K2);
}

// ---------- final linear: out = (x1+x2) @ Wl + bl ----------
__global__ __launch_bounds__(256) void k_final(const float* __restrict__ X1,
        const float* __restrict__ X2, const float* __restrict__ Wl,
        const float* __restrict__ bl, float* __restrict__ out) {
    const int g = blockIdx.x, c = threadIdx.x;
    float acc = bl[c];
    for (int k = 0; k < 512; ++k) {
        const float xv = X1[g * 512 + k] + X2[g * 512 + k];
        acc = fmaf(xv, Wl[k * HID + c], acc);
    }
    out[g * HID + c] = acc;
}

extern "C" void kernel_launch(void* const* d_in, const int* in_sizes, int n_in,
                              void* d_out, int out_size, void* d_ws, size_t ws_size,
                              hipStream_t stream) {
    (void)in_sizes; (void)n_in; (void)out_size; (void)ws_size;
    const float* x       = (const float*)d_in[0];
    const int*   src     = (const int*)  d_in[1];
    const int*   dst     = (const int*)  d_in[2];
    const float* W_rel1  = (const float*)d_in[3];
    const float* b_rel1  = (const float*)d_in[4];
    const float* W_root1 = (const float*)d_in[5];
    const float* g1      = (const float*)d_in[6];
    const float* bt1     = (const float*)d_in[7];
    const float* p1      = (const float*)d_in[8];
    const float* g2      = (const float*)d_in[9];
    const float* bt2     = (const float*)d_in[10];
    const float* W_rel2  = (const float*)d_in[11];
    const float* b_rel2  = (const float*)d_in[12];
    const float* W_root2 = (const float*)d_in[13];
    const float* p2      = (const float*)d_in[14];
    const float* Wl      = (const float*)d_in[15];
    const float* bl      = (const float*)d_in[16];
    float* out = (float*)d_out;

    char* w = (char*)d_ws;
    size_t off = 0;
    auto alloc = [&](size_t bytes) -> void* {
        void* p = w + off;
        off += (bytes + 255) & ~(size_t)255;
        return p;
    };
    unsigned short* A1h = (unsigned short*)alloc((size_t)NN0 * 256 * 2);  // 32 MB
    unsigned short* A1l = (unsigned short*)alloc((size_t)NN0 * 256 * 2);  // 32 MB
    float* HG     = (float*)alloc((size_t)NN0 * 256 * 4);   // 64 MB: gelu(conv1) fp32
    float* H2F    = (float*)alloc((size_t)NN1 * 256 * 4);   // 32 MB: gelu(bn2) fp32
    int*   ROWP   = (int*)  alloc((size_t)GG * (NPG + 1) * 4);
    int*   SSRC   = (int*)  alloc((size_t)NE * 4);
    float* SCORES = (float*)alloc((size_t)NN0 * 4);         // reused for pool2
    int*   PERM1  = (int*)  alloc((size_t)NN1 * 4);
    float* VALS1  = (float*)alloc((size_t)NN1 * 4);
    int*   MAP1   = (int*)  alloc((size_t)NN0 * 4);
    int*   PERM2  = (int*)  alloc((size_t)NN2 * 4);
    float* VALS2  = (float*)alloc((size_t)NN2 * 4);
    float* STATS1 = (float*)alloc(512 * 4);
    float* STATS2 = (float*)alloc(512 * 4);
    float* SCALE1 = (float*)alloc(256 * 4);
    float* SHIFT1 = (float*)alloc(256 * 4);
    float* Q1     = (float*)alloc(256 * 4);
    float* R1     = (float*)alloc(256);
    float* SCALE2 = (float*)alloc(256 * 4);
    float* SHIFT2 = (float*)alloc(256 * 4);
    float* Q2     = (float*)alloc(256 * 4);
    unsigned short* W1Th = (unsigned short*)alloc((size_t)256 * 256 * 2);
    unsigned short* W1Tl = (unsigned short*)alloc((size_t)256 * 256 * 2);
    unsigned short* W2Th = (unsigned short*)alloc((size_t)256 * 512 * 2);
    unsigned short* W2Tl = (unsigned short*)alloc((size_t)256 * 512 * 2);
    float* X1     = (float*)alloc((size_t)GG * 512 * 4);
    float* X2     = (float*)alloc((size_t)GG * 512 * 4);
    float* PMAX   = (float*)alloc((size_t)512 * 256 * 4);
    float* PSUM   = (float*)alloc((size_t)512 * 256 * 4);
    float* PSQ    = (float*)alloc((size_t)512 * 256 * 4);
    // aliases (stream-ordered, producer dead before reuse):
    float* H1P = (float*)A1h;                 // 32 MB: written after gemm1 consumed A1h
    float* H2  = (float*)A1l;                 // 32 MB: gemm2 out, after gemm1
    unsigned short* A2h = (unsigned short*)HG;                   // 32 MB of HG
    unsigned short* A2l = (unsigned short*)(HG + (size_t)NN0 * 128);  // next 32 MB

    hipMemsetAsync(STATS1, 0, 512 * sizeof(float), stream);
    hipMemsetAsync(STATS2, 0, 512 * sizeof(float), stream);
    hipMemsetAsync(MAP1, 0xFF, (size_t)NN0 * sizeof(int), stream);

    k_csr<<<GG, 512, 0, stream>>>(src, dst, ROWP, SSRC);
    k_w1t<<<256, 256, 0, stream>>>(W_rel1, W_root1, W1Th, W1Tl);
    k_w2t<<<512, 256, 0, stream>>>(W_rel2, W_root2, W2Th, W2Tl);
    k_q2norm<<<1, 256, 0, stream>>>(p2, Q2);
    k_agg1<<<8192, 256, 0, stream>>>(x, ROWP, SSRC, A1h, A1l);
    k_gemm3<256, 1><<<dim3(512, 2), 256, 0, stream>>>(A1h, A1l, W1Th, W1Tl,
        b_rel1, HG, STATS1, nullptr, nullptr, NN0);
    k_finalize1<<<1, 256, 0, stream>>>(STATS1, g1, bt1, p1, SCALE1, SHIFT1, Q1, R1);
    k_score<<<NN0 / 4, 256, 0, stream>>>(HG, Q1, R1, SCORES);
    k_topk<NPG, K1, 512><<<GG, 512, 0, stream>>>(SCORES, PERM1, VALS1, MAP1);
    k_pool1p<<<512, 256, 0, stream>>>(HG, PERM1, VALS1, SCALE1, SHIFT1, H1P, PMAX, PSUM, PSQ);
    k_pool1r<<<GG, 256, 0, stream>>>(PMAX, PSUM, PSQ, X1, STATS2);
    k_finalize2<<<1, 256, 0, stream>>>(STATS2, g2, bt2, SCALE2, SHIFT2);
    k_h2in<<<2048, 256, 0, stream>>>(H1P, SCALE2, SHIFT2, A2h, A2l, H2F);
    k_agg2<<<8192, 256, 0, stream>>>(H2F, ROWP, SSRC, PERM1, MAP1, A2h, A2l);
    hipMemsetAsync(SCORES, 0, (size_t)NN1 * sizeof(float), stream);
    k_gemm3<512, 2><<<dim3(256, 2), 256, 0, stream>>>(A2h, A2l, W2Th, W2Tl,
        b_rel2, H2, nullptr, Q2, SCORES, NN1);
    k_topk<K1, K2, 256><<<GG, 256, 0, stream>>>(SCORES, PERM2, VALS2, nullptr);
    k_x2<<<GG, 256, 0, stream>>>(H2, PERM2, VALS2, X2);
    k_final<<<GG, 256, 0, stream>>>(X1, X2, Wl, bl, out);
}

// Round 10
// 349.898 us; speedup vs baseline: 1.0289x; 1.0069x over previous
//
#include <hip/hip_runtime.h>
#include <hip/hip_bf16.h>
#include <float.h>

#define GG    64
#define NPG   1024
#define EPG   8192      // edges per graph
#define NE    524288
#define FIN   128
#define HID   256
#define K1    512
#define K2    256
#define NN0   65536     // GG*NPG
#define NN1   32768     // GG*K1
#define NN2   16384     // GG*K2
#define EPSBN 1e-5f

typedef _Float16 f16x8 __attribute__((ext_vector_type(8)));
typedef _Float16 f16x4 __attribute__((ext_vector_type(4)));
typedef float f32x4 __attribute__((ext_vector_type(4)));

__device__ __forceinline__ float gelu_exact(float v) {
    return 0.5f * v * (1.0f + erff(v * 0.7071067811865476f));
}

// async global->LDS, 16B per lane; lds dest must be wave-uniform base
__device__ __forceinline__ void gld16(const void* g, void* lds) {
    __builtin_amdgcn_global_load_lds(
        (const __attribute__((address_space(1))) unsigned int*)g,
        (__attribute__((address_space(3))) unsigned int*)lds, 16, 0, 0);
}

// ---------- prep: weight transpose to fp16 hi/lo [N][K], q2norm, stats zero ----
// B-lo is pre-scaled by 2048 so it stays in fp16 normal range; epilogue
// divides back. grid 770 x 256.
__global__ __launch_bounds__(256) void k_prep(
        const float* __restrict__ Wrel1, const float* __restrict__ Wroot1,
        const float* __restrict__ Wrel2, const float* __restrict__ Wroot2,
        const float* __restrict__ p2,
        _Float16* __restrict__ W1h, _Float16* __restrict__ W1l,
        _Float16* __restrict__ W2h, _Float16* __restrict__ W2l,
        float* __restrict__ q2, float* __restrict__ stats1,
        float* __restrict__ stats2) {
    const int b = blockIdx.x, tid = threadIdx.x;
    if (b < 256) {                                      // W1: 256n x 256k
        const int i = b * 256 + tid;
        const int n = i >> 8, k = i & 255;
        const float v = (k < FIN) ? Wrel1[k * HID + n] : Wroot1[(k - FIN) * HID + n];
        const _Float16 hi = (_Float16)v;
        W1h[i] = hi;
        W1l[i] = (_Float16)((v - (float)hi) * 2048.0f);
    } else if (b < 768) {                               // W2: 256n x 512k
        const int i = (b - 256) * 256 + tid;
        const int n = i >> 9, k = i & 511;
        const float v = (k < HID) ? Wrel2[k * HID + n] : Wroot2[(k - HID) * HID + n];
        const _Float16 hi = (_Float16)v;
        W2h[i] = hi;
        W2l[i] = (_Float16)((v - (float)hi) * 2048.0f);
    } else if (b == 768) {                              // q2 = p2/||p2||
        __shared__ float red[256];
        const float pv = p2[tid];
        red[tid] = pv * pv;
        __syncthreads();
        for (int s = 128; s > 0; s >>= 1) {
            if (tid < s) red[tid] += red[tid + s];
            __syncthreads();
        }
        q2[tid] = pv * rsqrtf(red[0]);
    } else {                                            // zero BN stats
        stats1[tid] = 0.f; stats1[256 + tid] = 0.f;
        stats2[tid] = 0.f; stats2[256 + tid] = 0.f;
    }
}

// ---------- CSR build: bucket edges by dst, one block per graph ----------
__global__ __launch_bounds__(512) void k_csr(const int* __restrict__ src,
        const int* __restrict__ dst, int* __restrict__ rowp,
        int* __restrict__ ssrc, int* __restrict__ map1) {
    __shared__ int cnt[NPG];
    __shared__ int sa[NPG];
    __shared__ int sb[NPG];
    const int g = blockIdx.x, tid = threadIdx.x;
    const int eb = g * EPG;
    for (int i = g * 512 + tid; i < NN0; i += GG * 512) map1[i] = -1;
    for (int i = tid; i < NPG; i += 512) cnt[i] = 0;
    __syncthreads();
    for (int e = tid; e < EPG; e += 512)
        atomicAdd(&cnt[dst[eb + e] & (NPG - 1)], 1);
    __syncthreads();
    for (int i = tid; i < NPG; i += 512) sa[i] = cnt[i];
    __syncthreads();
    int* cur = sa; int* nxt = sb;
    for (int d = 1; d < NPG; d <<= 1) {                 // inclusive scan
        for (int i = tid; i < NPG; i += 512)
            nxt[i] = cur[i] + ((i >= d) ? cur[i - d] : 0);
        __syncthreads();
        int* t = cur; cur = nxt; nxt = t;
    }
    for (int i = tid; i < NPG; i += 512) {
        const int st = cur[i] - cnt[i];                 // exclusive start
        rowp[g * (NPG + 1) + i] = st;
        cnt[i] = st;                                    // reuse as cursor
    }
    if (tid == 0) rowp[g * (NPG + 1) + NPG] = EPG;
    __syncthreads();
    for (int e = tid; e < EPG; e += 512) {
        const int d = dst[eb + e] & (NPG - 1);
        const int p = atomicAdd(&cnt[d], 1);
        ssrc[eb + p] = src[eb + e] & (NPG - 1);
    }
}

// ---------- agg1: CSR gather-sum + own-row copy, fp16 out ----------
__global__ __launch_bounds__(256) void k_agg1(const float* __restrict__ x,
        const int* __restrict__ rowp, const int* __restrict__ ssrc,
        _Float16* __restrict__ A1) {
    const int b = blockIdx.x;
    const int g = b & 63;
    const int ng = b >> 6;                              // 0..127
    const int tid = threadIdx.x;
    const int ln = tid & 31;                            // col float4 0..31
    const int node = (ng << 3) + (tid >> 5);            // 0..1023
    const int s0 = rowp[g * (NPG + 1) + node];
    const int s1 = rowp[g * (NPG + 1) + node + 1];
    const float4* x4 = reinterpret_cast<const float4*>(x);
    const size_t gb = (size_t)(g << 10) * 32;           // 32 float4 per x row
    const int* sp = ssrc + (size_t)g * EPG;
    float4 acc = make_float4(0.f, 0.f, 0.f, 0.f);
    for (int j = s0; j < s1; ++j) {
        const float4 v = x4[gb + (size_t)sp[j] * 32 + ln];
        acc.x += v.x; acc.y += v.y; acc.z += v.z; acc.w += v.w;
    }
    const size_t rb = ((size_t)((g << 10) + node)) * 256;
    *reinterpret_cast<f16x4*>(&A1[rb + (ln << 2)]) =
        (f16x4){(_Float16)acc.x, (_Float16)acc.y, (_Float16)acc.z, (_Float16)acc.w};
    const float4 xv = x4[gb + (size_t)node * 32 + ln];  // lin_root operand
    *reinterpret_cast<f16x4*>(&A1[rb + 128 + (ln << 2)]) =
        (f16x4){(_Float16)xv.x, (_Float16)xv.y, (_Float16)xv.z, (_Float16)xv.w};
}

// ---------- agg2: reuse layer-1 CSR buckets, fp16 in/out ----------
__global__ __launch_bounds__(256) void k_agg2(const _Float16* __restrict__ A2r,
        const int* __restrict__ rowp, const int* __restrict__ ssrc,
        const int* __restrict__ perm1, const int* __restrict__ map1,
        _Float16* __restrict__ A2w) {
    const int b = blockIdx.x;
    const int g = b & 63;
    const int ng = b >> 6;                              // 0..127
    const int tid = threadIdx.x;
    const int ln = tid & 63;                            // col quad 0..63
    const int ni = (ng << 2) + (tid >> 6);              // new node 0..511
    const int on = perm1[(g << 9) + ni] & (NPG - 1);    // old node id
    const int s0 = rowp[g * (NPG + 1) + on];
    const int s1 = rowp[g * (NPG + 1) + on + 1];
    const int* sp = ssrc + (size_t)g * EPG;
    const int* mp = map1 + ((size_t)g << 10);
    float4 acc = make_float4(0.f, 0.f, 0.f, 0.f);
    for (int j = s0; j < s1; ++j) {
        const int ms = mp[sp[j]];                       // global new id or -1
        if (ms < 0) continue;                           // lane-uniform branch
        const f16x4 v = *reinterpret_cast<const f16x4*>(
            &A2r[(size_t)ms * 512 + 256 + (ln << 2)]);
        acc.x += (float)v[0]; acc.y += (float)v[1];
        acc.z += (float)v[2]; acc.w += (float)v[3];
    }
    *reinterpret_cast<f16x4*>(&A2w[((size_t)((g << 9) + ni)) * 512 + (ln << 2)]) =
        (f16x4){(_Float16)acc.x, (_Float16)acc.y, (_Float16)acc.z, (_Float16)acc.w};
}

// ---------- fp16 2-term MFMA GEMM: C = A @ (Bh + Bl/2048)^T ----------
// A single fp16 plane [M][K]; B hi/lo fp16 [256][K]. 128x128 tile, 4 waves
// 2x2, each wave 64x64 = 4x4 frags of 16x16x32. A double-buffered
// (counted vmcnt keeps A(k+1) in flight); B single-buffered (L2-hot).
// Value-swizzled LDS (global k-chunk = slot ^ ((row>>1)&3)), 0 bank conflicts.
// EPI 0: +bias; 1: +bias, gelu, col sum/sumsq stats; 2: +bias, fused score-dot
// EPI 2 writes RACE-FREE per-(strip,wn) partials: slot = blockIdx.y*2 + wn.
template<int K, int EPI>
__global__ __launch_bounds__(256) void k_gemm3(
        const _Float16* __restrict__ A,
        const _Float16* __restrict__ Bh, const _Float16* __restrict__ Bl,
        const float* __restrict__ bias, float* __restrict__ C,
        float* __restrict__ stats, const float* __restrict__ qv2,
        float* __restrict__ scores, int M) {
    __shared__ _Float16 Ash[2][128 * 32];                // 8 KB per buf
    __shared__ _Float16 Bsh[128 * 32];
    __shared__ _Float16 Bsl[128 * 32];
    __shared__ float csum[128];
    __shared__ float csq[128];
    const int tid = threadIdx.x;
    const int l = tid & 63, w = tid >> 6;
    const int wm = w >> 1, wn = w & 1;
    const int m0 = blockIdx.x * 128, n0 = blockIdx.y * 128;
    const int r16 = l & 15, kg = l >> 4;

    // staging: wave w stages 16-row chunks {2w, 2w+1}; lane row = l>>2,
    // 16B-slot = l&3, global k-chunk = slot ^ ((row>>1)&3)  (value swizzle)
    const int c0r = (w << 5) + (l >> 2);
    const int c1r = c0r + 16;
    const size_t aoff0 = (size_t)(m0 + c0r) * K + (((l & 3) ^ ((c0r >> 1) & 3)) << 3);
    const size_t aoff1 = (size_t)(m0 + c1r) * K + (((l & 3) ^ ((c1r >> 1) & 3)) << 3);
    const size_t boff0 = (size_t)(n0 + c0r) * K + (((l & 3) ^ ((c0r >> 1) & 3)) << 3);
    const size_t boff1 = (size_t)(n0 + c1r) * K + (((l & 3) ^ ((c1r >> 1) & 3)) << 3);
    const int lds0 = (w << 11);
    const int lds1 = (w << 11) + 1024;

    f32x4 accH[4][4] = {};
    f32x4 accL[4][4] = {};

    // prologue: A(0) -> buf 0
    gld16(A + aoff0, (char*)Ash[0] + lds0);
    gld16(A + aoff1, (char*)Ash[0] + lds1);

    for (int k0 = 0; k0 < K; k0 += 32) {
        const int cur = (k0 >> 5) & 1;
        __builtin_amdgcn_sched_barrier(0);
        __builtin_amdgcn_s_barrier();                    // frees Bs + abuf[cur^1]
        __builtin_amdgcn_sched_barrier(0);
        gld16(Bh + boff0 + k0, (char*)Bsh + lds0);
        gld16(Bh + boff1 + k0, (char*)Bsh + lds1);
        gld16(Bl + boff0 + k0, (char*)Bsl + lds0);
        gld16(Bl + boff1 + k0, (char*)Bsl + lds1);
        if (k0 + 32 < K) {
            const int nxt = cur ^ 1;
            gld16(A + aoff0 + k0 + 32, (char*)Ash[nxt] + lds0);
            gld16(A + aoff1 + k0 + 32, (char*)Ash[nxt] + lds1);
            asm volatile("s_waitcnt vmcnt(2)" ::: "memory");  // B(k) landed; A(k+1) in flight
        } else {
            asm volatile("s_waitcnt vmcnt(0)" ::: "memory");
        }
        __builtin_amdgcn_s_barrier();
        __builtin_amdgcn_sched_barrier(0);
        const char* ab = (const char*)Ash[cur];
        f16x8 af[4], bfh[4], bfl[4];
#pragma unroll
        for (int mi = 0; mi < 4; ++mi) {
            const int r = wm * 64 + mi * 16 + r16;
            const int bo = r * 64 + (((kg ^ ((r >> 1) & 3))) << 4);
            af[mi] = *reinterpret_cast<const f16x8*>(ab + bo);
        }
#pragma unroll
        for (int ni = 0; ni < 4; ++ni) {
            const int r = wn * 64 + ni * 16 + r16;
            const int bo = r * 64 + (((kg ^ ((r >> 1) & 3))) << 4);
            bfh[ni] = *reinterpret_cast<const f16x8*>((const char*)Bsh + bo);
            bfl[ni] = *reinterpret_cast<const f16x8*>((const char*)Bsl + bo);
        }
#pragma unroll
        for (int mi = 0; mi < 4; ++mi)
#pragma unroll
            for (int ni = 0; ni < 4; ++ni) {
                accH[mi][ni] = __builtin_amdgcn_mfma_f32_16x16x32_f16(
                    af[mi], bfh[ni], accH[mi][ni], 0, 0, 0);
                accL[mi][ni] = __builtin_amdgcn_mfma_f32_16x16x32_f16(
                    af[mi], bfl[ni], accL[mi][ni], 0, 0, 0);
            }
    }

    if (EPI == 1) {
        if (tid < 128) { csum[tid] = 0.f; csq[tid] = 0.f; }
        __syncthreads();
    }

    float qv[4];
    if (EPI == 2) {
#pragma unroll
        for (int ni = 0; ni < 4; ++ni) qv[ni] = qv2[n0 + wn * 64 + ni * 16 + r16];
    }
    float sA[4] = {0, 0, 0, 0};
    float qA[4] = {0, 0, 0, 0};
    float sp[4][4] = {};
#pragma unroll
    for (int mi = 0; mi < 4; ++mi)
#pragma unroll
        for (int ni = 0; ni < 4; ++ni) {
            const int col = n0 + wn * 64 + ni * 16 + r16;
            const float bc = bias[col];
#pragma unroll
            for (int r = 0; r < 4; ++r) {
                const int row = m0 + wm * 64 + mi * 16 + (kg << 2) + r;
                float t = accH[mi][ni][r] + accL[mi][ni][r] * (1.0f / 2048.0f) + bc;
                if (EPI == 1) {
                    t = gelu_exact(t);
                    sA[ni] += t;
                    qA[ni] += t * t;
                }
                if (EPI == 2) sp[mi][r] += t * qv[ni];
                C[(size_t)row * 256 + col] = t;
            }
        }
    if (EPI == 1) {
#pragma unroll
        for (int ni = 0; ni < 4; ++ni) {
            const int cl = wn * 64 + ni * 16 + r16;
            unsafeAtomicAdd(&csum[cl], sA[ni]);
            unsafeAtomicAdd(&csq[cl], qA[ni]);
        }
        __syncthreads();
        if (tid < 128) {
            unsafeAtomicAdd(&stats[n0 + tid], csum[tid]);
            unsafeAtomicAdd(&stats[HID + n0 + tid], csq[tid]);
        }
    }
    if (EPI == 2) {
        // partial over this (strip, wn)'s 64 cols; unique slot per writer
        const int slot = (int)blockIdx.y * 2 + wn;
#pragma unroll
        for (int mi = 0; mi < 4; ++mi)
#pragma unroll
            for (int r = 0; r < 4; ++r) {
                float s = sp[mi][r];
                s += __shfl_xor(s, 1);
                s += __shfl_xor(s, 2);
                s += __shfl_xor(s, 4);
                s += __shfl_xor(s, 8);
                if (r16 == 0)
                    scores[(size_t)slot * M + m0 + wm * 64 + mi * 16 + (kg << 2) + r] = s;
            }
    }
}

// ---------- BN finalize / score fold ----------
__global__ __launch_bounds__(256) void k_finalize1(const float* __restrict__ stats,
        const float* __restrict__ g1, const float* __restrict__ bt1,
        const float* __restrict__ p1, float* __restrict__ scale,
        float* __restrict__ shift, float* __restrict__ q, float* __restrict__ r) {
    __shared__ float red[256];
    const int c = threadIdx.x;
    const float m = stats[c] * (1.f / NN0);
    const float v = stats[HID + c] * (1.f / NN0) - m * m;
    const float sc = g1[c] * rsqrtf(v + EPSBN);
    const float sh = bt1[c] - m * sc;
    scale[c] = sc;
    shift[c] = sh;
    const float pv = p1[c];
    red[c] = pv * pv;
    __syncthreads();
    for (int s = 128; s > 0; s >>= 1) {
        if (c < s) red[c] += red[c + s];
        __syncthreads();
    }
    const float inv = rsqrtf(red[0]);
    q[c] = sc * pv * inv;
    __syncthreads();
    red[c] = sh * pv * inv;
    __syncthreads();
    for (int s = 128; s > 0; s >>= 1) {
        if (c < s) red[c] += red[c + s];
        __syncthreads();
    }
    if (c == 0) r[0] = red[0];
}

__global__ __launch_bounds__(256) void k_finalize2(const float* __restrict__ stats,
        const float* __restrict__ g2, const float* __restrict__ bt2,
        float* __restrict__ scale, float* __restrict__ shift) {
    const int c = threadIdx.x;
    const float m = stats[c] * (1.f / NN1);
    const float v = stats[HID + c] * (1.f / NN1) - m * m;
    const float sc = g2[c] * rsqrtf(v + EPSBN);
    scale[c] = sc;
    shift[c] = bt2[c] - m * sc;
}

// ---------- scores (layer1): raw dot h.q + r (tanh applied in topk) ----------
__global__ __launch_bounds__(256) void k_score(const float* __restrict__ H,
        const float* __restrict__ q, const float* __restrict__ r,
        float* __restrict__ out) {
    const int node = blockIdx.x * 4 + (threadIdx.x >> 6);
    const int lane = threadIdx.x & 63;
    const float4 h = *reinterpret_cast<const float4*>(H + (size_t)node * HID + (lane << 2));
    const float4 qv = *reinterpret_cast<const float4*>(q + (lane << 2));
    float d = h.x * qv.x + h.y * qv.y + h.z * qv.z + h.w * qv.w;
#pragma unroll
    for (int off = 32; off > 0; off >>= 1) d += __shfl_xor(d, off);
    if (lane == 0) out[node] = d + (r ? r[0] : 0.f);
}

// ---------- per-graph bitonic top-k (sums nparts partials, tanh at load) ----
template<int NN_, int KK_, int NT_>
__global__ __launch_bounds__(NT_) void k_topk(const float* __restrict__ scores,
        int nparts, int pstride, int* __restrict__ perm,
        float* __restrict__ vals, int* __restrict__ mapping) {
    __shared__ float s[NN_];
    __shared__ int id[NN_];
    const int g = blockIdx.x, tid = threadIdx.x;
    for (int i = tid; i < NN_; i += NT_) {
        float raw = 0.f;
        for (int p = 0; p < nparts; ++p)
            raw += scores[(size_t)p * pstride + g * NN_ + i];
        s[i] = tanhf(raw);
        id[i] = i;
    }
    __syncthreads();
    for (int k = 2; k <= NN_; k <<= 1) {
        for (int j = k >> 1; j > 0; j >>= 1) {
            for (int t = tid; t < NN_; t += NT_) {
                const int ixj = t ^ j;
                if (ixj > t) {
                    const bool desc = ((t & k) == 0);
                    const float s1 = s[t], s2 = s[ixj];
                    const int i1 = id[t], i2 = id[ixj];
                    const bool inOrder = (s1 > s2) || (s1 == s2 && i1 < i2);
                    if (inOrder != desc) { s[t] = s2; s[ixj] = s1; id[t] = i2; id[ixj] = i1; }
                }
            }
            __syncthreads();
        }
    }
    for (int i = tid; i < KK_; i += NT_) {
        const int oid = id[i];
        perm[g * KK_ + i] = g * NN_ + oid;
        vals[g * KK_ + i] = s[i];
        if (mapping) mapping[g * NN_ + oid] = g * KK_ + i;
    }
}

// ---------- pool1 apply, stage 1: 512 blocks (g x 8 node-groups) ----------
__global__ __launch_bounds__(256) void k_pool1p(const float* __restrict__ HG,
        const int* __restrict__ perm, const float* __restrict__ vals,
        const float* __restrict__ scale1, const float* __restrict__ shift1,
        float* __restrict__ H1P, float* __restrict__ pmax,
        float* __restrict__ psum, float* __restrict__ psq) {
    const int b = blockIdx.x;
    const int g = b >> 3, ig = b & 7;
    const int c = threadIdx.x;
    const float sc = scale1[c], sh = shift1[c];
    float mx = -FLT_MAX, sm = 0.f, sq = 0.f;
    for (int i = ig * 64; i < ig * 64 + 64; ++i) {
        const int idx = (g << 9) + i;
        const int srow = perm[idx];
        const float val = vals[idx];
        const float hv = HG[(size_t)srow * HID + c];
        const float xn = (hv * sc + sh) * val;
        H1P[(size_t)idx * HID + c] = xn;
        mx = fmaxf(mx, xn);
        sm += xn;
        sq += xn * xn;
    }
    pmax[b * 256 + c] = mx;
    psum[b * 256 + c] = sm;
    psq[b * 256 + c] = sq;
}

// ---------- pool1 stage 2: reduce 8 partials, x1 readout, bn2 stats ----------
__global__ __launch_bounds__(256) void k_pool1r(const float* __restrict__ pmax,
        const float* __restrict__ psum, const float* __restrict__ psq,
        float* __restrict__ X1, float* __restrict__ stats2) {
    const int g = blockIdx.x, c = threadIdx.x;
    float mx = -FLT_MAX, sm = 0.f, sq = 0.f;
    for (int ig = 0; ig < 8; ++ig) {
        const int o = ((g << 3) + ig) * 256 + c;
        mx = fmaxf(mx, pmax[o]);
        sm += psum[o];
        sq += psq[o];
    }
    X1[g * 512 + c] = mx;
    X1[g * 512 + 256 + c] = sm * (1.f / K1);
    unsafeAtomicAdd(&stats2[c], sm);
    unsafeAtomicAdd(&stats2[HID + c], sq);
}

// ---------- h2in = gelu(bn2(h1p)) -> fp16 A2 right half ----------
__global__ __launch_bounds__(256) void k_h2in(const float* __restrict__ H1P,
        const float* __restrict__ scale2, const float* __restrict__ shift2,
        _Float16* __restrict__ A2) {
    const int total = NN1 * (HID / 4);
    for (int i = blockIdx.x * 256 + threadIdx.x; i < total; i += gridDim.x * 256) {
        const int r = i >> 6, c4 = i & 63;
        const float4 v = reinterpret_cast<const float4*>(H1P)[i];
        const float4 sc = reinterpret_cast<const float4*>(scale2)[c4];
        const float4 sh = reinterpret_cast<const float4*>(shift2)[c4];
        *reinterpret_cast<f16x4*>(&A2[(size_t)r * 512 + 256 + (c4 << 2)]) =
            (f16x4){(_Float16)gelu_exact(v.x * sc.x + sh.x),
                    (_Float16)gelu_exact(v.y * sc.y + sh.y),
                    (_Float16)gelu_exact(v.z * sc.z + sh.z),
                    (_Float16)gelu_exact(v.w * sc.w + sh.w)};
    }
}

// ---------- x2 readout ----------
__global__ __launch_bounds__(256) void k_x2(const float* __restrict__ H2,
        const int* __restrict__ perm, const float* __restrict__ vals,
        float* __restrict__ X2) {
    const int g = blockIdx.x, c = threadIdx.x;
    float mx = -FLT_MAX, sm = 0.f;
    for (int i = 0; i < K2; ++i) {
        const int idx = g * K2 + i;
        const int srow = perm[idx];
        const float v = H2[(size_t)srow * HID + c] * vals[idx];
        mx = fmaxf(mx, v);
        sm += v;
    }
    X2[g * 512 + c] = mx;
    X2[g * 512 + 256 + c] = sm * (1.f / K2);
}

// ---------- final linear: out = (x1+x2) @ Wl + bl ----------
__global__ __launch_bounds__(256) void k_final(const float* __restrict__ X1,
        const float* __restrict__ X2, const float* __restrict__ Wl,
        const float* __restrict__ bl, float* __restrict__ out) {
    const int g = blockIdx.x, c = threadIdx.x;
    float acc = bl[c];
    for (int k = 0; k < 512; ++k) {
        const float xv = X1[g * 512 + k] + X2[g * 512 + k];
        acc = fmaf(xv, Wl[k * HID + c], acc);
    }
    out[g * HID + c] = acc;
}

extern "C" void kernel_launch(void* const* d_in, const int* in_sizes, int n_in,
                              void* d_out, int out_size, void* d_ws, size_t ws_size,
                              hipStream_t stream) {
    (void)in_sizes; (void)n_in; (void)out_size; (void)ws_size;
    const float* x       = (const float*)d_in[0];
    const int*   src     = (const int*)  d_in[1];
    const int*   dst     = (const int*)  d_in[2];
    const float* W_rel1  = (const float*)d_in[3];
    const float* b_rel1  = (const float*)d_in[4];
    const float* W_root1 = (const float*)d_in[5];
    const float* g1      = (const float*)d_in[6];
    const float* bt1     = (const float*)d_in[7];
    const float* p1      = (const float*)d_in[8];
    const float* g2      = (const float*)d_in[9];
    const float* bt2     = (const float*)d_in[10];
    const float* W_rel2  = (const float*)d_in[11];
    const float* b_rel2  = (const float*)d_in[12];
    const float* W_root2 = (const float*)d_in[13];
    const float* p2      = (const float*)d_in[14];
    const float* Wl      = (const float*)d_in[15];
    const float* bl      = (const float*)d_in[16];
    float* out = (float*)d_out;

    char* w = (char*)d_ws;
    size_t off = 0;
    auto alloc = [&](size_t bytes) -> void* {
        void* p = w + off;
        off += (bytes + 255) & ~(size_t)255;
        return p;
    };
    _Float16* A1  = (_Float16*)alloc((size_t)NN0 * 256 * 2);  // 32 MB: [agg|x] fp16
    float* HG     = (float*)alloc((size_t)NN0 * 256 * 4);     // 64 MB: gelu(conv1) fp32
    int*   ROWP   = (int*)  alloc((size_t)GG * (NPG + 1) * 4);
    int*   SSRC   = (int*)  alloc((size_t)NE * 4);
    float* SCORES = (float*)alloc((size_t)4 * NN1 * 4);       // NN0 for L1 / 4xNN1 partials
    int*   PERM1  = (int*)  alloc((size_t)NN1 * 4);
    float* VALS1  = (float*)alloc((size_t)NN1 * 4);
    int*   MAP1   = (int*)  alloc((size_t)NN0 * 4);
    int*   PERM2  = (int*)  alloc((size_t)NN2 * 4);
    float* VALS2  = (float*)alloc((size_t)NN2 * 4);
    float* STATS1 = (float*)alloc(512 * 4);
    float* STATS2 = (float*)alloc(512 * 4);
    float* SCALE1 = (float*)alloc(256 * 4);
    float* SHIFT1 = (float*)alloc(256 * 4);
    float* Q1     = (float*)alloc(256 * 4);
    float* R1     = (float*)alloc(256);
    float* SCALE2 = (float*)alloc(256 * 4);
    float* SHIFT2 = (float*)alloc(256 * 4);
    float* Q2     = (float*)alloc(256 * 4);
    _Float16* W1h = (_Float16*)alloc((size_t)256 * 256 * 2);
    _Float16* W1l = (_Float16*)alloc((size_t)256 * 256 * 2);
    _Float16* W2h = (_Float16*)alloc((size_t)256 * 512 * 2);
    _Float16* W2l = (_Float16*)alloc((size_t)256 * 512 * 2);
    float* X1     = (float*)alloc((size_t)GG * 512 * 4);
    float* X2     = (float*)alloc((size_t)GG * 512 * 4);
    float* PMAX   = (float*)alloc((size_t)512 * 256 * 4);
    float* PSUM   = (float*)alloc((size_t)512 * 256 * 4);
    float* PSQ    = (float*)alloc((size_t)512 * 256 * 4);
    // aliases (stream-ordered, producer dead before reuse):
    float* H1P = (float*)A1;                          // 32 MB: A1 dead after gemm1
    _Float16* A2 = (_Float16*)HG;                     // 32 MB: HG dead after pool1p
    float* H2 = (float*)(HG + (size_t)NN0 * 128);     // second 32 MB of HG

    k_prep<<<770, 256, 0, stream>>>(W_rel1, W_root1, W_rel2, W_root2, p2,
        W1h, W1l, W2h, W2l, Q2, STATS1, STATS2);
    k_csr<<<GG, 512, 0, stream>>>(src, dst, ROWP, SSRC, MAP1);
    k_agg1<<<8192, 256, 0, stream>>>(x, ROWP, SSRC, A1);
    k_gemm3<256, 1><<<dim3(512, 2), 256, 0, stream>>>(A1, W1h, W1l,
        b_rel1, HG, STATS1, nullptr, nullptr, NN0);
    k_finalize1<<<1, 256, 0, stream>>>(STATS1, g1, bt1, p1, SCALE1, SHIFT1, Q1, R1);
    k_score<<<NN0 / 4, 256, 0, stream>>>(HG, Q1, R1, SCORES);
    k_topk<NPG, K1, 512><<<GG, 512, 0, stream>>>(SCORES, 1, 0, PERM1, VALS1, MAP1);
    k_pool1p<<<512, 256, 0, stream>>>(HG, PERM1, VALS1, SCALE1, SHIFT1, H1P, PMAX, PSUM, PSQ);
    k_pool1r<<<GG, 256, 0, stream>>>(PMAX, PSUM, PSQ, X1, STATS2);
    k_finalize2<<<1, 256, 0, stream>>>(STATS2, g2, bt2, SCALE2, SHIFT2);
    k_h2in<<<2048, 256, 0, stream>>>(H1P, SCALE2, SHIFT2, A2);
    k_agg2<<<8192, 256, 0, stream>>>(A2, ROWP, SSRC, PERM1, MAP1, A2);
    k_gemm3<512, 2><<<dim3(256, 2), 256, 0, stream>>>(A2, W2h, W2l,
        b_rel2, H2, nullptr, Q2, SCORES, NN1);
    k_topk<K1, K2, 256><<<GG, 256, 0, stream>>>(SCORES, 4, NN1, PERM2, VALS2, nullptr);
    k_x2<<<GG, 256, 0, stream>>>(H2, PERM2, VALS2, X2);
    k_final<<<GG, 256, 0, stream>>>(X1, X2, Wl, bl, out);
}

// Round 11
// 300.249 us; speedup vs baseline: 1.1990x; 1.1654x over previous
//
#include <hip/hip_runtime.h>
#include <hip/hip_bf16.h>
#include <float.h>

#define GG    64
#define NPG   1024
#define EPG   8192      // edges per graph
#define NE    524288
#define FIN   128
#define HID   256
#define K1    512
#define K2    256
#define NN0   65536     // GG*NPG
#define NN1   32768     // GG*K1
#define NN2   16384     // GG*K2
#define EPSBN 1e-5f

typedef _Float16 f16x8 __attribute__((ext_vector_type(8)));
typedef _Float16 f16x4 __attribute__((ext_vector_type(4)));
typedef float f32x4 __attribute__((ext_vector_type(4)));

__device__ __forceinline__ float gelu_exact(float v) {
    return 0.5f * v * (1.0f + erff(v * 0.7071067811865476f));
}

// async global->LDS, 16B per lane; lds dest must be wave-uniform base
__device__ __forceinline__ void gld16(const void* g, void* lds) {
    __builtin_amdgcn_global_load_lds(
        (const __attribute__((address_space(1))) unsigned int*)g,
        (__attribute__((address_space(3))) unsigned int*)lds, 16, 0, 0);
}

// ---------- prep: weight transpose to fp16 hi/lo [N][K], q2norm, stats zero ----
// B-lo is pre-scaled by 2048 so it stays in fp16 normal range; epilogue
// divides back. grid 770 x 256.
__global__ __launch_bounds__(256) void k_prep(
        const float* __restrict__ Wrel1, const float* __restrict__ Wroot1,
        const float* __restrict__ Wrel2, const float* __restrict__ Wroot2,
        const float* __restrict__ p2,
        _Float16* __restrict__ W1h, _Float16* __restrict__ W1l,
        _Float16* __restrict__ W2h, _Float16* __restrict__ W2l,
        float* __restrict__ q2, float* __restrict__ stats1,
        float* __restrict__ stats2) {
    const int b = blockIdx.x, tid = threadIdx.x;
    if (b < 256) {                                      // W1: 256n x 256k
        const int i = b * 256 + tid;
        const int n = i >> 8, k = i & 255;
        const float v = (k < FIN) ? Wrel1[k * HID + n] : Wroot1[(k - FIN) * HID + n];
        const _Float16 hi = (_Float16)v;
        W1h[i] = hi;
        W1l[i] = (_Float16)((v - (float)hi) * 2048.0f);
    } else if (b < 768) {                               // W2: 256n x 512k
        const int i = (b - 256) * 256 + tid;
        const int n = i >> 9, k = i & 511;
        const float v = (k < HID) ? Wrel2[k * HID + n] : Wroot2[(k - HID) * HID + n];
        const _Float16 hi = (_Float16)v;
        W2h[i] = hi;
        W2l[i] = (_Float16)((v - (float)hi) * 2048.0f);
    } else if (b == 768) {                              // q2 = p2/||p2||
        __shared__ float red[256];
        const float pv = p2[tid];
        red[tid] = pv * pv;
        __syncthreads();
        for (int s = 128; s > 0; s >>= 1) {
            if (tid < s) red[tid] += red[tid + s];
            __syncthreads();
        }
        q2[tid] = pv * rsqrtf(red[0]);
    } else {                                            // zero BN stats
        stats1[tid] = 0.f; stats1[256 + tid] = 0.f;
        stats2[tid] = 0.f; stats2[256 + tid] = 0.f;
    }
}

// ---------- CSR build: bucket edges by dst, one block per graph ----------
__global__ __launch_bounds__(512) void k_csr(const int* __restrict__ src,
        const int* __restrict__ dst, int* __restrict__ rowp,
        int* __restrict__ ssrc, int* __restrict__ map1) {
    __shared__ int cnt[NPG];
    __shared__ int sa[NPG];
    __shared__ int sb[NPG];
    const int g = blockIdx.x, tid = threadIdx.x;
    const int eb = g * EPG;
    for (int i = g * 512 + tid; i < NN0; i += GG * 512) map1[i] = -1;
    for (int i = tid; i < NPG; i += 512) cnt[i] = 0;
    __syncthreads();
    for (int e = tid; e < EPG; e += 512)
        atomicAdd(&cnt[dst[eb + e] & (NPG - 1)], 1);
    __syncthreads();
    for (int i = tid; i < NPG; i += 512) sa[i] = cnt[i];
    __syncthreads();
    int* cur = sa; int* nxt = sb;
    for (int d = 1; d < NPG; d <<= 1) {                 // inclusive scan
        for (int i = tid; i < NPG; i += 512)
            nxt[i] = cur[i] + ((i >= d) ? cur[i - d] : 0);
        __syncthreads();
        int* t = cur; cur = nxt; nxt = t;
    }
    for (int i = tid; i < NPG; i += 512) {
        const int st = cur[i] - cnt[i];                 // exclusive start
        rowp[g * (NPG + 1) + i] = st;
        cnt[i] = st;                                    // reuse as cursor
    }
    if (tid == 0) rowp[g * (NPG + 1) + NPG] = EPG;
    __syncthreads();
    for (int e = tid; e < EPG; e += 512) {
        const int d = dst[eb + e] & (NPG - 1);
        const int p = atomicAdd(&cnt[d], 1);
        ssrc[eb + p] = src[eb + e] & (NPG - 1);
    }
}

// ---------- agg1: CSR gather-sum + own-row copy, fp16 out ----------
__global__ __launch_bounds__(256) void k_agg1(const float* __restrict__ x,
        const int* __restrict__ rowp, const int* __restrict__ ssrc,
        _Float16* __restrict__ A1) {
    const int b = blockIdx.x;
    const int g = b & 63;
    const int ng = b >> 6;                              // 0..127
    const int tid = threadIdx.x;
    const int ln = tid & 31;                            // col float4 0..31
    const int node = (ng << 3) + (tid >> 5);            // 0..1023
    const int s0 = rowp[g * (NPG + 1) + node];
    const int s1 = rowp[g * (NPG + 1) + node + 1];
    const float4* x4 = reinterpret_cast<const float4*>(x);
    const size_t gb = (size_t)(g << 10) * 32;           // 32 float4 per x row
    const int* sp = ssrc + (size_t)g * EPG;
    float4 acc = make_float4(0.f, 0.f, 0.f, 0.f);
    for (int j = s0; j < s1; ++j) {
        const float4 v = x4[gb + (size_t)sp[j] * 32 + ln];
        acc.x += v.x; acc.y += v.y; acc.z += v.z; acc.w += v.w;
    }
    const size_t rb = ((size_t)((g << 10) + node)) * 256;
    *reinterpret_cast<f16x4*>(&A1[rb + (ln << 2)]) =
        (f16x4){(_Float16)acc.x, (_Float16)acc.y, (_Float16)acc.z, (_Float16)acc.w};
    const float4 xv = x4[gb + (size_t)node * 32 + ln];  // lin_root operand
    *reinterpret_cast<f16x4*>(&A1[rb + 128 + (ln << 2)]) =
        (f16x4){(_Float16)xv.x, (_Float16)xv.y, (_Float16)xv.z, (_Float16)xv.w};
}

// ---------- agg2: reuse layer-1 CSR buckets, fp16 in/out ----------
__global__ __launch_bounds__(256) void k_agg2(const _Float16* __restrict__ A2r,
        const int* __restrict__ rowp, const int* __restrict__ ssrc,
        const int* __restrict__ perm1, const int* __restrict__ map1,
        _Float16* __restrict__ A2w) {
    const int b = blockIdx.x;
    const int g = b & 63;
    const int ng = b >> 6;                              // 0..127
    const int tid = threadIdx.x;
    const int ln = tid & 63;                            // col quad 0..63
    const int ni = (ng << 2) + (tid >> 6);              // new node 0..511
    const int on = perm1[(g << 9) + ni] & (NPG - 1);    // old node id
    const int s0 = rowp[g * (NPG + 1) + on];
    const int s1 = rowp[g * (NPG + 1) + on + 1];
    const int* sp = ssrc + (size_t)g * EPG;
    const int* mp = map1 + ((size_t)g << 10);
    float4 acc = make_float4(0.f, 0.f, 0.f, 0.f);
    for (int j = s0; j < s1; ++j) {
        const int ms = mp[sp[j]];                       // global new id or -1
        if (ms < 0) continue;                           // lane-uniform branch
        const f16x4 v = *reinterpret_cast<const f16x4*>(
            &A2r[(size_t)ms * 512 + 256 + (ln << 2)]);
        acc.x += (float)v[0]; acc.y += (float)v[1];
        acc.z += (float)v[2]; acc.w += (float)v[3];
    }
    *reinterpret_cast<f16x4*>(&A2w[((size_t)((g << 9) + ni)) * 512 + (ln << 2)]) =
        (f16x4){(_Float16)acc.x, (_Float16)acc.y, (_Float16)acc.z, (_Float16)acc.w};
}

// ---------- fp16 2-term MFMA GEMM: C = A @ (Bh + Bl/2048)^T, fp16 C ----------
// 512 threads, 8 waves in 2(M)x4(N) grid; wave tile 64x32 = 4x2 frags of
// 16x16x32 -> accH+accL = 64 VGPR total. A double-buffered (per-wave
// vmcnt(1) keeps A(k+1) in flight across barriers); B single-buffered
// (L2-hot). Value-swizzled LDS, 0 bank conflicts.
// EPI 0: +bias; 1: +bias, gelu, col sum/sumsq stats; 2: +bias, fused score-dot
// EPI 2 writes RACE-FREE per-(strip,wn) partials: slot = blockIdx.y*4 + wn.
template<int K, int EPI>
__global__ __launch_bounds__(512, 4) void k_gemm3(
        const _Float16* __restrict__ A,
        const _Float16* __restrict__ Bh, const _Float16* __restrict__ Bl,
        const float* __restrict__ bias, _Float16* __restrict__ C,
        float* __restrict__ stats, const float* __restrict__ qv2,
        float* __restrict__ scores, int M) {
    __shared__ _Float16 Ash[2][128 * 32];                // 8 KB per buf
    __shared__ _Float16 Bsh[128 * 32];
    __shared__ _Float16 Bsl[128 * 32];
    __shared__ float csum[128];
    __shared__ float csq[128];
    const int tid = threadIdx.x;
    const int l = tid & 63, w = tid >> 6;                // 8 waves
    const int wm = w >> 2, wn = w & 3;                   // 2 x 4 wave grid
    const int m0 = blockIdx.x * 128, n0 = blockIdx.y * 128;
    const int r16 = l & 15, kg = l >> 4;

    // staging: wave w stages rows 16w..16w+15 of each plane (1KB chunk).
    // lane row = l>>2, 16B-slot = l&3, global k-chunk = slot ^ ((row>>1)&3)
    const int srow = (w << 4) + (l >> 2);
    const int swz = ((l & 3) ^ ((srow >> 1) & 3)) << 3;
    const size_t aoff = (size_t)(m0 + srow) * K + swz;
    const size_t boff = (size_t)(n0 + srow) * K + swz;
    const int ldsb = w << 10;                            // 1KB per wave chunk

    f32x4 accH[4][2] = {};
    f32x4 accL[4][2] = {};

    gld16(A + aoff, (char*)Ash[0] + ldsb);               // prologue A(0)

    for (int k0 = 0; k0 < K; k0 += 32) {
        const int cur = (k0 >> 5) & 1;
        __builtin_amdgcn_sched_barrier(0);
        __builtin_amdgcn_s_barrier();                    // frees Bs + abuf[cur^1]
        __builtin_amdgcn_sched_barrier(0);
        gld16(Bh + boff + k0, (char*)Bsh + ldsb);
        gld16(Bl + boff + k0, (char*)Bsl + ldsb);
        if (k0 + 32 < K) {
            gld16(A + aoff + k0 + 32, (char*)Ash[cur ^ 1] + ldsb);
            asm volatile("s_waitcnt vmcnt(1)" ::: "memory");  // A(k),B(k) landed
        } else {
            asm volatile("s_waitcnt vmcnt(0)" ::: "memory");
        }
        __builtin_amdgcn_s_barrier();
        __builtin_amdgcn_sched_barrier(0);
        const char* ab = (const char*)Ash[cur];
        f16x8 af[4], bfh[2], bfl[2];
#pragma unroll
        for (int mi = 0; mi < 4; ++mi) {
            const int r = wm * 64 + mi * 16 + r16;
            const int bo = r * 64 + ((kg ^ ((r >> 1) & 3)) << 4);
            af[mi] = *reinterpret_cast<const f16x8*>(ab + bo);
        }
#pragma unroll
        for (int ni = 0; ni < 2; ++ni) {
            const int r = wn * 32 + ni * 16 + r16;
            const int bo = r * 64 + ((kg ^ ((r >> 1) & 3)) << 4);
            bfh[ni] = *reinterpret_cast<const f16x8*>((const char*)Bsh + bo);
            bfl[ni] = *reinterpret_cast<const f16x8*>((const char*)Bsl + bo);
        }
#pragma unroll
        for (int mi = 0; mi < 4; ++mi)
#pragma unroll
            for (int ni = 0; ni < 2; ++ni) {
                accH[mi][ni] = __builtin_amdgcn_mfma_f32_16x16x32_f16(
                    af[mi], bfh[ni], accH[mi][ni], 0, 0, 0);
                accL[mi][ni] = __builtin_amdgcn_mfma_f32_16x16x32_f16(
                    af[mi], bfl[ni], accL[mi][ni], 0, 0, 0);
            }
    }

    if (EPI == 1) {
        if (tid < 128) { csum[tid] = 0.f; csq[tid] = 0.f; }
        __syncthreads();
    }

    float qv[2];
    if (EPI == 2) {
#pragma unroll
        for (int ni = 0; ni < 2; ++ni) qv[ni] = qv2[n0 + wn * 32 + ni * 16 + r16];
    }
    float sA[2] = {0, 0};
    float qA[2] = {0, 0};
    float sp[4][4] = {};
#pragma unroll
    for (int mi = 0; mi < 4; ++mi)
#pragma unroll
        for (int ni = 0; ni < 2; ++ni) {
            const int col = n0 + wn * 32 + ni * 16 + r16;
            const float bc = bias[col];
#pragma unroll
            for (int r = 0; r < 4; ++r) {
                const int row = m0 + wm * 64 + mi * 16 + (kg << 2) + r;
                float t = accH[mi][ni][r] + accL[mi][ni][r] * (1.0f / 2048.0f) + bc;
                if (EPI == 1) {
                    t = gelu_exact(t);
                    sA[ni] += t;
                    qA[ni] += t * t;
                }
                if (EPI == 2) sp[mi][r] += t * qv[ni];
                C[(size_t)row * 256 + col] = (_Float16)t;
            }
        }
    if (EPI == 1) {
#pragma unroll
        for (int ni = 0; ni < 2; ++ni) {
            const int cl = wn * 32 + ni * 16 + r16;
            unsafeAtomicAdd(&csum[cl], sA[ni]);
            unsafeAtomicAdd(&csq[cl], qA[ni]);
        }
        __syncthreads();
        if (tid < 128) {
            unsafeAtomicAdd(&stats[n0 + tid], csum[tid]);
            unsafeAtomicAdd(&stats[HID + n0 + tid], csq[tid]);
        }
    }
    if (EPI == 2) {
        // partial over this (strip, wn)'s 32 cols; unique slot per writer
        const int slot = (int)blockIdx.y * 4 + wn;
#pragma unroll
        for (int mi = 0; mi < 4; ++mi)
#pragma unroll
            for (int r = 0; r < 4; ++r) {
                float s = sp[mi][r];
                s += __shfl_xor(s, 1);
                s += __shfl_xor(s, 2);
                s += __shfl_xor(s, 4);
                s += __shfl_xor(s, 8);
                if (r16 == 0)
                    scores[(size_t)slot * M + m0 + wm * 64 + mi * 16 + (kg << 2) + r] = s;
            }
    }
}

// ---------- BN finalize / score fold ----------
__global__ __launch_bounds__(256) void k_finalize1(const float* __restrict__ stats,
        const float* __restrict__ g1, const float* __restrict__ bt1,
        const float* __restrict__ p1, float* __restrict__ scale,
        float* __restrict__ shift, float* __restrict__ q, float* __restrict__ r) {
    __shared__ float red[256];
    const int c = threadIdx.x;
    const float m = stats[c] * (1.f / NN0);
    const float v = stats[HID + c] * (1.f / NN0) - m * m;
    const float sc = g1[c] * rsqrtf(v + EPSBN);
    const float sh = bt1[c] - m * sc;
    scale[c] = sc;
    shift[c] = sh;
    const float pv = p1[c];
    red[c] = pv * pv;
    __syncthreads();
    for (int s = 128; s > 0; s >>= 1) {
        if (c < s) red[c] += red[c + s];
        __syncthreads();
    }
    const float inv = rsqrtf(red[0]);
    q[c] = sc * pv * inv;
    __syncthreads();
    red[c] = sh * pv * inv;
    __syncthreads();
    for (int s = 128; s > 0; s >>= 1) {
        if (c < s) red[c] += red[c + s];
        __syncthreads();
    }
    if (c == 0) r[0] = red[0];
}

__global__ __launch_bounds__(256) void k_finalize2(const float* __restrict__ stats,
        const float* __restrict__ g2, const float* __restrict__ bt2,
        float* __restrict__ scale, float* __restrict__ shift) {
    const int c = threadIdx.x;
    const float m = stats[c] * (1.f / NN1);
    const float v = stats[HID + c] * (1.f / NN1) - m * m;
    const float sc = g2[c] * rsqrtf(v + EPSBN);
    scale[c] = sc;
    shift[c] = bt2[c] - m * sc;
}

// ---------- scores (layer1): raw dot h.q + r (tanh applied in topk) ----------
__global__ __launch_bounds__(256) void k_score(const _Float16* __restrict__ H,
        const float* __restrict__ q, const float* __restrict__ r,
        float* __restrict__ out) {
    const int node = blockIdx.x * 4 + (threadIdx.x >> 6);
    const int lane = threadIdx.x & 63;
    const f16x4 h = *reinterpret_cast<const f16x4*>(H + (size_t)node * HID + (lane << 2));
    const float4 qv = *reinterpret_cast<const float4*>(q + (lane << 2));
    float d = (float)h[0] * qv.x + (float)h[1] * qv.y +
              (float)h[2] * qv.z + (float)h[3] * qv.w;
#pragma unroll
    for (int off = 32; off > 0; off >>= 1) d += __shfl_xor(d, off);
    if (lane == 0) out[node] = d + (r ? r[0] : 0.f);
}

// ---------- per-graph bitonic top-k (sums nparts partials, tanh at load) ----
template<int NN_, int KK_, int NT_>
__global__ __launch_bounds__(NT_) void k_topk(const float* __restrict__ scores,
        int nparts, int pstride, int* __restrict__ perm,
        float* __restrict__ vals, int* __restrict__ mapping) {
    __shared__ float s[NN_];
    __shared__ int id[NN_];
    const int g = blockIdx.x, tid = threadIdx.x;
    for (int i = tid; i < NN_; i += NT_) {
        float raw = 0.f;
        for (int p = 0; p < nparts; ++p)
            raw += scores[(size_t)p * pstride + g * NN_ + i];
        s[i] = tanhf(raw);
        id[i] = i;
    }
    __syncthreads();
    for (int k = 2; k <= NN_; k <<= 1) {
        for (int j = k >> 1; j > 0; j >>= 1) {
            for (int t = tid; t < NN_; t += NT_) {
                const int ixj = t ^ j;
                if (ixj > t) {
                    const bool desc = ((t & k) == 0);
                    const float s1 = s[t], s2 = s[ixj];
                    const int i1 = id[t], i2 = id[ixj];
                    const bool inOrder = (s1 > s2) || (s1 == s2 && i1 < i2);
                    if (inOrder != desc) { s[t] = s2; s[ixj] = s1; id[t] = i2; id[ixj] = i1; }
                }
            }
            __syncthreads();
        }
    }
    for (int i = tid; i < KK_; i += NT_) {
        const int oid = id[i];
        perm[g * KK_ + i] = g * NN_ + oid;
        vals[g * KK_ + i] = s[i];
        if (mapping) mapping[g * NN_ + oid] = g * KK_ + i;
    }
}

// ---------- pool1 apply, stage 1: 512 blocks (g x 8 node-groups) ----------
__global__ __launch_bounds__(256) void k_pool1p(const _Float16* __restrict__ HG,
        const int* __restrict__ perm, const float* __restrict__ vals,
        const float* __restrict__ scale1, const float* __restrict__ shift1,
        float* __restrict__ H1P, float* __restrict__ pmax,
        float* __restrict__ psum, float* __restrict__ psq) {
    const int b = blockIdx.x;
    const int g = b >> 3, ig = b & 7;
    const int c = threadIdx.x;
    const float sc = scale1[c], sh = shift1[c];
    float mx = -FLT_MAX, sm = 0.f, sq = 0.f;
    for (int i = ig * 64; i < ig * 64 + 64; ++i) {
        const int idx = (g << 9) + i;
        const int srow = perm[idx];
        const float val = vals[idx];
        const float hv = (float)HG[(size_t)srow * HID + c];
        const float xn = (hv * sc + sh) * val;
        H1P[(size_t)idx * HID + c] = xn;
        mx = fmaxf(mx, xn);
        sm += xn;
        sq += xn * xn;
    }
    pmax[b * 256 + c] = mx;
    psum[b * 256 + c] = sm;
    psq[b * 256 + c] = sq;
}

// ---------- pool1 stage 2: reduce 8 partials, x1 readout, bn2 stats ----------
__global__ __launch_bounds__(256) void k_pool1r(const float* __restrict__ pmax,
        const float* __restrict__ psum, const float* __restrict__ psq,
        float* __restrict__ X1, float* __restrict__ stats2) {
    const int g = blockIdx.x, c = threadIdx.x;
    float mx = -FLT_MAX, sm = 0.f, sq = 0.f;
    for (int ig = 0; ig < 8; ++ig) {
        const int o = ((g << 3) + ig) * 256 + c;
        mx = fmaxf(mx, pmax[o]);
        sm += psum[o];
        sq += psq[o];
    }
    X1[g * 512 + c] = mx;
    X1[g * 512 + 256 + c] = sm * (1.f / K1);
    unsafeAtomicAdd(&stats2[c], sm);
    unsafeAtomicAdd(&stats2[HID + c], sq);
}

// ---------- h2in = gelu(bn2(h1p)) -> fp16 A2 right half ----------
__global__ __launch_bounds__(256) void k_h2in(const float* __restrict__ H1P,
        const float* __restrict__ scale2, const float* __restrict__ shift2,
        _Float16* __restrict__ A2) {
    const int total = NN1 * (HID / 4);
    for (int i = blockIdx.x * 256 + threadIdx.x; i < total; i += gridDim.x * 256) {
        const int r = i >> 6, c4 = i & 63;
        const float4 v = reinterpret_cast<const float4*>(H1P)[i];
        const float4 sc = reinterpret_cast<const float4*>(scale2)[c4];
        const float4 sh = reinterpret_cast<const float4*>(shift2)[c4];
        *reinterpret_cast<f16x4*>(&A2[(size_t)r * 512 + 256 + (c4 << 2)]) =
            (f16x4){(_Float16)gelu_exact(v.x * sc.x + sh.x),
                    (_Float16)gelu_exact(v.y * sc.y + sh.y),
                    (_Float16)gelu_exact(v.z * sc.z + sh.z),
                    (_Float16)gelu_exact(v.w * sc.w + sh.w)};
    }
}

// ---------- x2 readout ----------
__global__ __launch_bounds__(256) void k_x2(const _Float16* __restrict__ H2,
        const int* __restrict__ perm, const float* __restrict__ vals,
        float* __restrict__ X2) {
    const int g = blockIdx.x, c = threadIdx.x;
    float mx = -FLT_MAX, sm = 0.f;
    for (int i = 0; i < K2; ++i) {
        const int idx = g * K2 + i;
        const int srow = perm[idx];
        const float v = (float)H2[(size_t)srow * HID + c] * vals[idx];
        mx = fmaxf(mx, v);
        sm += v;
    }
    X2[g * 512 + c] = mx;
    X2[g * 512 + 256 + c] = sm * (1.f / K2);
}

// ---------- final linear: out = (x1+x2) @ Wl + bl ----------
__global__ __launch_bounds__(256) void k_final(const float* __restrict__ X1,
        const float* __restrict__ X2, const float* __restrict__ Wl,
        const float* __restrict__ bl, float* __restrict__ out) {
    const int g = blockIdx.x, c = threadIdx.x;
    float acc = bl[c];
    for (int k = 0; k < 512; ++k) {
        const float xv = X1[g * 512 + k] + X2[g * 512 + k];
        acc = fmaf(xv, Wl[k * HID + c], acc);
    }
    out[g * HID + c] = acc;
}

extern "C" void kernel_launch(void* const* d_in, const int* in_sizes, int n_in,
                              void* d_out, int out_size, void* d_ws, size_t ws_size,
                              hipStream_t stream) {
    (void)in_sizes; (void)n_in; (void)out_size; (void)ws_size;
    const float* x       = (const float*)d_in[0];
    const int*   src     = (const int*)  d_in[1];
    const int*   dst     = (const int*)  d_in[2];
    const float* W_rel1  = (const float*)d_in[3];
    const float* b_rel1  = (const float*)d_in[4];
    const float* W_root1 = (const float*)d_in[5];
    const float* g1      = (const float*)d_in[6];
    const float* bt1     = (const float*)d_in[7];
    const float* p1      = (const float*)d_in[8];
    const float* g2      = (const float*)d_in[9];
    const float* bt2     = (const float*)d_in[10];
    const float* W_rel2  = (const float*)d_in[11];
    const float* b_rel2  = (const float*)d_in[12];
    const float* W_root2 = (const float*)d_in[13];
    const float* p2      = (const float*)d_in[14];
    const float* Wl      = (const float*)d_in[15];
    const float* bl      = (const float*)d_in[16];
    float* out = (float*)d_out;

    char* w = (char*)d_ws;
    size_t off = 0;
    auto alloc = [&](size_t bytes) -> void* {
        void* p = w + off;
        off += (bytes + 255) & ~(size_t)255;
        return p;
    };
    _Float16* A1  = (_Float16*)alloc((size_t)NN0 * 256 * 2);  // 32 MB: [agg|x] fp16
    _Float16* HG  = (_Float16*)alloc((size_t)NN0 * 256 * 2);  // 32 MB: gelu(conv1) fp16
    _Float16* H2  = (_Float16*)alloc((size_t)NN1 * 256 * 2);  // 16 MB: conv2 out fp16
    int*   ROWP   = (int*)  alloc((size_t)GG * (NPG + 1) * 4);
    int*   SSRC   = (int*)  alloc((size_t)NE * 4);
    float* SCORES = (float*)alloc((size_t)8 * NN1 * 4);       // NN0 L1 / 8xNN1 partials
    int*   PERM1  = (int*)  alloc((size_t)NN1 * 4);
    float* VALS1  = (float*)alloc((size_t)NN1 * 4);
    int*   MAP1   = (int*)  alloc((size_t)NN0 * 4);
    int*   PERM2  = (int*)  alloc((size_t)NN2 * 4);
    float* VALS2  = (float*)alloc((size_t)NN2 * 4);
    float* STATS1 = (float*)alloc(512 * 4);
    float* STATS2 = (float*)alloc(512 * 4);
    float* SCALE1 = (float*)alloc(256 * 4);
    float* SHIFT1 = (float*)alloc(256 * 4);
    float* Q1     = (float*)alloc(256 * 4);
    float* R1     = (float*)alloc(256);
    float* SCALE2 = (float*)alloc(256 * 4);
    float* SHIFT2 = (float*)alloc(256 * 4);
    float* Q2     = (float*)alloc(256 * 4);
    _Float16* W1h = (_Float16*)alloc((size_t)256 * 256 * 2);
    _Float16* W1l = (_Float16*)alloc((size_t)256 * 256 * 2);
    _Float16* W2h = (_Float16*)alloc((size_t)256 * 512 * 2);
    _Float16* W2l = (_Float16*)alloc((size_t)256 * 512 * 2);
    float* X1     = (float*)alloc((size_t)GG * 512 * 4);
    float* X2     = (float*)alloc((size_t)GG * 512 * 4);
    float* PMAX   = (float*)alloc((size_t)512 * 256 * 4);
    float* PSUM   = (float*)alloc((size_t)512 * 256 * 4);
    float* PSQ    = (float*)alloc((size_t)512 * 256 * 4);
    // aliases (stream-ordered, producer dead before reuse):
    float* H1P = (float*)A1;              // 32 MB: A1 dead after gemm1
    _Float16* A2 = HG;                    // 32 MB: HG dead after pool1p

    k_prep<<<770, 256, 0, stream>>>(W_rel1, W_root1, W_rel2, W_root2, p2,
        W1h, W1l, W2h, W2l, Q2, STATS1, STATS2);
    k_csr<<<GG, 512, 0, stream>>>(src, dst, ROWP, SSRC, MAP1);
    k_agg1<<<8192, 256, 0, stream>>>(x, ROWP, SSRC, A1);
    k_gemm3<256, 1><<<dim3(512, 2), 512, 0, stream>>>(A1, W1h, W1l,
        b_rel1, HG, STATS1, nullptr, nullptr, NN0);
    k_finalize1<<<1, 256, 0, stream>>>(STATS1, g1, bt1, p1, SCALE1, SHIFT1, Q1, R1);
    k_score<<<NN0 / 4, 256, 0, stream>>>(HG, Q1, R1, SCORES);
    k_topk<NPG, K1, 512><<<GG, 512, 0, stream>>>(SCORES, 1, 0, PERM1, VALS1, MAP1);
    k_pool1p<<<512, 256, 0, stream>>>(HG, PERM1, VALS1, SCALE1, SHIFT1, H1P, PMAX, PSUM, PSQ);
    k_pool1r<<<GG, 256, 0, stream>>>(PMAX, PSUM, PSQ, X1, STATS2);
    k_finalize2<<<1, 256, 0, stream>>>(STATS2, g2, bt2, SCALE2, SHIFT2);
    k_h2in<<<2048, 256, 0, stream>>>(H1P, SCALE2, SHIFT2, A2);
    k_agg2<<<8192, 256, 0, stream>>>(A2, ROWP, SSRC, PERM1, MAP1, A2);
    k_gemm3<512, 2><<<dim3(256, 2), 512, 0, stream>>>(A2, W2h, W2l,
        b_rel2, H2, nullptr, Q2, SCORES, NN1);
    k_topk<K1, K2, 256><<<GG, 256, 0, stream>>>(SCORES, 8, NN1, PERM2, VALS2, nullptr);
    k_x2<<<GG, 256, 0, stream>>>(H2, PERM2, VALS2, X2);
    k_final<<<GG, 256, 0, stream>>>(X1, X2, Wl, bl, out);
}

// Round 12
// 293.042 us; speedup vs baseline: 1.2285x; 1.0246x over previous
//
#include <hip/hip_runtime.h>
#include <hip/hip_bf16.h>
#include <float.h>

#define GG    64
#define NPG   1024
#define EPG   8192      // edges per graph
#define NE    524288
#define FIN   128
#define HID   256
#define K1    512
#define K2    256
#define NN0   65536     // GG*NPG
#define NN1   32768     // GG*K1
#define NN2   16384     // GG*K2
#define EPSBN 1e-5f

typedef _Float16 f16x8 __attribute__((ext_vector_type(8)));
typedef _Float16 f16x4 __attribute__((ext_vector_type(4)));
typedef float f32x4 __attribute__((ext_vector_type(4)));

__device__ __forceinline__ float gelu_exact(float v) {
    return 0.5f * v * (1.0f + erff(v * 0.7071067811865476f));
}

// async global->LDS, 16B per lane; lds dest must be wave-uniform base
__device__ __forceinline__ void gld16(const void* g, void* lds) {
    __builtin_amdgcn_global_load_lds(
        (const __attribute__((address_space(1))) unsigned int*)g,
        (__attribute__((address_space(3))) unsigned int*)lds, 16, 0, 0);
}

// ---------- prep: weight transpose to fp16 hi/lo [N][K], q2norm, stats zero ----
// B-lo is pre-scaled by 2048 so it stays in fp16 normal range; epilogue
// divides back. grid 770 x 256.
__global__ __launch_bounds__(256) void k_prep(
        const float* __restrict__ Wrel1, const float* __restrict__ Wroot1,
        const float* __restrict__ Wrel2, const float* __restrict__ Wroot2,
        const float* __restrict__ p2,
        _Float16* __restrict__ W1h, _Float16* __restrict__ W1l,
        _Float16* __restrict__ W2h, _Float16* __restrict__ W2l,
        float* __restrict__ q2, float* __restrict__ stats1,
        float* __restrict__ stats2) {
    const int b = blockIdx.x, tid = threadIdx.x;
    if (b < 256) {                                      // W1: 256n x 256k
        const int i = b * 256 + tid;
        const int n = i >> 8, k = i & 255;
        const float v = (k < FIN) ? Wrel1[k * HID + n] : Wroot1[(k - FIN) * HID + n];
        const _Float16 hi = (_Float16)v;
        W1h[i] = hi;
        W1l[i] = (_Float16)((v - (float)hi) * 2048.0f);
    } else if (b < 768) {                               // W2: 256n x 512k
        const int i = (b - 256) * 256 + tid;
        const int n = i >> 9, k = i & 511;
        const float v = (k < HID) ? Wrel2[k * HID + n] : Wroot2[(k - HID) * HID + n];
        const _Float16 hi = (_Float16)v;
        W2h[i] = hi;
        W2l[i] = (_Float16)((v - (float)hi) * 2048.0f);
    } else if (b == 768) {                              // q2 = p2/||p2||
        __shared__ float red[256];
        const float pv = p2[tid];
        red[tid] = pv * pv;
        __syncthreads();
        for (int s = 128; s > 0; s >>= 1) {
            if (tid < s) red[tid] += red[tid + s];
            __syncthreads();
        }
        q2[tid] = pv * rsqrtf(red[0]);
    } else {                                            // zero BN stats
        stats1[tid] = 0.f; stats1[256 + tid] = 0.f;
        stats2[tid] = 0.f; stats2[256 + tid] = 0.f;
    }
}

// ---------- CSR build: bucket edges by dst, one block per graph ----------
__global__ __launch_bounds__(512) void k_csr(const int* __restrict__ src,
        const int* __restrict__ dst, int* __restrict__ rowp,
        int* __restrict__ ssrc, int* __restrict__ map1) {
    __shared__ int cnt[NPG];
    __shared__ int sa[NPG];
    __shared__ int sb[NPG];
    const int g = blockIdx.x, tid = threadIdx.x;
    const int eb = g * EPG;
    for (int i = g * 512 + tid; i < NN0; i += GG * 512) map1[i] = -1;
    for (int i = tid; i < NPG; i += 512) cnt[i] = 0;
    __syncthreads();
    for (int e = tid; e < EPG; e += 512)
        atomicAdd(&cnt[dst[eb + e] & (NPG - 1)], 1);
    __syncthreads();
    for (int i = tid; i < NPG; i += 512) sa[i] = cnt[i];
    __syncthreads();
    int* cur = sa; int* nxt = sb;
    for (int d = 1; d < NPG; d <<= 1) {                 // inclusive scan
        for (int i = tid; i < NPG; i += 512)
            nxt[i] = cur[i] + ((i >= d) ? cur[i - d] : 0);
        __syncthreads();
        int* t = cur; cur = nxt; nxt = t;
    }
    for (int i = tid; i < NPG; i += 512) {
        const int st = cur[i] - cnt[i];                 // exclusive start
        rowp[g * (NPG + 1) + i] = st;
        cnt[i] = st;                                    // reuse as cursor
    }
    if (tid == 0) rowp[g * (NPG + 1) + NPG] = EPG;
    __syncthreads();
    for (int e = tid; e < EPG; e += 512) {
        const int d = dst[eb + e] & (NPG - 1);
        const int p = atomicAdd(&cnt[d], 1);
        ssrc[eb + p] = src[eb + e] & (NPG - 1);
    }
}

// ---------- agg1: CSR gather-sum + own-row copy, fp16 out ----------
__global__ __launch_bounds__(256) void k_agg1(const float* __restrict__ x,
        const int* __restrict__ rowp, const int* __restrict__ ssrc,
        _Float16* __restrict__ A1) {
    const int b = blockIdx.x;
    const int g = b & 63;
    const int ng = b >> 6;                              // 0..127
    const int tid = threadIdx.x;
    const int ln = tid & 31;                            // col float4 0..31
    const int node = (ng << 3) + (tid >> 5);            // 0..1023
    const int s0 = rowp[g * (NPG + 1) + node];
    const int s1 = rowp[g * (NPG + 1) + node + 1];
    const float4* x4 = reinterpret_cast<const float4*>(x);
    const size_t gb = (size_t)(g << 10) * 32;           // 32 float4 per x row
    const int* sp = ssrc + (size_t)g * EPG;
    float4 acc = make_float4(0.f, 0.f, 0.f, 0.f);
    for (int j = s0; j < s1; ++j) {
        const float4 v = x4[gb + (size_t)sp[j] * 32 + ln];
        acc.x += v.x; acc.y += v.y; acc.z += v.z; acc.w += v.w;
    }
    const size_t rb = ((size_t)((g << 10) + node)) * 256;
    *reinterpret_cast<f16x4*>(&A1[rb + (ln << 2)]) =
        (f16x4){(_Float16)acc.x, (_Float16)acc.y, (_Float16)acc.z, (_Float16)acc.w};
    const float4 xv = x4[gb + (size_t)node * 32 + ln];  // lin_root operand
    *reinterpret_cast<f16x4*>(&A1[rb + 128 + (ln << 2)]) =
        (f16x4){(_Float16)xv.x, (_Float16)xv.y, (_Float16)xv.z, (_Float16)xv.w};
}

// ---------- agg2: reuse layer-1 CSR buckets, fp16 in/out ----------
__global__ __launch_bounds__(256) void k_agg2(const _Float16* __restrict__ A2r,
        const int* __restrict__ rowp, const int* __restrict__ ssrc,
        const int* __restrict__ perm1, const int* __restrict__ map1,
        _Float16* __restrict__ A2w) {
    const int b = blockIdx.x;
    const int g = b & 63;
    const int ng = b >> 6;                              // 0..127
    const int tid = threadIdx.x;
    const int ln = tid & 63;                            // col quad 0..63
    const int ni = (ng << 2) + (tid >> 6);              // new node 0..511
    const int on = perm1[(g << 9) + ni] & (NPG - 1);    // old node id
    const int s0 = rowp[g * (NPG + 1) + on];
    const int s1 = rowp[g * (NPG + 1) + on + 1];
    const int* sp = ssrc + (size_t)g * EPG;
    const int* mp = map1 + ((size_t)g << 10);
    float4 acc = make_float4(0.f, 0.f, 0.f, 0.f);
    for (int j = s0; j < s1; ++j) {
        const int ms = mp[sp[j]];                       // global new id or -1
        if (ms < 0) continue;                           // lane-uniform branch
        const f16x4 v = *reinterpret_cast<const f16x4*>(
            &A2r[(size_t)ms * 512 + 256 + (ln << 2)]);
        acc.x += (float)v[0]; acc.y += (float)v[1];
        acc.z += (float)v[2]; acc.w += (float)v[3];
    }
    *reinterpret_cast<f16x4*>(&A2w[((size_t)((g << 9) + ni)) * 512 + (ln << 2)]) =
        (f16x4){(_Float16)acc.x, (_Float16)acc.y, (_Float16)acc.z, (_Float16)acc.w};
}

// ---------- fp16 2-term MFMA GEMM: C = A @ (Bh + Bl/2048)^T, fp16 C ----------
// 512 threads, 8 waves 2(M)x4(N); wave tile 64x32. FULL double-buffer:
// A, Bh, Bl all 2-deep; iter k issues k+1's loads then waits vmcnt(3) --
// only iter-k loads (issued one full K-step earlier) are drained, so NO
// load latency is on the critical path. Value-swizzled LDS, 0 conflicts.
// EPI 0: +bias; 1: +bias, gelu, col sum/sumsq stats; 2: +bias, fused score-dot
// EPI 2 writes RACE-FREE per-(strip,wn) partials: slot = blockIdx.y*4 + wn.
template<int K, int EPI>
__global__ __launch_bounds__(512, 4) void k_gemm3(
        const _Float16* __restrict__ A,
        const _Float16* __restrict__ Bh, const _Float16* __restrict__ Bl,
        const float* __restrict__ bias, _Float16* __restrict__ C,
        float* __restrict__ stats, const float* __restrict__ qv2,
        float* __restrict__ scores, int M) {
    __shared__ _Float16 Ash[2][128 * 32];                // 8 KB per buf
    __shared__ _Float16 Bsh[2][128 * 32];
    __shared__ _Float16 Bsl[2][128 * 32];
    __shared__ float csum[128];
    __shared__ float csq[128];
    const int tid = threadIdx.x;
    const int l = tid & 63, w = tid >> 6;                // 8 waves
    const int wm = w >> 2, wn = w & 3;                   // 2 x 4 wave grid
    const int m0 = blockIdx.x * 128, n0 = blockIdx.y * 128;
    const int r16 = l & 15, kg = l >> 4;

    // staging: wave w stages rows 16w..16w+15 of each plane (1KB chunk).
    // lane row = l>>2, 16B-slot = l&3, global k-chunk = slot ^ ((row>>1)&3)
    const int srow = (w << 4) + (l >> 2);
    const int swz = ((l & 3) ^ ((srow >> 1) & 3)) << 3;
    const size_t aoff = (size_t)(m0 + srow) * K + swz;
    const size_t boff = (size_t)(n0 + srow) * K + swz;
    const int ldsb = w << 10;                            // 1KB per wave chunk

    f32x4 accH[4][2] = {};
    f32x4 accL[4][2] = {};

    // prologue: all three planes of k-step 0 -> buf 0
    gld16(A + aoff, (char*)Ash[0] + ldsb);
    gld16(Bh + boff, (char*)Bsh[0] + ldsb);
    gld16(Bl + boff, (char*)Bsl[0] + ldsb);

    for (int k0 = 0; k0 < K; k0 += 32) {
        const int cur = (k0 >> 5) & 1;
        __builtin_amdgcn_s_barrier();                    // iter k-1 reads of buf[cur^1] done
        if (k0 + 32 < K) {
            const int nxt = cur ^ 1;
            gld16(A + aoff + k0 + 32, (char*)Ash[nxt] + ldsb);
            gld16(Bh + boff + k0 + 32, (char*)Bsh[nxt] + ldsb);
            gld16(Bl + boff + k0 + 32, (char*)Bsl[nxt] + ldsb);
            asm volatile("s_waitcnt vmcnt(3)" ::: "memory");  // iter-k loads landed; k+1 in flight
        } else {
            asm volatile("s_waitcnt vmcnt(0)" ::: "memory");
        }
        __builtin_amdgcn_s_barrier();                    // buf[cur] fully populated
        __builtin_amdgcn_sched_barrier(0);
        const char* ab = (const char*)Ash[cur];
        const char* bbh = (const char*)Bsh[cur];
        const char* bbl = (const char*)Bsl[cur];
        f16x8 af[4], bfh[2], bfl[2];
#pragma unroll
        for (int mi = 0; mi < 4; ++mi) {
            const int r = wm * 64 + mi * 16 + r16;
            const int bo = r * 64 + ((kg ^ ((r >> 1) & 3)) << 4);
            af[mi] = *reinterpret_cast<const f16x8*>(ab + bo);
        }
#pragma unroll
        for (int ni = 0; ni < 2; ++ni) {
            const int r = wn * 32 + ni * 16 + r16;
            const int bo = r * 64 + ((kg ^ ((r >> 1) & 3)) << 4);
            bfh[ni] = *reinterpret_cast<const f16x8*>(bbh + bo);
            bfl[ni] = *reinterpret_cast<const f16x8*>(bbl + bo);
        }
#pragma unroll
        for (int mi = 0; mi < 4; ++mi)
#pragma unroll
            for (int ni = 0; ni < 2; ++ni) {
                accH[mi][ni] = __builtin_amdgcn_mfma_f32_16x16x32_f16(
                    af[mi], bfh[ni], accH[mi][ni], 0, 0, 0);
                accL[mi][ni] = __builtin_amdgcn_mfma_f32_16x16x32_f16(
                    af[mi], bfl[ni], accL[mi][ni], 0, 0, 0);
            }
    }

    if (EPI == 1) {
        if (tid < 128) { csum[tid] = 0.f; csq[tid] = 0.f; }
        __syncthreads();
    }

    float qv[2];
    if (EPI == 2) {
#pragma unroll
        for (int ni = 0; ni < 2; ++ni) qv[ni] = qv2[n0 + wn * 32 + ni * 16 + r16];
    }
    float sA[2] = {0, 0};
    float qA[2] = {0, 0};
    float sp[4][4] = {};
#pragma unroll
    for (int mi = 0; mi < 4; ++mi)
#pragma unroll
        for (int ni = 0; ni < 2; ++ni) {
            const int col = n0 + wn * 32 + ni * 16 + r16;
            const float bc = bias[col];
#pragma unroll
            for (int r = 0; r < 4; ++r) {
                const int row = m0 + wm * 64 + mi * 16 + (kg << 2) + r;
                float t = accH[mi][ni][r] + accL[mi][ni][r] * (1.0f / 2048.0f) + bc;
                if (EPI == 1) {
                    t = gelu_exact(t);
                    sA[ni] += t;
                    qA[ni] += t * t;
                }
                if (EPI == 2) sp[mi][r] += t * qv[ni];
                C[(size_t)row * 256 + col] = (_Float16)t;
            }
        }
    if (EPI == 1) {
#pragma unroll
        for (int ni = 0; ni < 2; ++ni) {
            const int cl = wn * 32 + ni * 16 + r16;
            unsafeAtomicAdd(&csum[cl], sA[ni]);
            unsafeAtomicAdd(&csq[cl], qA[ni]);
        }
        __syncthreads();
        if (tid < 128) {
            unsafeAtomicAdd(&stats[n0 + tid], csum[tid]);
            unsafeAtomicAdd(&stats[HID + n0 + tid], csq[tid]);
        }
    }
    if (EPI == 2) {
        // partial over this (strip, wn)'s 32 cols; unique slot per writer
        const int slot = (int)blockIdx.y * 4 + wn;
#pragma unroll
        for (int mi = 0; mi < 4; ++mi)
#pragma unroll
            for (int r = 0; r < 4; ++r) {
                float s = sp[mi][r];
                s += __shfl_xor(s, 1);
                s += __shfl_xor(s, 2);
                s += __shfl_xor(s, 4);
                s += __shfl_xor(s, 8);
                if (r16 == 0)
                    scores[(size_t)slot * M + m0 + wm * 64 + mi * 16 + (kg << 2) + r] = s;
            }
    }
}

// ---------- BN finalize / score fold ----------
__global__ __launch_bounds__(256) void k_finalize1(const float* __restrict__ stats,
        const float* __restrict__ g1, const float* __restrict__ bt1,
        const float* __restrict__ p1, float* __restrict__ scale,
        float* __restrict__ shift, float* __restrict__ q, float* __restrict__ r) {
    __shared__ float red[256];
    const int c = threadIdx.x;
    const float m = stats[c] * (1.f / NN0);
    const float v = stats[HID + c] * (1.f / NN0) - m * m;
    const float sc = g1[c] * rsqrtf(v + EPSBN);
    const float sh = bt1[c] - m * sc;
    scale[c] = sc;
    shift[c] = sh;
    const float pv = p1[c];
    red[c] = pv * pv;
    __syncthreads();
    for (int s = 128; s > 0; s >>= 1) {
        if (c < s) red[c] += red[c + s];
        __syncthreads();
    }
    const float inv = rsqrtf(red[0]);
    q[c] = sc * pv * inv;
    __syncthreads();
    red[c] = sh * pv * inv;
    __syncthreads();
    for (int s = 128; s > 0; s >>= 1) {
        if (c < s) red[c] += red[c + s];
        __syncthreads();
    }
    if (c == 0) r[0] = red[0];
}

__global__ __launch_bounds__(256) void k_finalize2(const float* __restrict__ stats,
        const float* __restrict__ g2, const float* __restrict__ bt2,
        float* __restrict__ scale, float* __restrict__ shift) {
    const int c = threadIdx.x;
    const float m = stats[c] * (1.f / NN1);
    const float v = stats[HID + c] * (1.f / NN1) - m * m;
    const float sc = g2[c] * rsqrtf(v + EPSBN);
    scale[c] = sc;
    shift[c] = bt2[c] - m * sc;
}

// ---------- scores (layer1): raw dot h.q + r (tanh applied in topk) ----------
__global__ __launch_bounds__(256) void k_score(const _Float16* __restrict__ H,
        const float* __restrict__ q, const float* __restrict__ r,
        float* __restrict__ out) {
    const int node = blockIdx.x * 4 + (threadIdx.x >> 6);
    const int lane = threadIdx.x & 63;
    const f16x4 h = *reinterpret_cast<const f16x4*>(H + (size_t)node * HID + (lane << 2));
    const float4 qv = *reinterpret_cast<const float4*>(q + (lane << 2));
    float d = (float)h[0] * qv.x + (float)h[1] * qv.y +
              (float)h[2] * qv.z + (float)h[3] * qv.w;
#pragma unroll
    for (int off = 32; off > 0; off >>= 1) d += __shfl_xor(d, off);
    if (lane == 0) out[node] = d + (r ? r[0] : 0.f);
}

// ---------- per-graph bitonic top-k (sums nparts partials, tanh at load) ----
template<int NN_, int KK_, int NT_>
__global__ __launch_bounds__(NT_) void k_topk(const float* __restrict__ scores,
        int nparts, int pstride, int* __restrict__ perm,
        float* __restrict__ vals, int* __restrict__ mapping) {
    __shared__ float s[NN_];
    __shared__ int id[NN_];
    const int g = blockIdx.x, tid = threadIdx.x;
    for (int i = tid; i < NN_; i += NT_) {
        float raw = 0.f;
        for (int p = 0; p < nparts; ++p)
            raw += scores[(size_t)p * pstride + g * NN_ + i];
        s[i] = tanhf(raw);
        id[i] = i;
    }
    __syncthreads();
    for (int k = 2; k <= NN_; k <<= 1) {
        for (int j = k >> 1; j > 0; j >>= 1) {
            for (int t = tid; t < NN_; t += NT_) {
                const int ixj = t ^ j;
                if (ixj > t) {
                    const bool desc = ((t & k) == 0);
                    const float s1 = s[t], s2 = s[ixj];
                    const int i1 = id[t], i2 = id[ixj];
                    const bool inOrder = (s1 > s2) || (s1 == s2 && i1 < i2);
                    if (inOrder != desc) { s[t] = s2; s[ixj] = s1; id[t] = i2; id[ixj] = i1; }
                }
            }
            __syncthreads();
        }
    }
    for (int i = tid; i < KK_; i += NT_) {
        const int oid = id[i];
        perm[g * KK_ + i] = g * NN_ + oid;
        vals[g * KK_ + i] = s[i];
        if (mapping) mapping[g * NN_ + oid] = g * KK_ + i;
    }
}

// ---------- pool1 apply, stage 1: 512 blocks (g x 8 node-groups) ----------
__global__ __launch_bounds__(256) void k_pool1p(const _Float16* __restrict__ HG,
        const int* __restrict__ perm, const float* __restrict__ vals,
        const float* __restrict__ scale1, const float* __restrict__ shift1,
        _Float16* __restrict__ H1P, float* __restrict__ pmax,
        float* __restrict__ psum, float* __restrict__ psq) {
    const int b = blockIdx.x;
    const int g = b >> 3, ig = b & 7;
    const int c = threadIdx.x;
    const float sc = scale1[c], sh = shift1[c];
    float mx = -FLT_MAX, sm = 0.f, sq = 0.f;
    for (int i = ig * 64; i < ig * 64 + 64; ++i) {
        const int idx = (g << 9) + i;
        const int srow = perm[idx];
        const float val = vals[idx];
        const float hv = (float)HG[(size_t)srow * HID + c];
        const float xn = (hv * sc + sh) * val;
        H1P[(size_t)idx * HID + c] = (_Float16)xn;
        mx = fmaxf(mx, xn);
        sm += xn;
        sq += xn * xn;
    }
    pmax[b * 256 + c] = mx;
    psum[b * 256 + c] = sm;
    psq[b * 256 + c] = sq;
}

// ---------- pool1 stage 2: reduce 8 partials, x1 readout, bn2 stats ----------
__global__ __launch_bounds__(256) void k_pool1r(const float* __restrict__ pmax,
        const float* __restrict__ psum, const float* __restrict__ psq,
        float* __restrict__ X1, float* __restrict__ stats2) {
    const int g = blockIdx.x, c = threadIdx.x;
    float mx = -FLT_MAX, sm = 0.f, sq = 0.f;
    for (int ig = 0; ig < 8; ++ig) {
        const int o = ((g << 3) + ig) * 256 + c;
        mx = fmaxf(mx, pmax[o]);
        sm += psum[o];
        sq += psq[o];
    }
    X1[g * 512 + c] = mx;
    X1[g * 512 + 256 + c] = sm * (1.f / K1);
    unsafeAtomicAdd(&stats2[c], sm);
    unsafeAtomicAdd(&stats2[HID + c], sq);
}

// ---------- h2in = gelu(bn2(h1p)) -> fp16 A2 right half ----------
__global__ __launch_bounds__(256) void k_h2in(const _Float16* __restrict__ H1P,
        const float* __restrict__ scale2, const float* __restrict__ shift2,
        _Float16* __restrict__ A2) {
    const int total = NN1 * (HID / 4);
    for (int i = blockIdx.x * 256 + threadIdx.x; i < total; i += gridDim.x * 256) {
        const int r = i >> 6, c4 = i & 63;
        const f16x4 v = reinterpret_cast<const f16x4*>(H1P)[i];
        const float4 sc = reinterpret_cast<const float4*>(scale2)[c4];
        const float4 sh = reinterpret_cast<const float4*>(shift2)[c4];
        *reinterpret_cast<f16x4*>(&A2[(size_t)r * 512 + 256 + (c4 << 2)]) =
            (f16x4){(_Float16)gelu_exact((float)v[0] * sc.x + sh.x),
                    (_Float16)gelu_exact((float)v[1] * sc.y + sh.y),
                    (_Float16)gelu_exact((float)v[2] * sc.z + sh.z),
                    (_Float16)gelu_exact((float)v[3] * sc.w + sh.w)};
    }
}

// ---------- x2 readout ----------
__global__ __launch_bounds__(256) void k_x2(const _Float16* __restrict__ H2,
        const int* __restrict__ perm, const float* __restrict__ vals,
        float* __restrict__ X2) {
    const int g = blockIdx.x, c = threadIdx.x;
    float mx = -FLT_MAX, sm = 0.f;
    for (int i = 0; i < K2; ++i) {
        const int idx = g * K2 + i;
        const int srow = perm[idx];
        const float v = (float)H2[(size_t)srow * HID + c] * vals[idx];
        mx = fmaxf(mx, v);
        sm += v;
    }
    X2[g * 512 + c] = mx;
    X2[g * 512 + 256 + c] = sm * (1.f / K2);
}

// ---------- final linear: out = (x1+x2) @ Wl + bl ----------
__global__ __launch_bounds__(256) void k_final(const float* __restrict__ X1,
        const float* __restrict__ X2, const float* __restrict__ Wl,
        const float* __restrict__ bl, float* __restrict__ out) {
    const int g = blockIdx.x, c = threadIdx.x;
    float acc = bl[c];
    for (int k = 0; k < 512; ++k) {
        const float xv = X1[g * 512 + k] + X2[g * 512 + k];
        acc = fmaf(xv, Wl[k * HID + c], acc);
    }
    out[g * HID + c] = acc;
}

extern "C" void kernel_launch(void* const* d_in, const int* in_sizes, int n_in,
                              void* d_out, int out_size, void* d_ws, size_t ws_size,
                              hipStream_t stream) {
    (void)in_sizes; (void)n_in; (void)out_size; (void)ws_size;
    const float* x       = (const float*)d_in[0];
    const int*   src     = (const int*)  d_in[1];
    const int*   dst     = (const int*)  d_in[2];
    const float* W_rel1  = (const float*)d_in[3];
    const float* b_rel1  = (const float*)d_in[4];
    const float* W_root1 = (const float*)d_in[5];
    const float* g1      = (const float*)d_in[6];
    const float* bt1     = (const float*)d_in[7];
    const float* p1      = (const float*)d_in[8];
    const float* g2      = (const float*)d_in[9];
    const float* bt2     = (const float*)d_in[10];
    const float* W_rel2  = (const float*)d_in[11];
    const float* b_rel2  = (const float*)d_in[12];
    const float* W_root2 = (const float*)d_in[13];
    const float* p2      = (const float*)d_in[14];
    const float* Wl      = (const float*)d_in[15];
    const float* bl      = (const float*)d_in[16];
    float* out = (float*)d_out;

    char* w = (char*)d_ws;
    size_t off = 0;
    auto alloc = [&](size_t bytes) -> void* {
        void* p = w + off;
        off += (bytes + 255) & ~(size_t)255;
        return p;
    };
    _Float16* A1  = (_Float16*)alloc((size_t)NN0 * 256 * 2);  // 32 MB: [agg|x] fp16
    _Float16* HG  = (_Float16*)alloc((size_t)NN0 * 256 * 2);  // 32 MB: gelu(conv1) fp16
    _Float16* H2  = (_Float16*)alloc((size_t)NN1 * 256 * 2);  // 16 MB: conv2 out fp16
    int*   ROWP   = (int*)  alloc((size_t)GG * (NPG + 1) * 4);
    int*   SSRC   = (int*)  alloc((size_t)NE * 4);
    float* SCORES = (float*)alloc((size_t)8 * NN1 * 4);       // NN0 L1 / 8xNN1 partials
    int*   PERM1  = (int*)  alloc((size_t)NN1 * 4);
    float* VALS1  = (float*)alloc((size_t)NN1 * 4);
    int*   MAP1   = (int*)  alloc((size_t)NN0 * 4);
    int*   PERM2  = (int*)  alloc((size_t)NN2 * 4);
    float* VALS2  = (float*)alloc((size_t)NN2 * 4);
    float* STATS1 = (float*)alloc(512 * 4);
    float* STATS2 = (float*)alloc(512 * 4);
    float* SCALE1 = (float*)alloc(256 * 4);
    float* SHIFT1 = (float*)alloc(256 * 4);
    float* Q1     = (float*)alloc(256 * 4);
    float* R1     = (float*)alloc(256);
    float* SCALE2 = (float*)alloc(256 * 4);
    float* SHIFT2 = (float*)alloc(256 * 4);
    float* Q2     = (float*)alloc(256 * 4);
    _Float16* W1h = (_Float16*)alloc((size_t)256 * 256 * 2);
    _Float16* W1l = (_Float16*)alloc((size_t)256 * 256 * 2);
    _Float16* W2h = (_Float16*)alloc((size_t)256 * 512 * 2);
    _Float16* W2l = (_Float16*)alloc((size_t)256 * 512 * 2);
    float* X1     = (float*)alloc((size_t)GG * 512 * 4);
    float* X2     = (float*)alloc((size_t)GG * 512 * 4);
    float* PMAX   = (float*)alloc((size_t)512 * 256 * 4);
    float* PSUM   = (float*)alloc((size_t)512 * 256 * 4);
    float* PSQ    = (float*)alloc((size_t)512 * 256 * 4);
    // aliases (stream-ordered, producer dead before reuse):
    _Float16* H1P = A1;                   // A1 dead after gemm1
    _Float16* A2 = HG;                    // HG dead after pool1p

    k_prep<<<770, 256, 0, stream>>>(W_rel1, W_root1, W_rel2, W_root2, p2,
        W1h, W1l, W2h, W2l, Q2, STATS1, STATS2);
    k_csr<<<GG, 512, 0, stream>>>(src, dst, ROWP, SSRC, MAP1);
    k_agg1<<<8192, 256, 0, stream>>>(x, ROWP, SSRC, A1);
    k_gemm3<256, 1><<<dim3(512, 2), 512, 0, stream>>>(A1, W1h, W1l,
        b_rel1, HG, STATS1, nullptr, nullptr, NN0);
    k_finalize1<<<1, 256, 0, stream>>>(STATS1, g1, bt1, p1, SCALE1, SHIFT1, Q1, R1);
    k_score<<<NN0 / 4, 256, 0, stream>>>(HG, Q1, R1, SCORES);
    k_topk<NPG, K1, 512><<<GG, 512, 0, stream>>>(SCORES, 1, 0, PERM1, VALS1, MAP1);
    k_pool1p<<<512, 256, 0, stream>>>(HG, PERM1, VALS1, SCALE1, SHIFT1, H1P, PMAX, PSUM, PSQ);
    k_pool1r<<<GG, 256, 0, stream>>>(PMAX, PSUM, PSQ, X1, STATS2);
    k_finalize2<<<1, 256, 0, stream>>>(STATS2, g2, bt2, SCALE2, SHIFT2);
    k_h2in<<<2048, 256, 0, stream>>>(H1P, SCALE2, SHIFT2, A2);
    k_agg2<<<8192, 256, 0, stream>>>(A2, ROWP, SSRC, PERM1, MAP1, A2);
    k_gemm3<512, 2><<<dim3(256, 2), 512, 0, stream>>>(A2, W2h, W2l,
        b_rel2, H2, nullptr, Q2, SCORES, NN1);
    k_topk<K1, K2, 256><<<GG, 256, 0, stream>>>(SCORES, 8, NN1, PERM2, VALS2, nullptr);
    k_x2<<<GG, 256, 0, stream>>>(H2, PERM2, VALS2, X2);
    k_final<<<GG, 256, 0, stream>>>(X1, X2, Wl, bl, out);
}

// Round 13
// 279.457 us; speedup vs baseline: 1.2882x; 1.0486x over previous
//
#include <hip/hip_runtime.h>
#include <hip/hip_bf16.h>
#include <float.h>

#define GG    64
#define NPG   1024
#define EPG   8192      // edges per graph
#define NE    524288
#define FIN   128
#define HID   256
#define K1    512
#define K2    256
#define NN0   65536     // GG*NPG
#define NN1   32768     // GG*K1
#define NN2   16384     // GG*K2
#define EPSBN 1e-5f

typedef _Float16 f16x8 __attribute__((ext_vector_type(8)));
typedef _Float16 f16x4 __attribute__((ext_vector_type(4)));
typedef float f32x4 __attribute__((ext_vector_type(4)));

__device__ __forceinline__ float gelu_exact(float v) {
    return 0.5f * v * (1.0f + erff(v * 0.7071067811865476f));
}

// async global->LDS, 16B per lane; lds dest must be wave-uniform base
__device__ __forceinline__ void gld16(const void* g, void* lds) {
    __builtin_amdgcn_global_load_lds(
        (const __attribute__((address_space(1))) unsigned int*)g,
        (__attribute__((address_space(3))) unsigned int*)lds, 16, 0, 0);
}

// ---------- prep: weight transpose to fp16 hi/lo [N][K], q2norm, stats zero ----
// B-lo is pre-scaled by 2048 so it stays in fp16 normal range; epilogue
// divides back. grid 770 x 256.
__global__ __launch_bounds__(256) void k_prep(
        const float* __restrict__ Wrel1, const float* __restrict__ Wroot1,
        const float* __restrict__ Wrel2, const float* __restrict__ Wroot2,
        const float* __restrict__ p2,
        _Float16* __restrict__ W1h, _Float16* __restrict__ W1l,
        _Float16* __restrict__ W2h, _Float16* __restrict__ W2l,
        float* __restrict__ q2, float* __restrict__ stats1,
        float* __restrict__ stats2) {
    const int b = blockIdx.x, tid = threadIdx.x;
    if (b < 256) {                                      // W1: 256n x 256k
        const int i = b * 256 + tid;
        const int n = i >> 8, k = i & 255;
        const float v = (k < FIN) ? Wrel1[k * HID + n] : Wroot1[(k - FIN) * HID + n];
        const _Float16 hi = (_Float16)v;
        W1h[i] = hi;
        W1l[i] = (_Float16)((v - (float)hi) * 2048.0f);
    } else if (b < 768) {                               // W2: 256n x 512k
        const int i = (b - 256) * 256 + tid;
        const int n = i >> 9, k = i & 511;
        const float v = (k < HID) ? Wrel2[k * HID + n] : Wroot2[(k - HID) * HID + n];
        const _Float16 hi = (_Float16)v;
        W2h[i] = hi;
        W2l[i] = (_Float16)((v - (float)hi) * 2048.0f);
    } else if (b == 768) {                              // q2 = p2/||p2||
        __shared__ float red[256];
        const float pv = p2[tid];
        red[tid] = pv * pv;
        __syncthreads();
        for (int s = 128; s > 0; s >>= 1) {
            if (tid < s) red[tid] += red[tid + s];
            __syncthreads();
        }
        q2[tid] = pv * rsqrtf(red[0]);
    } else {                                            // zero BN stats
        stats1[tid] = 0.f; stats1[256 + tid] = 0.f;
        stats2[tid] = 0.f; stats2[256 + tid] = 0.f;
    }
}

// ---------- CSR build: bucket edges by dst, one block per graph ----------
__global__ __launch_bounds__(512) void k_csr(const int* __restrict__ src,
        const int* __restrict__ dst, int* __restrict__ rowp,
        int* __restrict__ ssrc, int* __restrict__ map1) {
    __shared__ int cnt[NPG];
    __shared__ int sa[NPG];
    __shared__ int sb[NPG];
    const int g = blockIdx.x, tid = threadIdx.x;
    const int eb = g * EPG;
    for (int i = g * 512 + tid; i < NN0; i += GG * 512) map1[i] = -1;
    for (int i = tid; i < NPG; i += 512) cnt[i] = 0;
    __syncthreads();
    for (int e = tid; e < EPG; e += 512)
        atomicAdd(&cnt[dst[eb + e] & (NPG - 1)], 1);
    __syncthreads();
    for (int i = tid; i < NPG; i += 512) sa[i] = cnt[i];
    __syncthreads();
    int* cur = sa; int* nxt = sb;
    for (int d = 1; d < NPG; d <<= 1) {                 // inclusive scan
        for (int i = tid; i < NPG; i += 512)
            nxt[i] = cur[i] + ((i >= d) ? cur[i - d] : 0);
        __syncthreads();
        int* t = cur; cur = nxt; nxt = t;
    }
    for (int i = tid; i < NPG; i += 512) {
        const int st = cur[i] - cnt[i];                 // exclusive start
        rowp[g * (NPG + 1) + i] = st;
        cnt[i] = st;                                    // reuse as cursor
    }
    if (tid == 0) rowp[g * (NPG + 1) + NPG] = EPG;
    __syncthreads();
    for (int e = tid; e < EPG; e += 512) {
        const int d = dst[eb + e] & (NPG - 1);
        const int p = atomicAdd(&cnt[d], 1);
        ssrc[eb + p] = src[eb + e] & (NPG - 1);
    }
}

// ---------- agg1: CSR gather-sum + own-row copy, fp16 out ----------
__global__ __launch_bounds__(256) void k_agg1(const float* __restrict__ x,
        const int* __restrict__ rowp, const int* __restrict__ ssrc,
        _Float16* __restrict__ A1) {
    const int b = blockIdx.x;
    const int g = b & 63;
    const int ng = b >> 6;                              // 0..127
    const int tid = threadIdx.x;
    const int ln = tid & 31;                            // col float4 0..31
    const int node = (ng << 3) + (tid >> 5);            // 0..1023
    const int s0 = rowp[g * (NPG + 1) + node];
    const int s1 = rowp[g * (NPG + 1) + node + 1];
    const float4* x4 = reinterpret_cast<const float4*>(x);
    const size_t gb = (size_t)(g << 10) * 32;           // 32 float4 per x row
    const int* sp = ssrc + (size_t)g * EPG;
    float4 acc = make_float4(0.f, 0.f, 0.f, 0.f);
    for (int j = s0; j < s1; ++j) {
        const float4 v = x4[gb + (size_t)sp[j] * 32 + ln];
        acc.x += v.x; acc.y += v.y; acc.z += v.z; acc.w += v.w;
    }
    const size_t rb = ((size_t)((g << 10) + node)) * 256;
    *reinterpret_cast<f16x4*>(&A1[rb + (ln << 2)]) =
        (f16x4){(_Float16)acc.x, (_Float16)acc.y, (_Float16)acc.z, (_Float16)acc.w};
    const float4 xv = x4[gb + (size_t)node * 32 + ln];  // lin_root operand
    *reinterpret_cast<f16x4*>(&A1[rb + 128 + (ln << 2)]) =
        (f16x4){(_Float16)xv.x, (_Float16)xv.y, (_Float16)xv.z, (_Float16)xv.w};
}

// ---------- agg2: reuse layer-1 CSR buckets, fp16 in/out ----------
__global__ __launch_bounds__(256) void k_agg2(const _Float16* __restrict__ A2r,
        const int* __restrict__ rowp, const int* __restrict__ ssrc,
        const int* __restrict__ perm1, const int* __restrict__ map1,
        _Float16* __restrict__ A2w) {
    const int b = blockIdx.x;
    const int g = b & 63;
    const int ng = b >> 6;                              // 0..127
    const int tid = threadIdx.x;
    const int ln = tid & 63;                            // col quad 0..63
    const int ni = (ng << 2) + (tid >> 6);              // new node 0..511
    const int on = perm1[(g << 9) + ni] & (NPG - 1);    // old node id
    const int s0 = rowp[g * (NPG + 1) + on];
    const int s1 = rowp[g * (NPG + 1) + on + 1];
    const int* sp = ssrc + (size_t)g * EPG;
    const int* mp = map1 + ((size_t)g << 10);
    float4 acc = make_float4(0.f, 0.f, 0.f, 0.f);
    for (int j = s0; j < s1; ++j) {
        const int ms = mp[sp[j]];                       // global new id or -1
        if (ms < 0) continue;                           // lane-uniform branch
        const f16x4 v = *reinterpret_cast<const f16x4*>(
            &A2r[(size_t)ms * 512 + 256 + (ln << 2)]);
        acc.x += (float)v[0]; acc.y += (float)v[1];
        acc.z += (float)v[2]; acc.w += (float)v[3];
    }
    *reinterpret_cast<f16x4*>(&A2w[((size_t)((g << 9) + ni)) * 512 + (ln << 2)]) =
        (f16x4){(_Float16)acc.x, (_Float16)acc.y, (_Float16)acc.z, (_Float16)acc.w};
}

// ---------- fp16 2-term MFMA GEMM: C = A @ (Bh + Bl/2048)^T, fp16 C ----------
// 512 threads, 8 waves 2(M)x4(N); wave tile 64x32. DEPTH-3 pipeline:
// A, Bh, Bl all 3-deep; iter i issues set(i+2) then waits vmcnt(6) -- the
// consumed set was issued TWO iterations (~1200cy) earlier, exceeding the
// ~900cy HBM latency, so no load latency on the critical path (T4 formula).
// Value-swizzled LDS, 0 bank conflicts.
// EPI 0: +bias; 1: +bias, gelu, col sum/sumsq stats; 2: +bias, fused score-dot
// EPI 2 writes RACE-FREE per-(strip,wn) partials: slot = blockIdx.y*4 + wn.
template<int K, int EPI>
__global__ __launch_bounds__(512, 4) void k_gemm3(
        const _Float16* __restrict__ A,
        const _Float16* __restrict__ Bh, const _Float16* __restrict__ Bl,
        const float* __restrict__ bias, _Float16* __restrict__ C,
        float* __restrict__ stats, const float* __restrict__ qv2,
        float* __restrict__ scores, int M) {
    __shared__ _Float16 Ash[3][128 * 32];                // 8 KB per buf
    __shared__ _Float16 Bsh[3][128 * 32];
    __shared__ _Float16 Bsl[3][128 * 32];
    __shared__ float csum[128];
    __shared__ float csq[128];
    const int tid = threadIdx.x;
    const int l = tid & 63, w = tid >> 6;                // 8 waves
    const int wm = w >> 2, wn = w & 3;                   // 2 x 4 wave grid
    const int m0 = blockIdx.x * 128, n0 = blockIdx.y * 128;
    const int r16 = l & 15, kg = l >> 4;

    // staging: wave w stages rows 16w..16w+15 of each plane (1KB chunk).
    // lane row = l>>2, 16B-slot = l&3, global k-chunk = slot ^ ((row>>1)&3)
    const int srow = (w << 4) + (l >> 2);
    const int swz = ((l & 3) ^ ((srow >> 1) & 3)) << 3;
    const size_t aoff = (size_t)(m0 + srow) * K + swz;
    const size_t boff = (size_t)(n0 + srow) * K + swz;
    const int ldsb = w << 10;                            // 1KB per wave chunk

    f32x4 accH[4][2] = {};
    f32x4 accL[4][2] = {};

    constexpr int NI = K / 32;
    // prologue: sets 0 and 1 in flight
    gld16(A + aoff, (char*)Ash[0] + ldsb);
    gld16(Bh + boff, (char*)Bsh[0] + ldsb);
    gld16(Bl + boff, (char*)Bsl[0] + ldsb);
    gld16(A + aoff + 32, (char*)Ash[1] + ldsb);
    gld16(Bh + boff + 32, (char*)Bsh[1] + ldsb);
    gld16(Bl + boff + 32, (char*)Bsl[1] + ldsb);

#pragma unroll
    for (int i = 0; i < NI; ++i) {
        const int k0 = i * 32;
        const int cur = i % 3;
        __builtin_amdgcn_s_barrier();                    // iter i-1 reads done
        if (i + 2 < NI) {
            const int nxt = (i + 2) % 3;
            gld16(A + aoff + k0 + 64, (char*)Ash[nxt] + ldsb);
            gld16(Bh + boff + k0 + 64, (char*)Bsh[nxt] + ldsb);
            gld16(Bl + boff + k0 + 64, (char*)Bsl[nxt] + ldsb);
            asm volatile("s_waitcnt vmcnt(6)" ::: "memory");  // set(i) landed
        } else if (i + 1 < NI) {
            asm volatile("s_waitcnt vmcnt(3)" ::: "memory");
        } else {
            asm volatile("s_waitcnt vmcnt(0)" ::: "memory");
        }
        __builtin_amdgcn_s_barrier();                    // buf[cur] ready for all
        __builtin_amdgcn_sched_barrier(0);
        const char* ab = (const char*)Ash[cur];
        const char* bbh = (const char*)Bsh[cur];
        const char* bbl = (const char*)Bsl[cur];
        f16x8 af[4], bfh[2], bfl[2];
#pragma unroll
        for (int mi = 0; mi < 4; ++mi) {
            const int r = wm * 64 + mi * 16 + r16;
            const int bo = r * 64 + ((kg ^ ((r >> 1) & 3)) << 4);
            af[mi] = *reinterpret_cast<const f16x8*>(ab + bo);
        }
#pragma unroll
        for (int ni = 0; ni < 2; ++ni) {
            const int r = wn * 32 + ni * 16 + r16;
            const int bo = r * 64 + ((kg ^ ((r >> 1) & 3)) << 4);
            bfh[ni] = *reinterpret_cast<const f16x8*>(bbh + bo);
            bfl[ni] = *reinterpret_cast<const f16x8*>(bbl + bo);
        }
#pragma unroll
        for (int mi = 0; mi < 4; ++mi)
#pragma unroll
            for (int ni = 0; ni < 2; ++ni) {
                accH[mi][ni] = __builtin_amdgcn_mfma_f32_16x16x32_f16(
                    af[mi], bfh[ni], accH[mi][ni], 0, 0, 0);
                accL[mi][ni] = __builtin_amdgcn_mfma_f32_16x16x32_f16(
                    af[mi], bfl[ni], accL[mi][ni], 0, 0, 0);
            }
    }

    if (EPI == 1) {
        if (tid < 128) { csum[tid] = 0.f; csq[tid] = 0.f; }
        __syncthreads();
    }

    float qv[2];
    if (EPI == 2) {
#pragma unroll
        for (int ni = 0; ni < 2; ++ni) qv[ni] = qv2[n0 + wn * 32 + ni * 16 + r16];
    }
    float sA[2] = {0, 0};
    float qA[2] = {0, 0};
    float sp[4][4] = {};
#pragma unroll
    for (int mi = 0; mi < 4; ++mi)
#pragma unroll
        for (int ni = 0; ni < 2; ++ni) {
            const int col = n0 + wn * 32 + ni * 16 + r16;
            const float bc = bias[col];
#pragma unroll
            for (int r = 0; r < 4; ++r) {
                const int row = m0 + wm * 64 + mi * 16 + (kg << 2) + r;
                float t = accH[mi][ni][r] + accL[mi][ni][r] * (1.0f / 2048.0f) + bc;
                if (EPI == 1) {
                    t = gelu_exact(t);
                    sA[ni] += t;
                    qA[ni] += t * t;
                }
                if (EPI == 2) sp[mi][r] += t * qv[ni];
                C[(size_t)row * 256 + col] = (_Float16)t;
            }
        }
    if (EPI == 1) {
#pragma unroll
        for (int ni = 0; ni < 2; ++ni) {
            const int cl = wn * 32 + ni * 16 + r16;
            unsafeAtomicAdd(&csum[cl], sA[ni]);
            unsafeAtomicAdd(&csq[cl], qA[ni]);
        }
        __syncthreads();
        if (tid < 128) {
            unsafeAtomicAdd(&stats[n0 + tid], csum[tid]);
            unsafeAtomicAdd(&stats[HID + n0 + tid], csq[tid]);
        }
    }
    if (EPI == 2) {
        // partial over this (strip, wn)'s 32 cols; unique slot per writer
        const int slot = (int)blockIdx.y * 4 + wn;
#pragma unroll
        for (int mi = 0; mi < 4; ++mi)
#pragma unroll
            for (int r = 0; r < 4; ++r) {
                float s = sp[mi][r];
                s += __shfl_xor(s, 1);
                s += __shfl_xor(s, 2);
                s += __shfl_xor(s, 4);
                s += __shfl_xor(s, 8);
                if (r16 == 0)
                    scores[(size_t)slot * M + m0 + wm * 64 + mi * 16 + (kg << 2) + r] = s;
            }
    }
}

// ---------- BN finalize / score fold ----------
__global__ __launch_bounds__(256) void k_finalize1(const float* __restrict__ stats,
        const float* __restrict__ g1, const float* __restrict__ bt1,
        const float* __restrict__ p1, float* __restrict__ scale,
        float* __restrict__ shift, float* __restrict__ q, float* __restrict__ r) {
    __shared__ float red[256];
    const int c = threadIdx.x;
    const float m = stats[c] * (1.f / NN0);
    const float v = stats[HID + c] * (1.f / NN0) - m * m;
    const float sc = g1[c] * rsqrtf(v + EPSBN);
    const float sh = bt1[c] - m * sc;
    scale[c] = sc;
    shift[c] = sh;
    const float pv = p1[c];
    red[c] = pv * pv;
    __syncthreads();
    for (int s = 128; s > 0; s >>= 1) {
        if (c < s) red[c] += red[c + s];
        __syncthreads();
    }
    const float inv = rsqrtf(red[0]);
    q[c] = sc * pv * inv;
    __syncthreads();
    red[c] = sh * pv * inv;
    __syncthreads();
    for (int s = 128; s > 0; s >>= 1) {
        if (c < s) red[c] += red[c + s];
        __syncthreads();
    }
    if (c == 0) r[0] = red[0];
}

__global__ __launch_bounds__(256) void k_finalize2(const float* __restrict__ stats,
        const float* __restrict__ g2, const float* __restrict__ bt2,
        float* __restrict__ scale, float* __restrict__ shift) {
    const int c = threadIdx.x;
    const float m = stats[c] * (1.f / NN1);
    const float v = stats[HID + c] * (1.f / NN1) - m * m;
    const float sc = g2[c] * rsqrtf(v + EPSBN);
    scale[c] = sc;
    shift[c] = bt2[c] - m * sc;
}

// ---------- scores (layer1): raw dot h.q + r (tanh applied in topk) ----------
__global__ __launch_bounds__(256) void k_score(const _Float16* __restrict__ H,
        const float* __restrict__ q, const float* __restrict__ r,
        float* __restrict__ out) {
    const int node = blockIdx.x * 4 + (threadIdx.x >> 6);
    const int lane = threadIdx.x & 63;
    const f16x4 h = *reinterpret_cast<const f16x4*>(H + (size_t)node * HID + (lane << 2));
    const float4 qv = *reinterpret_cast<const float4*>(q + (lane << 2));
    float d = (float)h[0] * qv.x + (float)h[1] * qv.y +
              (float)h[2] * qv.z + (float)h[3] * qv.w;
#pragma unroll
    for (int off = 32; off > 0; off >>= 1) d += __shfl_xor(d, off);
    if (lane == 0) out[node] = d + (r ? r[0] : 0.f);
}

// ---------- per-graph bitonic top-k (sums nparts partials, tanh at load) ----
template<int NN_, int KK_, int NT_>
__global__ __launch_bounds__(NT_) void k_topk(const float* __restrict__ scores,
        int nparts, int pstride, int* __restrict__ perm,
        float* __restrict__ vals, int* __restrict__ mapping) {
    __shared__ float s[NN_];
    __shared__ int id[NN_];
    const int g = blockIdx.x, tid = threadIdx.x;
    for (int i = tid; i < NN_; i += NT_) {
        float raw = 0.f;
        for (int p = 0; p < nparts; ++p)
            raw += scores[(size_t)p * pstride + g * NN_ + i];
        s[i] = tanhf(raw);
        id[i] = i;
    }
    __syncthreads();
    for (int k = 2; k <= NN_; k <<= 1) {
        for (int j = k >> 1; j > 0; j >>= 1) {
            for (int t = tid; t < NN_; t += NT_) {
                const int ixj = t ^ j;
                if (ixj > t) {
                    const bool desc = ((t & k) == 0);
                    const float s1 = s[t], s2 = s[ixj];
                    const int i1 = id[t], i2 = id[ixj];
                    const bool inOrder = (s1 > s2) || (s1 == s2 && i1 < i2);
                    if (inOrder != desc) { s[t] = s2; s[ixj] = s1; id[t] = i2; id[ixj] = i1; }
                }
            }
            __syncthreads();
        }
    }
    for (int i = tid; i < KK_; i += NT_) {
        const int oid = id[i];
        perm[g * KK_ + i] = g * NN_ + oid;
        vals[g * KK_ + i] = s[i];
        if (mapping) mapping[g * NN_ + oid] = g * KK_ + i;
    }
}

// ---------- pool1 apply, stage 1: 512 blocks (g x 8 node-groups) ----------
__global__ __launch_bounds__(256) void k_pool1p(const _Float16* __restrict__ HG,
        const int* __restrict__ perm, const float* __restrict__ vals,
        const float* __restrict__ scale1, const float* __restrict__ shift1,
        _Float16* __restrict__ H1P, float* __restrict__ pmax,
        float* __restrict__ psum, float* __restrict__ psq) {
    const int b = blockIdx.x;
    const int g = b >> 3, ig = b & 7;
    const int c = threadIdx.x;
    const float sc = scale1[c], sh = shift1[c];
    float mx = -FLT_MAX, sm = 0.f, sq = 0.f;
    for (int i = ig * 64; i < ig * 64 + 64; ++i) {
        const int idx = (g << 9) + i;
        const int srow = perm[idx];
        const float val = vals[idx];
        const float hv = (float)HG[(size_t)srow * HID + c];
        const float xn = (hv * sc + sh) * val;
        H1P[(size_t)idx * HID + c] = (_Float16)xn;
        mx = fmaxf(mx, xn);
        sm += xn;
        sq += xn * xn;
    }
    pmax[b * 256 + c] = mx;
    psum[b * 256 + c] = sm;
    psq[b * 256 + c] = sq;
}

// ---------- pool1 stage 2: reduce 8 partials, x1 readout, bn2 stats ----------
__global__ __launch_bounds__(256) void k_pool1r(const float* __restrict__ pmax,
        const float* __restrict__ psum, const float* __restrict__ psq,
        float* __restrict__ X1, float* __restrict__ stats2) {
    const int g = blockIdx.x, c = threadIdx.x;
    float mx = -FLT_MAX, sm = 0.f, sq = 0.f;
    for (int ig = 0; ig < 8; ++ig) {
        const int o = ((g << 3) + ig) * 256 + c;
        mx = fmaxf(mx, pmax[o]);
        sm += psum[o];
        sq += psq[o];
    }
    X1[g * 512 + c] = mx;
    X1[g * 512 + 256 + c] = sm * (1.f / K1);
    unsafeAtomicAdd(&stats2[c], sm);
    unsafeAtomicAdd(&stats2[HID + c], sq);
}

// ---------- h2in = gelu(bn2(h1p)) -> fp16 A2 right half ----------
__global__ __launch_bounds__(256) void k_h2in(const _Float16* __restrict__ H1P,
        const float* __restrict__ scale2, const float* __restrict__ shift2,
        _Float16* __restrict__ A2) {
    const int total = NN1 * (HID / 4);
    for (int i = blockIdx.x * 256 + threadIdx.x; i < total; i += gridDim.x * 256) {
        const int r = i >> 6, c4 = i & 63;
        const f16x4 v = reinterpret_cast<const f16x4*>(H1P)[i];
        const float4 sc = reinterpret_cast<const float4*>(scale2)[c4];
        const float4 sh = reinterpret_cast<const float4*>(shift2)[c4];
        *reinterpret_cast<f16x4*>(&A2[(size_t)r * 512 + 256 + (c4 << 2)]) =
            (f16x4){(_Float16)gelu_exact((float)v[0] * sc.x + sh.x),
                    (_Float16)gelu_exact((float)v[1] * sc.y + sh.y),
                    (_Float16)gelu_exact((float)v[2] * sc.z + sh.z),
                    (_Float16)gelu_exact((float)v[3] * sc.w + sh.w)};
    }
}

// ---------- x2 readout, stage 1: 512 blocks (g x 8 row-groups of 32) -------
__global__ __launch_bounds__(256) void k_x2p(const _Float16* __restrict__ H2,
        const int* __restrict__ perm, const float* __restrict__ vals,
        float* __restrict__ pmax, float* __restrict__ psum) {
    const int b = blockIdx.x;
    const int g = b >> 3, ig = b & 7;
    const int c = threadIdx.x;
    float mx = -FLT_MAX, sm = 0.f;
    for (int i = ig * 32; i < ig * 32 + 32; ++i) {
        const int idx = (g << 8) + i;
        const int srow = perm[idx];
        const float v = (float)H2[(size_t)srow * HID + c] * vals[idx];
        mx = fmaxf(mx, v);
        sm += v;
    }
    pmax[b * 256 + c] = mx;
    psum[b * 256 + c] = sm;
}

// ---------- x2 stage 2: reduce 8 partials ----------
__global__ __launch_bounds__(256) void k_x2r(const float* __restrict__ pmax,
        const float* __restrict__ psum, float* __restrict__ X2) {
    const int g = blockIdx.x, c = threadIdx.x;
    float mx = -FLT_MAX, sm = 0.f;
    for (int ig = 0; ig < 8; ++ig) {
        const int o = ((g << 3) + ig) * 256 + c;
        mx = fmaxf(mx, pmax[o]);
        sm += psum[o];
    }
    X2[g * 512 + c] = mx;
    X2[g * 512 + 256 + c] = sm * (1.f / K2);
}

// ---------- final linear: out = (x1+x2) @ Wl + bl ----------
__global__ __launch_bounds__(256) void k_final(const float* __restrict__ X1,
        const float* __restrict__ X2, const float* __restrict__ Wl,
        const float* __restrict__ bl, float* __restrict__ out) {
    const int g = blockIdx.x, c = threadIdx.x;
    float acc = bl[c];
    for (int k = 0; k < 512; ++k) {
        const float xv = X1[g * 512 + k] + X2[g * 512 + k];
        acc = fmaf(xv, Wl[k * HID + c], acc);
    }
    out[g * HID + c] = acc;
}

extern "C" void kernel_launch(void* const* d_in, const int* in_sizes, int n_in,
                              void* d_out, int out_size, void* d_ws, size_t ws_size,
                              hipStream_t stream) {
    (void)in_sizes; (void)n_in; (void)out_size; (void)ws_size;
    const float* x       = (const float*)d_in[0];
    const int*   src     = (const int*)  d_in[1];
    const int*   dst     = (const int*)  d_in[2];
    const float* W_rel1  = (const float*)d_in[3];
    const float* b_rel1  = (const float*)d_in[4];
    const float* W_root1 = (const float*)d_in[5];
    const float* g1      = (const float*)d_in[6];
    const float* bt1     = (const float*)d_in[7];
    const float* p1      = (const float*)d_in[8];
    const float* g2      = (const float*)d_in[9];
    const float* bt2     = (const float*)d_in[10];
    const float* W_rel2  = (const float*)d_in[11];
    const float* b_rel2  = (const float*)d_in[12];
    const float* W_root2 = (const float*)d_in[13];
    const float* p2      = (const float*)d_in[14];
    const float* Wl      = (const float*)d_in[15];
    const float* bl      = (const float*)d_in[16];
    float* out = (float*)d_out;

    char* w = (char*)d_ws;
    size_t off = 0;
    auto alloc = [&](size_t bytes) -> void* {
        void* p = w + off;
        off += (bytes + 255) & ~(size_t)255;
        return p;
    };
    _Float16* A1  = (_Float16*)alloc((size_t)NN0 * 256 * 2);  // 32 MB: [agg|x] fp16
    _Float16* HG  = (_Float16*)alloc((size_t)NN0 * 256 * 2);  // 32 MB: gelu(conv1) fp16
    _Float16* H2  = (_Float16*)alloc((size_t)NN1 * 256 * 2);  // 16 MB: conv2 out fp16
    int*   ROWP   = (int*)  alloc((size_t)GG * (NPG + 1) * 4);
    int*   SSRC   = (int*)  alloc((size_t)NE * 4);
    float* SCORES = (float*)alloc((size_t)8 * NN1 * 4);       // NN0 L1 / 8xNN1 partials
    int*   PERM1  = (int*)  alloc((size_t)NN1 * 4);
    float* VALS1  = (float*)alloc((size_t)NN1 * 4);
    int*   MAP1   = (int*)  alloc((size_t)NN0 * 4);
    int*   PERM2  = (int*)  alloc((size_t)NN2 * 4);
    float* VALS2  = (float*)alloc((size_t)NN2 * 4);
    float* STATS1 = (float*)alloc(512 * 4);
    float* STATS2 = (float*)alloc(512 * 4);
    float* SCALE1 = (float*)alloc(256 * 4);
    float* SHIFT1 = (float*)alloc(256 * 4);
    float* Q1     = (float*)alloc(256 * 4);
    float* R1     = (float*)alloc(256);
    float* SCALE2 = (float*)alloc(256 * 4);
    float* SHIFT2 = (float*)alloc(256 * 4);
    float* Q2     = (float*)alloc(256 * 4);
    _Float16* W1h = (_Float16*)alloc((size_t)256 * 256 * 2);
    _Float16* W1l = (_Float16*)alloc((size_t)256 * 256 * 2);
    _Float16* W2h = (_Float16*)alloc((size_t)256 * 512 * 2);
    _Float16* W2l = (_Float16*)alloc((size_t)256 * 512 * 2);
    float* X1     = (float*)alloc((size_t)GG * 512 * 4);
    float* X2     = (float*)alloc((size_t)GG * 512 * 4);
    float* PMAX   = (float*)alloc((size_t)512 * 256 * 4);
    float* PSUM   = (float*)alloc((size_t)512 * 256 * 4);
    float* PSQ    = (float*)alloc((size_t)512 * 256 * 4);
    // aliases (stream-ordered, producer dead before reuse):
    _Float16* H1P = A1;                   // A1 dead after gemm1
    _Float16* A2 = HG;                    // HG dead after pool1p

    k_prep<<<770, 256, 0, stream>>>(W_rel1, W_root1, W_rel2, W_root2, p2,
        W1h, W1l, W2h, W2l, Q2, STATS1, STATS2);
    k_csr<<<GG, 512, 0, stream>>>(src, dst, ROWP, SSRC, MAP1);
    k_agg1<<<8192, 256, 0, stream>>>(x, ROWP, SSRC, A1);
    k_gemm3<256, 1><<<dim3(512, 2), 512, 0, stream>>>(A1, W1h, W1l,
        b_rel1, HG, STATS1, nullptr, nullptr, NN0);
    k_finalize1<<<1, 256, 0, stream>>>(STATS1, g1, bt1, p1, SCALE1, SHIFT1, Q1, R1);
    k_score<<<NN0 / 4, 256, 0, stream>>>(HG, Q1, R1, SCORES);
    k_topk<NPG, K1, 512><<<GG, 512, 0, stream>>>(SCORES, 1, 0, PERM1, VALS1, MAP1);
    k_pool1p<<<512, 256, 0, stream>>>(HG, PERM1, VALS1, SCALE1, SHIFT1, H1P, PMAX, PSUM, PSQ);
    k_pool1r<<<GG, 256, 0, stream>>>(PMAX, PSUM, PSQ, X1, STATS2);
    k_finalize2<<<1, 256, 0, stream>>>(STATS2, g2, bt2, SCALE2, SHIFT2);
    k_h2in<<<2048, 256, 0, stream>>>(H1P, SCALE2, SHIFT2, A2);
    k_agg2<<<8192, 256, 0, stream>>>(A2, ROWP, SSRC, PERM1, MAP1, A2);
    k_gemm3<512, 2><<<dim3(256, 2), 512, 0, stream>>>(A2, W2h, W2l,
        b_rel2, H2, nullptr, Q2, SCORES, NN1);
    k_topk<K1, K2, 256><<<GG, 256, 0, stream>>>(SCORES, 8, NN1, PERM2, VALS2, nullptr);
    k_x2p<<<512, 256, 0, stream>>>(H2, PERM2, VALS2, PMAX, PSUM);
    k_x2r<<<GG, 256, 0, stream>>>(PMAX, PSUM, X2);
    k_final<<<GG, 256, 0, stream>>>(X1, X2, Wl, bl, out);
}

// Round 14
// 257.637 us; speedup vs baseline: 1.3973x; 1.0847x over previous
//
#include <hip/hip_runtime.h>
#include <hip/hip_bf16.h>
#include <float.h>

#define GG    64
#define NPG   1024
#define EPG   8192      // edges per graph
#define NE    524288
#define FIN   128
#define HID   256
#define K1    512
#define K2    256
#define NN0   65536     // GG*NPG
#define NN1   32768     // GG*K1
#define NN2   16384     // GG*K2
#define EPSBN 1e-5f

typedef _Float16 f16x8 __attribute__((ext_vector_type(8)));
typedef _Float16 f16x4 __attribute__((ext_vector_type(4)));
typedef float f32x4 __attribute__((ext_vector_type(4)));

__device__ __forceinline__ float gelu_exact(float v) {
    return 0.5f * v * (1.0f + erff(v * 0.7071067811865476f));
}

// async global->LDS, 16B per lane; lds dest must be wave-uniform base
__device__ __forceinline__ void gld16(const void* g, void* lds) {
    __builtin_amdgcn_global_load_lds(
        (const __attribute__((address_space(1))) unsigned int*)g,
        (__attribute__((address_space(3))) unsigned int*)lds, 16, 0, 0);
}

// ---------- merged prep + CSR ----------
// b<64: per-graph CSR build (+map1 init). b 64..191: W1 fp16 transpose.
// b 192..447: W2. b=448: q2 norm. b=449: stats zero.
__global__ __launch_bounds__(512) void k_prepcsr(
        const int* __restrict__ src, const int* __restrict__ dst,
        int* __restrict__ rowp, int* __restrict__ ssrc, int* __restrict__ map1,
        const float* __restrict__ Wrel1, const float* __restrict__ Wroot1,
        const float* __restrict__ Wrel2, const float* __restrict__ Wroot2,
        const float* __restrict__ p2,
        _Float16* __restrict__ W1h, _Float16* __restrict__ W2h,
        float* __restrict__ q2, float* __restrict__ stats1,
        float* __restrict__ stats2) {
    __shared__ int cnt[NPG];
    __shared__ int sa[NPG];
    __shared__ int sb[NPG];
    __shared__ float red[256];
    const int b = blockIdx.x, tid = threadIdx.x;
    if (b < 64) {
        const int g = b;
        const int eb = g * EPG;
        for (int i = g * 512 + tid; i < NN0; i += GG * 512) map1[i] = -1;
        for (int i = tid; i < NPG; i += 512) cnt[i] = 0;
        __syncthreads();
        for (int e = tid; e < EPG; e += 512)
            atomicAdd(&cnt[dst[eb + e] & (NPG - 1)], 1);
        __syncthreads();
        for (int i = tid; i < NPG; i += 512) sa[i] = cnt[i];
        __syncthreads();
        int* cur = sa; int* nxt = sb;
        for (int d = 1; d < NPG; d <<= 1) {             // inclusive scan
            for (int i = tid; i < NPG; i += 512)
                nxt[i] = cur[i] + ((i >= d) ? cur[i - d] : 0);
            __syncthreads();
            int* t = cur; cur = nxt; nxt = t;
        }
        for (int i = tid; i < NPG; i += 512) {
            const int st = cur[i] - cnt[i];             // exclusive start
            rowp[g * (NPG + 1) + i] = st;
            cnt[i] = st;                                // reuse as cursor
        }
        if (tid == 0) rowp[g * (NPG + 1) + NPG] = EPG;
        __syncthreads();
        for (int e = tid; e < EPG; e += 512) {
            const int d = dst[eb + e] & (NPG - 1);
            const int p = atomicAdd(&cnt[d], 1);
            ssrc[eb + p] = src[eb + e] & (NPG - 1);
        }
    } else if (b < 192) {                               // W1: 256n x 256k
        const int i = (b - 64) * 512 + tid;
        const int n = i >> 8, k = i & 255;
        const float v = (k < FIN) ? Wrel1[k * HID + n] : Wroot1[(k - FIN) * HID + n];
        W1h[i] = (_Float16)v;
    } else if (b < 448) {                               // W2: 256n x 512k
        const int i = (b - 192) * 512 + tid;
        const int n = i >> 9, k = i & 511;
        const float v = (k < HID) ? Wrel2[k * HID + n] : Wroot2[(k - HID) * HID + n];
        W2h[i] = (_Float16)v;
    } else if (b == 448) {                              // q2 = p2/||p2||
        if (tid < 256) { const float pv = p2[tid]; red[tid] = pv * pv; }
        __syncthreads();
        for (int s = 128; s > 0; s >>= 1) {
            if (tid < s) red[tid] += red[tid + s];
            __syncthreads();
        }
        if (tid < 256) q2[tid] = p2[tid] * rsqrtf(red[0]);
    } else {                                            // zero BN stats (512 each)
        stats1[tid] = 0.f;
        stats2[tid] = 0.f;
    }
}

// ---------- agg1: CSR gather-sum + own-row copy, fp16 out ----------
__global__ __launch_bounds__(256) void k_agg1(const float* __restrict__ x,
        const int* __restrict__ rowp, const int* __restrict__ ssrc,
        _Float16* __restrict__ A1) {
    const int b = blockIdx.x;
    const int g = b & 63;
    const int ng = b >> 6;                              // 0..127
    const int tid = threadIdx.x;
    const int ln = tid & 31;                            // col float4 0..31
    const int node = (ng << 3) + (tid >> 5);            // 0..1023
    const int s0 = rowp[g * (NPG + 1) + node];
    const int s1 = rowp[g * (NPG + 1) + node + 1];
    const float4* x4 = reinterpret_cast<const float4*>(x);
    const size_t gb = (size_t)(g << 10) * 32;           // 32 float4 per x row
    const int* sp = ssrc + (size_t)g * EPG;
    float4 acc = make_float4(0.f, 0.f, 0.f, 0.f);
    for (int j = s0; j < s1; ++j) {
        const float4 v = x4[gb + (size_t)sp[j] * 32 + ln];
        acc.x += v.x; acc.y += v.y; acc.z += v.z; acc.w += v.w;
    }
    const size_t rb = ((size_t)((g << 10) + node)) * 256;
    *reinterpret_cast<f16x4*>(&A1[rb + (ln << 2)]) =
        (f16x4){(_Float16)acc.x, (_Float16)acc.y, (_Float16)acc.z, (_Float16)acc.w};
    const float4 xv = x4[gb + (size_t)node * 32 + ln];  // lin_root operand
    *reinterpret_cast<f16x4*>(&A1[rb + 128 + (ln << 2)]) =
        (f16x4){(_Float16)xv.x, (_Float16)xv.y, (_Float16)xv.z, (_Float16)xv.w};
}

// ---------- agg2: reuse layer-1 CSR buckets, fp16 in/out ----------
__global__ __launch_bounds__(256) void k_agg2(const _Float16* __restrict__ A2r,
        const int* __restrict__ rowp, const int* __restrict__ ssrc,
        const int* __restrict__ perm1, const int* __restrict__ map1,
        _Float16* __restrict__ A2w) {
    const int b = blockIdx.x;
    const int g = b & 63;
    const int ng = b >> 6;                              // 0..127
    const int tid = threadIdx.x;
    const int ln = tid & 63;                            // col quad 0..63
    const int ni = (ng << 2) + (tid >> 6);              // new node 0..511
    const int on = perm1[(g << 9) + ni] & (NPG - 1);    // old node id
    const int s0 = rowp[g * (NPG + 1) + on];
    const int s1 = rowp[g * (NPG + 1) + on + 1];
    const int* sp = ssrc + (size_t)g * EPG;
    const int* mp = map1 + ((size_t)g << 10);
    float4 acc = make_float4(0.f, 0.f, 0.f, 0.f);
    for (int j = s0; j < s1; ++j) {
        const int ms = mp[sp[j]];                       // global new id or -1
        if (ms < 0) continue;                           // lane-uniform branch
        const f16x4 v = *reinterpret_cast<const f16x4*>(
            &A2r[(size_t)ms * 512 + 256 + (ln << 2)]);
        acc.x += (float)v[0]; acc.y += (float)v[1];
        acc.z += (float)v[2]; acc.w += (float)v[3];
    }
    *reinterpret_cast<f16x4*>(&A2w[((size_t)((g << 9) + ni)) * 512 + (ln << 2)]) =
        (f16x4){(_Float16)acc.x, (_Float16)acc.y, (_Float16)acc.z, (_Float16)acc.w};
}

// ---------- fp16 MFMA GEMM: C[M][256] = A[M][K] @ B[256][K]^T, fp16 C ------
// 512 threads, 8 waves 2(M)x4(N); wave tile 64x64 (4x4 frags = 64 VGPR acc).
// Block covers FULL N=256 (no y-split) -> 2x MFMA per staged byte vs 128-wide.
// DEPTH-3 pipeline: sets 3-deep, iter i issues set(i+2), waits vmcnt(6);
// consumed set was issued 2 iterations (~1200cy) earlier > HBM latency.
// Value-swizzled LDS (k-chunk = slot ^ ((row>>1)&3)), 0 bank conflicts.
// EPI 0: +bias; 1: +bias, gelu, col sum/sumsq stats; 2: +bias, fused score-dot
// EPI 2 writes RACE-FREE per-wn partials: slot = wn (4 slots).
template<int K, int EPI>
__global__ __launch_bounds__(512, 4) void k_gemm(
        const _Float16* __restrict__ A, const _Float16* __restrict__ B,
        const float* __restrict__ bias, _Float16* __restrict__ C,
        float* __restrict__ stats, const float* __restrict__ qv2,
        float* __restrict__ scores, int M) {
    __shared__ _Float16 Ash[3][128 * 32];                // 8 KB per buf
    __shared__ _Float16 Bsh[3][256 * 32];                // 16 KB per buf
    __shared__ float csum[256];
    __shared__ float csq[256];
    const int tid = threadIdx.x;
    const int l = tid & 63, w = tid >> 6;                // 8 waves
    const int wm = w >> 2, wn = w & 3;                   // 2 x 4 wave grid
    const int m0 = blockIdx.x * 128;
    const int r16 = l & 15, kg = l >> 4;

    // staging: wave w stages A rows 16w..16w+15 (1KB) and B rows 32w..32w+31
    // (2 x 1KB). lane row = l>>2, slot = l&3, k-chunk = slot ^ ((row>>1)&3).
    const int srA = (w << 4) + (l >> 2);
    const int swA = ((l & 3) ^ ((srA >> 1) & 3)) << 3;
    const size_t aoff = (size_t)(m0 + srA) * K + swA;
    const int ldsA = w << 10;
    const int srB0 = (w << 5) + (l >> 2);
    const int srB1 = srB0 + 16;
    const int swB0 = ((l & 3) ^ ((srB0 >> 1) & 3)) << 3;
    const int swB1 = ((l & 3) ^ ((srB1 >> 1) & 3)) << 3;
    const size_t boff0 = (size_t)srB0 * K + swB0;
    const size_t boff1 = (size_t)srB1 * K + swB1;
    const int ldsB0 = w << 11, ldsB1 = (w << 11) + 1024;

    f32x4 acc[4][4] = {};
    constexpr int NI = K / 32;

    // prologue: sets 0 and 1 in flight (3 loads per set per wave)
    gld16(A + aoff,       (char*)Ash[0] + ldsA);
    gld16(B + boff0,      (char*)Bsh[0] + ldsB0);
    gld16(B + boff1,      (char*)Bsh[0] + ldsB1);
    gld16(A + aoff + 32,  (char*)Ash[1] + ldsA);
    gld16(B + boff0 + 32, (char*)Bsh[1] + ldsB0);
    gld16(B + boff1 + 32, (char*)Bsh[1] + ldsB1);

#pragma unroll
    for (int i = 0; i < NI; ++i) {
        const int k0 = i * 32;
        const int cur = i % 3;
        __builtin_amdgcn_s_barrier();                    // iter i-1 reads done
        if (i + 2 < NI) {
            const int nxt = (i + 2) % 3;
            gld16(A + aoff + k0 + 64,  (char*)Ash[nxt] + ldsA);
            gld16(B + boff0 + k0 + 64, (char*)Bsh[nxt] + ldsB0);
            gld16(B + boff1 + k0 + 64, (char*)Bsh[nxt] + ldsB1);
            asm volatile("s_waitcnt vmcnt(6)" ::: "memory");  // set(i) landed
        } else if (i + 1 < NI) {
            asm volatile("s_waitcnt vmcnt(3)" ::: "memory");
        } else {
            asm volatile("s_waitcnt vmcnt(0)" ::: "memory");
        }
        __builtin_amdgcn_s_barrier();                    // buf[cur] ready
        __builtin_amdgcn_sched_barrier(0);
        const char* ab = (const char*)Ash[cur];
        const char* bb = (const char*)Bsh[cur];
        f16x8 af[4], bf[4];
#pragma unroll
        for (int mi = 0; mi < 4; ++mi) {
            const int r = wm * 64 + mi * 16 + r16;
            const int bo = r * 64 + ((kg ^ ((r >> 1) & 3)) << 4);
            af[mi] = *reinterpret_cast<const f16x8*>(ab + bo);
        }
#pragma unroll
        for (int ni = 0; ni < 4; ++ni) {
            const int r = wn * 64 + ni * 16 + r16;
            const int bo = r * 64 + ((kg ^ ((r >> 1) & 3)) << 4);
            bf[ni] = *reinterpret_cast<const f16x8*>(bb + bo);
        }
#pragma unroll
        for (int mi = 0; mi < 4; ++mi)
#pragma unroll
            for (int ni = 0; ni < 4; ++ni)
                acc[mi][ni] = __builtin_amdgcn_mfma_f32_16x16x32_f16(
                    af[mi], bf[ni], acc[mi][ni], 0, 0, 0);
    }

    if (EPI == 1) {
        if (tid < 256) { csum[tid] = 0.f; csq[tid] = 0.f; }
        __syncthreads();
    }

    float qv[4];
    if (EPI == 2) {
#pragma unroll
        for (int ni = 0; ni < 4; ++ni) qv[ni] = qv2[wn * 64 + ni * 16 + r16];
    }
    float sA[4] = {0, 0, 0, 0};
    float qA[4] = {0, 0, 0, 0};
    float sp[4][4] = {};
#pragma unroll
    for (int mi = 0; mi < 4; ++mi)
#pragma unroll
        for (int ni = 0; ni < 4; ++ni) {
            const int col = wn * 64 + ni * 16 + r16;
            const float bc = bias[col];
#pragma unroll
            for (int r = 0; r < 4; ++r) {
                const int row = m0 + wm * 64 + mi * 16 + (kg << 2) + r;
                float t = acc[mi][ni][r] + bc;
                if (EPI == 1) {
                    t = gelu_exact(t);
                    sA[ni] += t;
                    qA[ni] += t * t;
                }
                if (EPI == 2) sp[mi][r] += t * qv[ni];
                C[(size_t)row * 256 + col] = (_Float16)t;
            }
        }
    if (EPI == 1) {
#pragma unroll
        for (int ni = 0; ni < 4; ++ni) {
            const int cl = wn * 64 + ni * 16 + r16;
            unsafeAtomicAdd(&csum[cl], sA[ni]);
            unsafeAtomicAdd(&csq[cl], qA[ni]);
        }
        __syncthreads();
        if (tid < 256) {
            unsafeAtomicAdd(&stats[tid], csum[tid]);
            unsafeAtomicAdd(&stats[HID + tid], csq[tid]);
        }
    }
    if (EPI == 2) {
        // partial over this wn's 64 cols; unique slot per writer
        const int slot = wn;
#pragma unroll
        for (int mi = 0; mi < 4; ++mi)
#pragma unroll
            for (int r = 0; r < 4; ++r) {
                float s = sp[mi][r];
                s += __shfl_xor(s, 1);
                s += __shfl_xor(s, 2);
                s += __shfl_xor(s, 4);
                s += __shfl_xor(s, 8);
                if (r16 == 0)
                    scores[(size_t)slot * M + m0 + wm * 64 + mi * 16 + (kg << 2) + r] = s;
            }
    }
}

// ---------- BN finalize / score fold ----------
__global__ __launch_bounds__(256) void k_finalize1(const float* __restrict__ stats,
        const float* __restrict__ g1, const float* __restrict__ bt1,
        const float* __restrict__ p1, float* __restrict__ scale,
        float* __restrict__ shift, float* __restrict__ q, float* __restrict__ r) {
    __shared__ float red[256];
    const int c = threadIdx.x;
    const float m = stats[c] * (1.f / NN0);
    const float v = stats[HID + c] * (1.f / NN0) - m * m;
    const float sc = g1[c] * rsqrtf(v + EPSBN);
    const float sh = bt1[c] - m * sc;
    scale[c] = sc;
    shift[c] = sh;
    const float pv = p1[c];
    red[c] = pv * pv;
    __syncthreads();
    for (int s = 128; s > 0; s >>= 1) {
        if (c < s) red[c] += red[c + s];
        __syncthreads();
    }
    const float inv = rsqrtf(red[0]);
    q[c] = sc * pv * inv;
    __syncthreads();
    red[c] = sh * pv * inv;
    __syncthreads();
    for (int s = 128; s > 0; s >>= 1) {
        if (c < s) red[c] += red[c + s];
        __syncthreads();
    }
    if (c == 0) r[0] = red[0];
}

__global__ __launch_bounds__(256) void k_finalize2(const float* __restrict__ stats,
        const float* __restrict__ g2, const float* __restrict__ bt2,
        float* __restrict__ scale, float* __restrict__ shift) {
    const int c = threadIdx.x;
    const float m = stats[c] * (1.f / NN1);
    const float v = stats[HID + c] * (1.f / NN1) - m * m;
    const float sc = g2[c] * rsqrtf(v + EPSBN);
    scale[c] = sc;
    shift[c] = bt2[c] - m * sc;
}

// ---------- scores (layer1): raw dot h.q + r (tanh applied in topk) ----------
__global__ __launch_bounds__(256) void k_score(const _Float16* __restrict__ H,
        const float* __restrict__ q, const float* __restrict__ r,
        float* __restrict__ out) {
    const int node = blockIdx.x * 4 + (threadIdx.x >> 6);
    const int lane = threadIdx.x & 63;
    const f16x4 h = *reinterpret_cast<const f16x4*>(H + (size_t)node * HID + (lane << 2));
    const float4 qv = *reinterpret_cast<const float4*>(q + (lane << 2));
    float d = (float)h[0] * qv.x + (float)h[1] * qv.y +
              (float)h[2] * qv.z + (float)h[3] * qv.w;
#pragma unroll
    for (int off = 32; off > 0; off >>= 1) d += __shfl_xor(d, off);
    if (lane == 0) out[node] = d + (r ? r[0] : 0.f);
}

// ---------- per-graph bitonic top-k (sums nparts partials, tanh at load) ----
template<int NN_, int KK_, int NT_>
__global__ __launch_bounds__(NT_) void k_topk(const float* __restrict__ scores,
        int nparts, int pstride, int* __restrict__ perm,
        float* __restrict__ vals, int* __restrict__ mapping) {
    __shared__ float s[NN_];
    __shared__ int id[NN_];
    const int g = blockIdx.x, tid = threadIdx.x;
    for (int i = tid; i < NN_; i += NT_) {
        float raw = 0.f;
        for (int p = 0; p < nparts; ++p)
            raw += scores[(size_t)p * pstride + g * NN_ + i];
        s[i] = tanhf(raw);
        id[i] = i;
    }
    __syncthreads();
    for (int k = 2; k <= NN_; k <<= 1) {
        for (int j = k >> 1; j > 0; j >>= 1) {
            for (int t = tid; t < NN_; t += NT_) {
                const int ixj = t ^ j;
                if (ixj > t) {
                    const bool desc = ((t & k) == 0);
                    const float s1 = s[t], s2 = s[ixj];
                    const int i1 = id[t], i2 = id[ixj];
                    const bool inOrder = (s1 > s2) || (s1 == s2 && i1 < i2);
                    if (inOrder != desc) { s[t] = s2; s[ixj] = s1; id[t] = i2; id[ixj] = i1; }
                }
            }
            __syncthreads();
        }
    }
    for (int i = tid; i < KK_; i += NT_) {
        const int oid = id[i];
        perm[g * KK_ + i] = g * NN_ + oid;
        vals[g * KK_ + i] = s[i];
        if (mapping) mapping[g * NN_ + oid] = g * KK_ + i;
    }
}

// ---------- pool1 stage 1: stats/readout partials only (no H1P store) ------
__global__ __launch_bounds__(256) void k_pool1p(const _Float16* __restrict__ HG,
        const int* __restrict__ perm, const float* __restrict__ vals,
        const float* __restrict__ scale1, const float* __restrict__ shift1,
        float* __restrict__ pmax, float* __restrict__ psum,
        float* __restrict__ psq) {
    const int b = blockIdx.x;
    const int g = b >> 3, ig = b & 7;
    const int c = threadIdx.x;
    const float sc = scale1[c], sh = shift1[c];
    float mx = -FLT_MAX, sm = 0.f, sq = 0.f;
    for (int i = ig * 64; i < ig * 64 + 64; ++i) {
        const int idx = (g << 9) + i;
        const int srow = perm[idx];
        const float val = vals[idx];
        const float hv = (float)HG[(size_t)srow * HID + c];
        const float xn = (hv * sc + sh) * val;
        mx = fmaxf(mx, xn);
        sm += xn;
        sq += xn * xn;
    }
    pmax[b * 256 + c] = mx;
    psum[b * 256 + c] = sm;
    psq[b * 256 + c] = sq;
}

// ---------- pool1 stage 2: reduce 8 partials, x1 readout, bn2 stats ----------
__global__ __launch_bounds__(256) void k_pool1r(const float* __restrict__ pmax,
        const float* __restrict__ psum, const float* __restrict__ psq,
        float* __restrict__ X1, float* __restrict__ stats2) {
    const int g = blockIdx.x, c = threadIdx.x;
    float mx = -FLT_MAX, sm = 0.f, sq = 0.f;
    for (int ig = 0; ig < 8; ++ig) {
        const int o = ((g << 3) + ig) * 256 + c;
        mx = fmaxf(mx, pmax[o]);
        sm += psum[o];
        sq += psq[o];
    }
    X1[g * 512 + c] = mx;
    X1[g * 512 + 256 + c] = sm * (1.f / K1);
    unsafeAtomicAdd(&stats2[c], sm);
    unsafeAtomicAdd(&stats2[HID + c], sq);
}

// ---------- h2in: gather HG, BN1*val + BN2 + gelu -> fp16 A2 right half -----
__global__ __launch_bounds__(256) void k_h2in(const _Float16* __restrict__ HG,
        const int* __restrict__ perm, const float* __restrict__ vals,
        const float* __restrict__ scale1, const float* __restrict__ shift1,
        const float* __restrict__ scale2, const float* __restrict__ shift2,
        _Float16* __restrict__ A2) {
    const int i = blockIdx.x * 256 + threadIdx.x;       // NN1*64
    const int idx = i >> 6, c4 = i & 63;
    const int srow = perm[idx];
    const float val = vals[idx];
    const f16x4 h = *reinterpret_cast<const f16x4*>(&HG[(size_t)srow * HID + (c4 << 2)]);
    const float4 s1 = reinterpret_cast<const float4*>(scale1)[c4];
    const float4 b1 = reinterpret_cast<const float4*>(shift1)[c4];
    const float4 s2 = reinterpret_cast<const float4*>(scale2)[c4];
    const float4 b2 = reinterpret_cast<const float4*>(shift2)[c4];
    const float x0 = ((float)h[0] * s1.x + b1.x) * val;
    const float x1 = ((float)h[1] * s1.y + b1.y) * val;
    const float x2 = ((float)h[2] * s1.z + b1.z) * val;
    const float x3 = ((float)h[3] * s1.w + b1.w) * val;
    *reinterpret_cast<f16x4*>(&A2[(size_t)idx * 512 + 256 + (c4 << 2)]) =
        (f16x4){(_Float16)gelu_exact(x0 * s2.x + b2.x),
                (_Float16)gelu_exact(x1 * s2.y + b2.y),
                (_Float16)gelu_exact(x2 * s2.z + b2.z),
                (_Float16)gelu_exact(x3 * s2.w + b2.w)};
}

// ---------- x2 readout, stage 1: 512 blocks (g x 8 row-groups of 32) -------
__global__ __launch_bounds__(256) void k_x2p(const _Float16* __restrict__ H2,
        const int* __restrict__ perm, const float* __restrict__ vals,
        float* __restrict__ pmax, float* __restrict__ psum) {
    const int b = blockIdx.x;
    const int g = b >> 3, ig = b & 7;
    const int c = threadIdx.x;
    float mx = -FLT_MAX, sm = 0.f;
    for (int i = ig * 32; i < ig * 32 + 32; ++i) {
        const int idx = (g << 8) + i;
        const int srow = perm[idx];
        const float v = (float)H2[(size_t)srow * HID + c] * vals[idx];
        mx = fmaxf(mx, v);
        sm += v;
    }
    pmax[b * 256 + c] = mx;
    psum[b * 256 + c] = sm;
}

// ---------- x2 stage 2 + final linear fused ----------
__global__ __launch_bounds__(256) void k_x2final(const float* __restrict__ pmax,
        const float* __restrict__ psum, const float* __restrict__ X1,
        const float* __restrict__ Wl, const float* __restrict__ bl,
        float* __restrict__ out) {
    __shared__ float sx2[512];
    const int g = blockIdx.x, c = threadIdx.x;
    float mx = -FLT_MAX, sm = 0.f;
    for (int ig = 0; ig < 8; ++ig) {
        const int o = ((g << 3) + ig) * 256 + c;
        mx = fmaxf(mx, pmax[o]);
        sm += psum[o];
    }
    sx2[c] = mx;
    sx2[256 + c] = sm * (1.f / K2);
    __syncthreads();
    float acc = bl[c];
    for (int k = 0; k < 512; ++k) {
        const float xv = X1[g * 512 + k] + sx2[k];
        acc = fmaf(xv, Wl[k * HID + c], acc);
    }
    out[g * HID + c] = acc;
}

extern "C" void kernel_launch(void* const* d_in, const int* in_sizes, int n_in,
                              void* d_out, int out_size, void* d_ws, size_t ws_size,
                              hipStream_t stream) {
    (void)in_sizes; (void)n_in; (void)out_size; (void)ws_size;
    const float* x       = (const float*)d_in[0];
    const int*   src     = (const int*)  d_in[1];
    const int*   dst     = (const int*)  d_in[2];
    const float* W_rel1  = (const float*)d_in[3];
    const float* b_rel1  = (const float*)d_in[4];
    const float* W_root1 = (const float*)d_in[5];
    const float* g1      = (const float*)d_in[6];
    const float* bt1     = (const float*)d_in[7];
    const float* p1      = (const float*)d_in[8];
    const float* g2      = (const float*)d_in[9];
    const float* bt2     = (const float*)d_in[10];
    const float* W_rel2  = (const float*)d_in[11];
    const float* b_rel2  = (const float*)d_in[12];
    const float* W_root2 = (const float*)d_in[13];
    const float* p2      = (const float*)d_in[14];
    const float* Wl      = (const float*)d_in[15];
    const float* bl      = (const float*)d_in[16];
    float* out = (float*)d_out;

    char* w = (char*)d_ws;
    size_t off = 0;
    auto alloc = [&](size_t bytes) -> void* {
        void* p = w + off;
        off += (bytes + 255) & ~(size_t)255;
        return p;
    };
    _Float16* A1  = (_Float16*)alloc((size_t)NN0 * 256 * 2);  // 32 MB: [agg|x] fp16
    _Float16* HG  = (_Float16*)alloc((size_t)NN0 * 256 * 2);  // 32 MB: gelu(conv1) fp16
    _Float16* H2  = (_Float16*)alloc((size_t)NN1 * 256 * 2);  // 16 MB: conv2 out fp16
    int*   ROWP   = (int*)  alloc((size_t)GG * (NPG + 1) * 4);
    int*   SSRC   = (int*)  alloc((size_t)NE * 4);
    float* SCORES = (float*)alloc((size_t)4 * NN1 * 4);       // NN0 L1 / 4xNN1 partials
    int*   PERM1  = (int*)  alloc((size_t)NN1 * 4);
    float* VALS1  = (float*)alloc((size_t)NN1 * 4);
    int*   MAP1   = (int*)  alloc((size_t)NN0 * 4);
    int*   PERM2  = (int*)  alloc((size_t)NN2 * 4);
    float* VALS2  = (float*)alloc((size_t)NN2 * 4);
    float* STATS1 = (float*)alloc(512 * 4);
    float* STATS2 = (float*)alloc(512 * 4);
    float* SCALE1 = (float*)alloc(256 * 4);
    float* SHIFT1 = (float*)alloc(256 * 4);
    float* Q1     = (float*)alloc(256 * 4);
    float* R1     = (float*)alloc(256);
    float* SCALE2 = (float*)alloc(256 * 4);
    float* SHIFT2 = (float*)alloc(256 * 4);
    float* Q2     = (float*)alloc(256 * 4);
    _Float16* W1h = (_Float16*)alloc((size_t)256 * 256 * 2);
    _Float16* W2h = (_Float16*)alloc((size_t)256 * 512 * 2);
    float* X1     = (float*)alloc((size_t)GG * 512 * 4);
    float* PMAX   = (float*)alloc((size_t)512 * 256 * 4);
    float* PSUM   = (float*)alloc((size_t)512 * 256 * 4);
    float* PSQ    = (float*)alloc((size_t)512 * 256 * 4);
    // alias (stream-ordered): A1 dead after gemm1; h2in/agg2 write A2 while
    // reading HG -> A2 must NOT alias HG.
    _Float16* A2 = A1;

    k_prepcsr<<<450, 512, 0, stream>>>(src, dst, ROWP, SSRC, MAP1,
        W_rel1, W_root1, W_rel2, W_root2, p2, W1h, W2h, Q2, STATS1, STATS2);
    k_agg1<<<8192, 256, 0, stream>>>(x, ROWP, SSRC, A1);
    k_gemm<256, 1><<<512, 512, 0, stream>>>(A1, W1h, b_rel1, HG, STATS1,
        nullptr, nullptr, NN0);
    k_finalize1<<<1, 256, 0, stream>>>(STATS1, g1, bt1, p1, SCALE1, SHIFT1, Q1, R1);
    k_score<<<NN0 / 4, 256, 0, stream>>>(HG, Q1, R1, SCORES);
    k_topk<NPG, K1, 512><<<GG, 512, 0, stream>>>(SCORES, 1, 0, PERM1, VALS1, MAP1);
    k_pool1p<<<512, 256, 0, stream>>>(HG, PERM1, VALS1, SCALE1, SHIFT1, PMAX, PSUM, PSQ);
    k_pool1r<<<GG, 256, 0, stream>>>(PMAX, PSUM, PSQ, X1, STATS2);
    k_finalize2<<<1, 256, 0, stream>>>(STATS2, g2, bt2, SCALE2, SHIFT2);
    k_h2in<<<8192, 256, 0, stream>>>(HG, PERM1, VALS1, SCALE1, SHIFT1,
        SCALE2, SHIFT2, A2);
    k_agg2<<<8192, 256, 0, stream>>>(A2, ROWP, SSRC, PERM1, MAP1, A2);
    k_gemm<512, 2><<<256, 512, 0, stream>>>(A2, W2h, b_rel2, H2, nullptr,
        Q2, SCORES, NN1);
    k_topk<K1, K2, 256><<<GG, 256, 0, stream>>>(SCORES, 4, NN1, PERM2, VALS2, nullptr);
    k_x2p<<<512, 256, 0, stream>>>(H2, PERM2, VALS2, PMAX, PSUM);
    k_x2final<<<GG, 256, 0, stream>>>(PMAX, PSUM, X1, Wl, bl, out);
}